// Round 6
// baseline (359.031 us; speedup 1.0000x reference)
//
#include <hip/hip_runtime.h>

#define NN 100000
#define NE 1600000
#define EN (NE + NN)          // edges incl. self-loops
#define FIN 128
#define H1 8
#define C1 16
#define F1 128                // H1*C1
#define NC 64
#define NEG 0.2f

// ---- CSR-build multisplit parameters ----
#define BSH 9                 // bucket = dst >> BSH
#define BKN 512               // nodes per bucket
#define NBUK ((NN + BKN - 1) / BKN)   // 196
#define NBLK 256              // edge-chunk blocks for P1/P2
#define CHUNK ((EN + NBLK - 1) / NBLK) // 6641
#define CAPB 12288            // LDS col capacity per bucket (avg 8704, +40 sigma)

typedef unsigned short ushort_t;
typedef unsigned int uint_t;

__device__ __forceinline__ ushort_t f2bf(float f) {
  uint_t u = __builtin_bit_cast(uint_t, f);
  u += 0x7FFF + ((u >> 16) & 1);  // RNE
  return (ushort_t)(u >> 16);
}
__device__ __forceinline__ float bflo(uint_t u) {
  return __builtin_bit_cast(float, u << 16);
}
__device__ __forceinline__ float bfhi(uint_t u) {
  return __builtin_bit_cast(float, u & 0xFFFF0000u);
}
__device__ __forceinline__ float bf2f(ushort_t s) {
  return __builtin_bit_cast(float, (uint_t)s << 16);
}

// --------------- SGEMM: H[n, BN] = X[n, 128] @ W[128, BN], bf16 out ---------
template <int BM, int BN>
__global__ __launch_bounds__(256) void sgemm_bf16out_kernel(
    const float* __restrict__ X, const float* __restrict__ W,
    ushort_t* __restrict__ Hout, int nrows) {
  constexpr int BK = 32;
  constexpr int K = 128;
  constexpr int LDX = BM + 4;
  constexpr int LDW = BN + 4;
  constexpr int TN = BN / 8;
  __shared__ float Xs[BK][LDX];
  __shared__ float Ws[BK][LDW];
  const int tid = threadIdx.x;
  const int tn = tid % TN;
  const int tm = tid / TN;
  const int row0 = blockIdx.x * BM;

  float acc[8][8];
#pragma unroll
  for (int i = 0; i < 8; ++i)
#pragma unroll
    for (int j = 0; j < 8; ++j) acc[i][j] = 0.f;

  constexpr int XF4 = BM * BK / 4;
  constexpr int WF4 = BK * BN / 4;

  for (int k0 = 0; k0 < K; k0 += BK) {
    if (k0) __syncthreads();
#pragma unroll
    for (int r = 0; r < XF4 / 256; ++r) {
      int i = tid + 256 * r;
      int m = i >> 3;
      int q = i & 7;
      int mg = row0 + m;
      if (mg >= nrows) mg = nrows - 1;
      float4 v = *(const float4*)(X + (size_t)mg * K + k0 + q * 4);
      Xs[q * 4 + 0][m] = v.x;
      Xs[q * 4 + 1][m] = v.y;
      Xs[q * 4 + 2][m] = v.z;
      Xs[q * 4 + 3][m] = v.w;
    }
#pragma unroll
    for (int r = 0; r < WF4 / 256; ++r) {
      int i = tid + 256 * r;
      int k = i / (BN / 4);
      int n4 = i % (BN / 4);
      float4 v = *(const float4*)(W + (size_t)(k0 + k) * BN + n4 * 4);
      *(float4*)&Ws[k][n4 * 4] = v;
    }
    __syncthreads();

#pragma unroll 8
    for (int k = 0; k < BK; ++k) {
      float4 a0 = *(const float4*)&Xs[k][tm * 4];
      float4 a1 = *(const float4*)&Xs[k][BM / 2 + tm * 4];
      float4 b0 = *(const float4*)&Ws[k][tn * 4];
      float4 b1 = *(const float4*)&Ws[k][BN / 2 + tn * 4];
      float a[8] = {a0.x, a0.y, a0.z, a0.w, a1.x, a1.y, a1.z, a1.w};
      float b[8] = {b0.x, b0.y, b0.z, b0.w, b1.x, b1.y, b1.z, b1.w};
#pragma unroll
      for (int i = 0; i < 8; ++i)
#pragma unroll
        for (int j = 0; j < 8; ++j) acc[i][j] = fmaf(a[i], b[j], acc[i][j]);
    }
  }

#pragma unroll
  for (int i = 0; i < 8; ++i) {
    int row = row0 + (i < 4 ? tm * 4 + i : BM / 2 + tm * 4 + (i - 4));
    if (row >= nrows) continue;
    ushort_t lo[4] = {f2bf(acc[i][0]), f2bf(acc[i][1]), f2bf(acc[i][2]),
                      f2bf(acc[i][3])};
    ushort_t hi[4] = {f2bf(acc[i][4]), f2bf(acc[i][5]), f2bf(acc[i][6]),
                      f2bf(acc[i][7])};
    *(uint2*)(Hout + (size_t)row * BN + tn * 4) = *(const uint2*)lo;
    *(uint2*)(Hout + (size_t)row * BN + BN / 2 + tn * 4) = *(const uint2*)hi;
  }
}

// ------------- layer-1 per-node attention terms: asn/adn [N,8] ---------------
__global__ void attn1_kernel(const ushort_t* __restrict__ h1,
                             const float* __restrict__ a_src,
                             const float* __restrict__ a_dst,
                             float* __restrict__ asn, float* __restrict__ adn) {
  int wid = (blockIdx.x * blockDim.x + threadIdx.x) >> 6;
  int lane = threadIdx.x & 63;
  if (wid >= NN) return;
  uint_t hv = ((const uint_t*)(h1 + (size_t)wid * F1))[lane];
  float hx = bflo(hv);
  float hy = bfhi(hv);
  float2 as = ((const float2*)a_src)[lane];
  float2 ad = ((const float2*)a_dst)[lane];
  float s = hx * as.x + hy * as.y;
  float d = hx * ad.x + hy * ad.y;
  s += __shfl_xor(s, 1); s += __shfl_xor(s, 2); s += __shfl_xor(s, 4);
  d += __shfl_xor(d, 1); d += __shfl_xor(d, 2); d += __shfl_xor(d, 4);
  if ((lane & 7) == 0) {
    asn[wid * 8 + (lane >> 3)] = s;
    adn[wid * 8 + (lane >> 3)] = d;
  }
}

// ------------- layer-2 per-node attention terms: asn/adn [N] -----------------
__global__ void attn2_kernel(const ushort_t* __restrict__ h2,
                             const float* __restrict__ a_src,
                             const float* __restrict__ a_dst,
                             float* __restrict__ asn, float* __restrict__ adn) {
  int wid = (blockIdx.x * blockDim.x + threadIdx.x) >> 6;
  int lane = threadIdx.x & 63;
  if (wid >= NN) return;
  float h = bf2f(h2[(size_t)wid * NC + lane]);
  float s = h * a_src[lane];
  float d = h * a_dst[lane];
#pragma unroll
  for (int m = 1; m < 64; m <<= 1) { s += __shfl_xor(s, m); d += __shfl_xor(d, m); }
  if (lane == 0) { asn[wid] = s; adn[wid] = d; }
}

// ------------------ CSR build: two-level multisplit by dst -------------------
__global__ __launch_bounds__(512) void bucket_count_kernel(
    const int* __restrict__ dstA, int* __restrict__ cnt) {
  __shared__ int histL[NBUK];
  int b = blockIdx.x, t = threadIdx.x;
  for (int i = t; i < NBUK; i += 512) histL[i] = 0;
  __syncthreads();
  int e0 = b * CHUNK, e1 = min(e0 + CHUNK, EN);
  for (int e = e0 + t; e < e1; e += 512) {
    int d = (e < NE) ? dstA[e] : (e - NE);
    atomicAdd(&histL[d >> BSH], 1);
  }
  __syncthreads();
  for (int i = t; i < NBUK; i += 512) cnt[i * NBLK + b] = histL[i];
}

__global__ __launch_bounds__(256) void bucket_scan_kernel(
    int* __restrict__ cnt, int* __restrict__ bucket_base) {
  __shared__ int colsum[NBUK];
  int t = threadIdx.x;
  if (t < NBUK) {
    int run = 0;
    int* c = cnt + t * NBLK;
    for (int b = 0; b < NBLK; ++b) { int v = c[b]; c[b] = run; run += v; }
    colsum[t] = run;
  }
  __syncthreads();
  if (t == 0) {
    int base = 0;
    for (int j = 0; j < NBUK; ++j) {
      bucket_base[j] = base;
      int v = colsum[j];
      colsum[j] = base;
      base += v;
    }
    bucket_base[NBUK] = base;  // == EN
  }
  __syncthreads();
  if (t < NBUK) {
    int bb = colsum[t];
    int* c = cnt + t * NBLK;
    for (int b = 0; b < NBLK; ++b) c[b] += bb;
  }
}

__global__ __launch_bounds__(512) void bucket_scatter_kernel(
    const int* __restrict__ srcA, const int* __restrict__ dstA,
    const int* __restrict__ cnt, int* __restrict__ staging) {
  __shared__ int cur[NBUK];
  int b = blockIdx.x, t = threadIdx.x;
  for (int i = t; i < NBUK; i += 512) cur[i] = cnt[i * NBLK + b];
  __syncthreads();
  int e0 = b * CHUNK, e1 = min(e0 + CHUNK, EN);
  for (int e = e0 + t; e < e1; e += 512) {
    int s, d;
    if (e < NE) { s = srcA[e]; d = dstA[e]; } else { s = e - NE; d = s; }
    int pos = atomicAdd(&cur[d >> BSH], 1);
    staging[pos] = s | ((d & (BKN - 1)) << 17);
  }
}

// P3: per-bucket fine CSR in LDS; each node's edge list sorted by src for
// L2 temporal locality in the gathers (all waves sweep src low->high).
__global__ __launch_bounds__(512) void bucket_csr_kernel(
    const int* __restrict__ staging, const int* __restrict__ bucket_base,
    int* __restrict__ rp, int* __restrict__ col) {
  __shared__ int degL[BKN];
  __shared__ int exclL[BKN];
  __shared__ int sdata[2][BKN];
  __shared__ int colL[CAPB];   // 48 KB
  int bk = blockIdx.x, t = threadIdx.x;
  int ebase = bucket_base[bk], eend = bucket_base[bk + 1];
  int ecnt = eend - ebase;
  bool fits = (ecnt <= CAPB);
  degL[t] = 0;
  __syncthreads();
  for (int e = t; e < ecnt; e += 512)
    atomicAdd(&degL[staging[ebase + e] >> 17], 1);
  __syncthreads();
  int v = degL[t];
  sdata[0][t] = v;
  __syncthreads();
  int sp = 0;
  for (int off = 1; off < BKN; off <<= 1) {
    int val = sdata[sp][t];
    if (t >= off) val += sdata[sp][t - off];
    sdata[sp ^ 1][t] = val;
    __syncthreads();
    sp ^= 1;
  }
  int ex = sdata[sp][t] - v;  // local exclusive offset within bucket
  exclL[t] = ex;
  int node = bk * BKN + t;
  if (node < NN) rp[node] = ebase + ex;
  if (bk == 0 && t == 0) rp[NN] = EN;
  __syncthreads();
  if (fits) {
    for (int e = t; e < ecnt; e += 512) {
      int pk = staging[ebase + e];
      int pos = atomicAdd(&exclL[pk >> 17], 1);
      colL[pos] = pk & 0x1FFFF;
    }
    __syncthreads();
    // per-node insertion sort of [ex, ex+v) by src
    for (int i = ex + 1; i < ex + v; ++i) {
      int key = colL[i];
      int j = i - 1;
      while (j >= ex && colL[j] > key) { colL[j + 1] = colL[j]; --j; }
      colL[j + 1] = key;
    }
    __syncthreads();
    for (int e = t; e < ecnt; e += 512) col[ebase + e] = colL[e];
  } else {  // statistically unreachable fallback (no sort)
    for (int e = t; e < ecnt; e += 512) {
      int pk = staging[ebase + e];
      int pos = atomicAdd(&exclL[pk >> 17], 1);
      col[ebase + pos] = pk & 0x1FFFF;
    }
  }
}

// ------ layer-1 gather: 16 lanes/node, 8 ch/lane (uint4), 2-edge unroll ------
__global__ __launch_bounds__(256) void gather1_kernel(
    const int* __restrict__ rp, const int* __restrict__ col,
    const float* __restrict__ asn, const float* __restrict__ adn,
    const ushort_t* __restrict__ h1, const float* __restrict__ b1,
    float* __restrict__ x2) {
  int node = (blockIdx.x << 4) + (threadIdx.x >> 4);
  if (node >= NN) return;
  int lane = threadIdx.x & 15;
  int head = lane >> 1;                 // 2 lanes per head (16 ch)
  float aD = adn[node * 8 + head];
  int p = rp[node], p1 = rp[node + 1];
  float a0 = 0, a1 = 0, a2 = 0, a3 = 0, a4 = 0, a5 = 0, a6 = 0, a7 = 0;
  float den = 0.f;
  const uint4* h1v = (const uint4*)h1;  // row = 16 uint4s

  for (; p + 1 < p1; p += 2) {
    int s0 = col[p], s1 = col[p + 1];
    float e0 = asn[s0 * 8 + head] + aD;
    float e1 = asn[s1 * 8 + head] + aD;
    uint4 v0 = h1v[(size_t)s0 * 16 + lane];
    uint4 v1 = h1v[(size_t)s1 * 16 + lane];
    e0 = e0 > 0.f ? e0 : NEG * e0;
    e1 = e1 > 0.f ? e1 : NEG * e1;
    float ee0 = __expf(e0), ee1 = __expf(e1);
    a0 += ee0 * bflo(v0.x) + ee1 * bflo(v1.x);
    a1 += ee0 * bfhi(v0.x) + ee1 * bfhi(v1.x);
    a2 += ee0 * bflo(v0.y) + ee1 * bflo(v1.y);
    a3 += ee0 * bfhi(v0.y) + ee1 * bfhi(v1.y);
    a4 += ee0 * bflo(v0.z) + ee1 * bflo(v1.z);
    a5 += ee0 * bfhi(v0.z) + ee1 * bfhi(v1.z);
    a6 += ee0 * bflo(v0.w) + ee1 * bflo(v1.w);
    a7 += ee0 * bfhi(v0.w) + ee1 * bfhi(v1.w);
    den += ee0 + ee1;
  }
  if (p < p1) {
    int s0 = col[p];
    float e0 = asn[s0 * 8 + head] + aD;
    uint4 v0 = h1v[(size_t)s0 * 16 + lane];
    e0 = e0 > 0.f ? e0 : NEG * e0;
    float ee0 = __expf(e0);
    a0 += ee0 * bflo(v0.x); a1 += ee0 * bfhi(v0.x);
    a2 += ee0 * bflo(v0.y); a3 += ee0 * bfhi(v0.y);
    a4 += ee0 * bflo(v0.z); a5 += ee0 * bfhi(v0.z);
    a6 += ee0 * bflo(v0.w); a7 += ee0 * bfhi(v0.w);
    den += ee0;
  }
  float inv = 1.f / den;
  const float4* b4 = (const float4*)b1;
  float4 ba = b4[lane * 2 + 0], bb = b4[lane * 2 + 1];
  float o0 = fmaf(a0, inv, ba.x), o1 = fmaf(a1, inv, ba.y);
  float o2 = fmaf(a2, inv, ba.z), o3 = fmaf(a3, inv, ba.w);
  float o4 = fmaf(a4, inv, bb.x), o5 = fmaf(a5, inv, bb.y);
  float o6 = fmaf(a6, inv, bb.z), o7 = fmaf(a7, inv, bb.w);
  o0 = o0 > 0.f ? o0 : __expf(o0) - 1.f;
  o1 = o1 > 0.f ? o1 : __expf(o1) - 1.f;
  o2 = o2 > 0.f ? o2 : __expf(o2) - 1.f;
  o3 = o3 > 0.f ? o3 : __expf(o3) - 1.f;
  o4 = o4 > 0.f ? o4 : __expf(o4) - 1.f;
  o5 = o5 > 0.f ? o5 : __expf(o5) - 1.f;
  o6 = o6 > 0.f ? o6 : __expf(o6) - 1.f;
  o7 = o7 > 0.f ? o7 : __expf(o7) - 1.f;
  float4 r0 = {o0, o1, o2, o3};
  float4 r1 = {o4, o5, o6, o7};
  float4* xr = (float4*)(x2 + (size_t)node * F1);
  xr[lane * 2 + 0] = r0;
  xr[lane * 2 + 1] = r1;
}

// ------ layer-2 gather: 16 lanes/node, 4 ch/lane (uint2) + log_softmax ------
__global__ __launch_bounds__(256) void gather2_kernel(
    const int* __restrict__ rp, const int* __restrict__ col,
    const float* __restrict__ asn, const float* __restrict__ adn,
    const ushort_t* __restrict__ h2, const float* __restrict__ b2,
    float* __restrict__ out) {
  int node = (blockIdx.x << 4) + (threadIdx.x >> 4);
  if (node >= NN) return;
  int lane = threadIdx.x & 15;
  float aD = adn[node];
  int p = rp[node], p1 = rp[node + 1];
  float a0 = 0, a1 = 0, a2 = 0, a3 = 0, den = 0.f;
  const uint2* h2v = (const uint2*)h2;  // row = 16 uint2s

  for (; p + 1 < p1; p += 2) {
    int s0 = col[p], s1 = col[p + 1];
    float e0 = asn[s0] + aD;
    float e1 = asn[s1] + aD;
    uint2 v0 = h2v[(size_t)s0 * 16 + lane];
    uint2 v1 = h2v[(size_t)s1 * 16 + lane];
    e0 = e0 > 0.f ? e0 : NEG * e0;
    e1 = e1 > 0.f ? e1 : NEG * e1;
    float ee0 = __expf(e0), ee1 = __expf(e1);
    a0 += ee0 * bflo(v0.x) + ee1 * bflo(v1.x);
    a1 += ee0 * bfhi(v0.x) + ee1 * bfhi(v1.x);
    a2 += ee0 * bflo(v0.y) + ee1 * bflo(v1.y);
    a3 += ee0 * bfhi(v0.y) + ee1 * bfhi(v1.y);
    den += ee0 + ee1;
  }
  if (p < p1) {
    int s0 = col[p];
    float e0 = asn[s0] + aD;
    uint2 v0 = h2v[(size_t)s0 * 16 + lane];
    e0 = e0 > 0.f ? e0 : NEG * e0;
    float ee0 = __expf(e0);
    a0 += ee0 * bflo(v0.x); a1 += ee0 * bfhi(v0.x);
    a2 += ee0 * bflo(v0.y); a3 += ee0 * bfhi(v0.y);
    den += ee0;
  }
  float inv = 1.f / den;
  float4 bv = ((const float4*)b2)[lane];
  float v0 = fmaf(a0, inv, bv.x), v1 = fmaf(a1, inv, bv.y);
  float v2 = fmaf(a2, inv, bv.z), v3 = fmaf(a3, inv, bv.w);
  float m = fmaxf(fmaxf(v0, v1), fmaxf(v2, v3));
#pragma unroll
  for (int k = 1; k < 16; k <<= 1) m = fmaxf(m, __shfl_xor(m, k));
  float ex = __expf(v0 - m) + __expf(v1 - m) + __expf(v2 - m) + __expf(v3 - m);
#pragma unroll
  for (int k = 1; k < 16; k <<= 1) ex += __shfl_xor(ex, k);
  float lse = m + __logf(ex);
  float4 r = {v0 - lse, v1 - lse, v2 - lse, v3 - lse};
  ((float4*)(out + (size_t)node * NC))[lane] = r;
}

extern "C" void kernel_launch(void* const* d_in, const int* in_sizes, int n_in,
                              void* d_out, int out_size, void* d_ws,
                              size_t ws_size, hipStream_t stream) {
  const float* x = (const float*)d_in[0];
  const int* edge_index = (const int*)d_in[1];
  const float* W1 = (const float*)d_in[2];
  const float* a_src1 = (const float*)d_in[3];
  const float* a_dst1 = (const float*)d_in[4];
  const float* b1 = (const float*)d_in[5];
  const float* W2 = (const float*)d_in[6];
  const float* a_src2 = (const float*)d_in[7];
  const float* a_dst2 = (const float*)d_in[8];
  const float* b2 = (const float*)d_in[9];
  float* out = (float*)d_out;
  float* ws = (float*)d_ws;

  // workspace layout (in floats):
  ushort_t* h1b = (ushort_t*)ws;         // 12.8M bf16 = 6.4M floats (h1 / h2)
  float* x2 = ws + 6400000;              // 12.8M floats (post-ELU l1 output)
  float* asn1 = x2 + 12800000;           // 800k
  float* adn1 = asn1 + 800000;           // 800k
  float* asn2 = adn1 + 800000;           // 100k
  float* adn2 = asn2 + 100000;           // 100k
  int* rp = (int*)(adn2 + 100000);       // NN+1
  int* col = rp + NN + 1;                // EN
  int* staging = col + EN;               // EN
  int* cnt = staging + EN;               // NBUK*NBLK = 50176
  int* bucket_base = cnt + NBUK * NBLK;  // NBUK+1

  const int* srcA = edge_index;
  const int* dstA = edge_index + NE;

  // ---- CSR build (multisplit, per-node src-sorted) ----
  bucket_count_kernel<<<NBLK, 512, 0, stream>>>(dstA, cnt);
  bucket_scan_kernel<<<1, 256, 0, stream>>>(cnt, bucket_base);
  bucket_scatter_kernel<<<NBLK, 512, 0, stream>>>(srcA, dstA, cnt, staging);
  bucket_csr_kernel<<<NBUK, 512, 0, stream>>>(staging, bucket_base, rp, col);

  // ---- layer 1 ----
  sgemm_bf16out_kernel<128, F1><<<(NN + 127) / 128, 256, 0, stream>>>(x, W1,
                                                                      h1b, NN);
  attn1_kernel<<<(NN * 64 + 255) / 256, 256, 0, stream>>>(h1b, a_src1, a_dst1,
                                                          asn1, adn1);
  gather1_kernel<<<(NN + 15) / 16, 256, 0, stream>>>(rp, col, asn1, adn1, h1b,
                                                     b1, x2);
  // ---- layer 2 ----
  ushort_t* h2b = h1b;  // h1 dead after gather1
  sgemm_bf16out_kernel<256, NC><<<(NN + 255) / 256, 256, 0, stream>>>(x2, W2,
                                                                      h2b, NN);
  attn2_kernel<<<(NN * 64 + 255) / 256, 256, 0, stream>>>(h2b, a_src2, a_dst2,
                                                          asn2, adn2);
  gather2_kernel<<<(NN + 15) / 16, 256, 0, stream>>>(rp, col, asn2, adn2, h2b,
                                                     b2, out);
}

// Round 8
// 304.754 us; speedup vs baseline: 1.1781x; 1.1781x over previous
//
#include <hip/hip_runtime.h>

#define NN 100000
#define NE 1600000
#define EN (NE + NN)          // edges incl. self-loops
#define FIN 128
#define H1 8
#define C1 16
#define F1 128                // H1*C1
#define NC 64
#define NEG 0.2f

// ---- CSR-build multisplit parameters ----
#define BSH 9                 // bucket = dst >> BSH
#define BKN 512               // nodes per bucket
#define NBUK ((NN + BKN - 1) / BKN)   // 196
#define NBLK 256              // edge-chunk blocks for P1/P2
#define CHUNK ((EN + NBLK - 1) / NBLK) // 6641
#define CAPB 12288            // LDS col capacity per bucket

typedef unsigned short ushort_t;
typedef unsigned int uint_t;
typedef __attribute__((ext_vector_type(8))) short short8v;
typedef __attribute__((ext_vector_type(4))) float f32x4;

union U8 { ushort_t u[8]; short8v v; uint4 q; };

__device__ __forceinline__ ushort_t f2bf(float f) {
  uint_t u = __builtin_bit_cast(uint_t, f);
  u += 0x7FFF + ((u >> 16) & 1);  // RNE
  return (ushort_t)(u >> 16);
}
__device__ __forceinline__ float bflo(uint_t u) {
  return __builtin_bit_cast(float, u << 16);
}
__device__ __forceinline__ float bfhi(uint_t u) {
  return __builtin_bit_cast(float, u & 0xFFFF0000u);
}
__device__ __forceinline__ float bf2f(ushort_t s) {
  return __builtin_bit_cast(float, (uint_t)s << 16);
}

// ---------- MFMA GEMM1: H[n,128] = bf16(X[n,128]) @ bf16(W1[128,128]) --------
// 256 thr = 4 waves; block tile 128 rows x 128 cols; wave = 32-row stripe.
// A: fp32 global -> bf16 in-register. B: W transposed to LDS bf16 once.
__global__ __launch_bounds__(256) void mfma_gemm1_kernel(
    const float* __restrict__ X, const float* __restrict__ W,
    ushort_t* __restrict__ H, int nrows) {
  __shared__ ushort_t Wt[128][136];  // [col][k], +8 pad
  const int tid = threadIdx.x;
  for (int i = tid; i < 128 * 128; i += 256) {
    int k = i >> 7, n = i & 127;
    Wt[n][k] = f2bf(W[i]);
  }
  __syncthreads();
  const int wave = tid >> 6, lane = tid & 63;
  const int row0 = blockIdx.x * 128 + wave * 32;
  const int rlo = lane & 15, khi = lane >> 4;  // khi in 0..3

  f32x4 acc[2][8];
#pragma unroll
  for (int m = 0; m < 2; ++m)
#pragma unroll
    for (int n = 0; n < 8; ++n) acc[m][n] = (f32x4){0.f, 0.f, 0.f, 0.f};

#pragma unroll
  for (int ks = 0; ks < 4; ++ks) {
    const int kk = ks * 32 + khi * 8;
    short8v a[2];
#pragma unroll
    for (int m = 0; m < 2; ++m) {
      int row = row0 + m * 16 + rlo;
      if (row >= nrows) row = nrows - 1;
      const float4* xp = (const float4*)(X + (size_t)row * 128 + kk);
      float4 u = xp[0], v = xp[1];
      U8 t;
      t.u[0] = f2bf(u.x); t.u[1] = f2bf(u.y); t.u[2] = f2bf(u.z); t.u[3] = f2bf(u.w);
      t.u[4] = f2bf(v.x); t.u[5] = f2bf(v.y); t.u[6] = f2bf(v.z); t.u[7] = f2bf(v.w);
      a[m] = t.v;
    }
#pragma unroll
    for (int nf = 0; nf < 8; ++nf) {
      short8v b = *(const short8v*)&Wt[nf * 16 + rlo][kk];
#pragma unroll
      for (int m = 0; m < 2; ++m)
        acc[m][nf] = __builtin_amdgcn_mfma_f32_16x16x32_bf16(a[m], b,
                                                             acc[m][nf], 0, 0, 0);
    }
  }
  // C/D layout: col = lane&15, row = (lane>>4)*4 + reg  [m89-verified]
#pragma unroll
  for (int m = 0; m < 2; ++m) {
    int rbase = row0 + m * 16 + khi * 4;
#pragma unroll
    for (int r = 0; r < 4; ++r) {
      int row = rbase + r;
      if (row >= nrows) continue;
      ushort_t* hp = H + (size_t)row * 128 + rlo;
#pragma unroll
      for (int nf = 0; nf < 8; ++nf) hp[nf * 16] = f2bf(acc[m][nf][r]);
    }
  }
}

// ---------- MFMA GEMM2: H[n,64] = X2bf16[n,128] @ bf16(W2[128,64]) -----------
__global__ __launch_bounds__(256) void mfma_gemm2_kernel(
    const ushort_t* __restrict__ X2, const float* __restrict__ W,
    ushort_t* __restrict__ H, int nrows) {
  __shared__ ushort_t Wt[64][136];
  const int tid = threadIdx.x;
  for (int i = tid; i < 128 * 64; i += 256) {
    int k = i >> 6, n = i & 63;
    Wt[n][k] = f2bf(W[i]);
  }
  __syncthreads();
  const int wave = tid >> 6, lane = tid & 63;
  const int row0 = blockIdx.x * 128 + wave * 32;
  const int rlo = lane & 15, khi = lane >> 4;

  f32x4 acc[2][4];
#pragma unroll
  for (int m = 0; m < 2; ++m)
#pragma unroll
    for (int n = 0; n < 4; ++n) acc[m][n] = (f32x4){0.f, 0.f, 0.f, 0.f};

#pragma unroll
  for (int ks = 0; ks < 4; ++ks) {
    const int kk = ks * 32 + khi * 8;
    short8v a[2];
#pragma unroll
    for (int m = 0; m < 2; ++m) {
      int row = row0 + m * 16 + rlo;
      if (row >= nrows) row = nrows - 1;
      U8 t;
      t.q = *(const uint4*)(X2 + (size_t)row * 128 + kk);
      a[m] = t.v;
    }
#pragma unroll
    for (int nf = 0; nf < 4; ++nf) {
      short8v b = *(const short8v*)&Wt[nf * 16 + rlo][kk];
#pragma unroll
      for (int m = 0; m < 2; ++m)
        acc[m][nf] = __builtin_amdgcn_mfma_f32_16x16x32_bf16(a[m], b,
                                                             acc[m][nf], 0, 0, 0);
    }
  }
#pragma unroll
  for (int m = 0; m < 2; ++m) {
    int rbase = row0 + m * 16 + khi * 4;
#pragma unroll
    for (int r = 0; r < 4; ++r) {
      int row = rbase + r;
      if (row >= nrows) continue;
      ushort_t* hp = H + (size_t)row * 64 + rlo;
#pragma unroll
      for (int nf = 0; nf < 4; ++nf) hp[nf * 16] = f2bf(acc[m][nf][r]);
    }
  }
}

// ------------- layer-1 per-node attention terms: asn/adn [N,8] ---------------
__global__ void attn1_kernel(const ushort_t* __restrict__ h1,
                             const float* __restrict__ a_src,
                             const float* __restrict__ a_dst,
                             float* __restrict__ asn, float* __restrict__ adn) {
  int wid = (blockIdx.x * blockDim.x + threadIdx.x) >> 6;
  int lane = threadIdx.x & 63;
  if (wid >= NN) return;
  uint_t hv = ((const uint_t*)(h1 + (size_t)wid * F1))[lane];
  float hx = bflo(hv);
  float hy = bfhi(hv);
  float2 as = ((const float2*)a_src)[lane];
  float2 ad = ((const float2*)a_dst)[lane];
  float s = hx * as.x + hy * as.y;
  float d = hx * ad.x + hy * ad.y;
  s += __shfl_xor(s, 1); s += __shfl_xor(s, 2); s += __shfl_xor(s, 4);
  d += __shfl_xor(d, 1); d += __shfl_xor(d, 2); d += __shfl_xor(d, 4);
  if ((lane & 7) == 0) {
    asn[wid * 8 + (lane >> 3)] = s;
    adn[wid * 8 + (lane >> 3)] = d;
  }
}

// ------------- layer-2 per-node attention terms: asn/adn [N] -----------------
__global__ void attn2_kernel(const ushort_t* __restrict__ h2,
                             const float* __restrict__ a_src,
                             const float* __restrict__ a_dst,
                             float* __restrict__ asn, float* __restrict__ adn) {
  int wid = (blockIdx.x * blockDim.x + threadIdx.x) >> 6;
  int lane = threadIdx.x & 63;
  if (wid >= NN) return;
  float h = bf2f(h2[(size_t)wid * NC + lane]);
  float s = h * a_src[lane];
  float d = h * a_dst[lane];
#pragma unroll
  for (int m = 1; m < 64; m <<= 1) { s += __shfl_xor(s, m); d += __shfl_xor(d, m); }
  if (lane == 0) { asn[wid] = s; adn[wid] = d; }
}

// ------------------ CSR build: two-level multisplit by dst -------------------
__global__ __launch_bounds__(512) void bucket_count_kernel(
    const int* __restrict__ dstA, int* __restrict__ cnt) {
  __shared__ int histL[NBUK];
  int b = blockIdx.x, t = threadIdx.x;
  for (int i = t; i < NBUK; i += 512) histL[i] = 0;
  __syncthreads();
  int e0 = b * CHUNK, e1 = min(e0 + CHUNK, EN);
  for (int e = e0 + t; e < e1; e += 512) {
    int d = (e < NE) ? dstA[e] : (e - NE);
    atomicAdd(&histL[d >> BSH], 1);
  }
  __syncthreads();
  for (int i = t; i < NBUK; i += 512) cnt[i * NBLK + b] = histL[i];
}

__global__ __launch_bounds__(256) void bucket_scan_kernel(
    int* __restrict__ cnt, int* __restrict__ bucket_base) {
  __shared__ int colsum[NBUK];
  int t = threadIdx.x;
  if (t < NBUK) {
    int run = 0;
    int* c = cnt + t * NBLK;
    for (int b = 0; b < NBLK; ++b) { int v = c[b]; c[b] = run; run += v; }
    colsum[t] = run;
  }
  __syncthreads();
  if (t == 0) {
    int base = 0;
    for (int j = 0; j < NBUK; ++j) {
      bucket_base[j] = base;
      int v = colsum[j];
      colsum[j] = base;
      base += v;
    }
    bucket_base[NBUK] = base;  // == EN
  }
  __syncthreads();
  if (t < NBUK) {
    int bb = colsum[t];
    int* c = cnt + t * NBLK;
    for (int b = 0; b < NBLK; ++b) c[b] += bb;
  }
}

__global__ __launch_bounds__(512) void bucket_scatter_kernel(
    const int* __restrict__ srcA, const int* __restrict__ dstA,
    const int* __restrict__ cnt, int* __restrict__ staging) {
  __shared__ int cur[NBUK];
  int b = blockIdx.x, t = threadIdx.x;
  for (int i = t; i < NBUK; i += 512) cur[i] = cnt[i * NBLK + b];
  __syncthreads();
  int e0 = b * CHUNK, e1 = min(e0 + CHUNK, EN);
  for (int e = e0 + t; e < e1; e += 512) {
    int s, d;
    if (e < NE) { s = srcA[e]; d = dstA[e]; } else { s = e - NE; d = s; }
    int pos = atomicAdd(&cur[d >> BSH], 1);
    staging[pos] = s | ((d & (BKN - 1)) << 17);
  }
}

// P3: per-bucket fine CSR in LDS; each node's edge list sorted by src.
__global__ __launch_bounds__(512) void bucket_csr_kernel(
    const int* __restrict__ staging, const int* __restrict__ bucket_base,
    int* __restrict__ rp, int* __restrict__ col) {
  __shared__ int degL[BKN];
  __shared__ int exclL[BKN];
  __shared__ int sdata[2][BKN];
  __shared__ int colL[CAPB];
  int bk = blockIdx.x, t = threadIdx.x;
  int ebase = bucket_base[bk], eend = bucket_base[bk + 1];
  int ecnt = eend - ebase;
  bool fits = (ecnt <= CAPB);
  degL[t] = 0;
  __syncthreads();
  for (int e = t; e < ecnt; e += 512)
    atomicAdd(&degL[staging[ebase + e] >> 17], 1);
  __syncthreads();
  int v = degL[t];
  sdata[0][t] = v;
  __syncthreads();
  int sp = 0;
  for (int off = 1; off < BKN; off <<= 1) {
    int val = sdata[sp][t];
    if (t >= off) val += sdata[sp][t - off];
    sdata[sp ^ 1][t] = val;
    __syncthreads();
    sp ^= 1;
  }
  int ex = sdata[sp][t] - v;  // local exclusive offset
  exclL[t] = ex;
  int node = bk * BKN + t;
  if (node < NN) rp[node] = ebase + ex;
  if (bk == 0 && t == 0) rp[NN] = EN;
  __syncthreads();
  if (fits) {
    for (int e = t; e < ecnt; e += 512) {
      int pk = staging[ebase + e];
      int pos = atomicAdd(&exclL[pk >> 17], 1);
      colL[pos] = pk & 0x1FFFF;
    }
    __syncthreads();
    for (int i = ex + 1; i < ex + v; ++i) {
      int key = colL[i];
      int j = i - 1;
      while (j >= ex && colL[j] > key) { colL[j + 1] = colL[j]; --j; }
      colL[j + 1] = key;
    }
    __syncthreads();
    for (int e = t; e < ecnt; e += 512) col[ebase + e] = colL[e];
  } else {
    for (int e = t; e < ecnt; e += 512) {
      int pk = staging[ebase + e];
      int pos = atomicAdd(&exclL[pk >> 17], 1);
      col[ebase + pos] = pk & 0x1FFFF;
    }
  }
}

// ------ layer-1 gather: 16 lanes/node, 8 ch/lane (uint4); bf16 x2 out --------
__global__ __launch_bounds__(256) void gather1_kernel(
    const int* __restrict__ rp, const int* __restrict__ col,
    const float* __restrict__ asn, const float* __restrict__ adn,
    const ushort_t* __restrict__ h1, const float* __restrict__ b1,
    ushort_t* __restrict__ x2) {
  int node = (blockIdx.x << 4) + (threadIdx.x >> 4);
  if (node >= NN) return;
  int lane = threadIdx.x & 15;
  int head = lane >> 1;
  float aD = adn[node * 8 + head];
  int p = rp[node], p1 = rp[node + 1];
  float a0 = 0, a1 = 0, a2 = 0, a3 = 0, a4 = 0, a5 = 0, a6 = 0, a7 = 0;
  float den = 0.f;
  const uint4* h1v = (const uint4*)h1;

  for (; p + 1 < p1; p += 2) {
    int s0 = col[p], s1 = col[p + 1];
    float e0 = asn[s0 * 8 + head] + aD;
    float e1 = asn[s1 * 8 + head] + aD;
    uint4 v0 = h1v[(size_t)s0 * 16 + lane];
    uint4 v1 = h1v[(size_t)s1 * 16 + lane];
    e0 = e0 > 0.f ? e0 : NEG * e0;
    e1 = e1 > 0.f ? e1 : NEG * e1;
    float ee0 = __expf(e0), ee1 = __expf(e1);
    a0 += ee0 * bflo(v0.x) + ee1 * bflo(v1.x);
    a1 += ee0 * bfhi(v0.x) + ee1 * bfhi(v1.x);
    a2 += ee0 * bflo(v0.y) + ee1 * bflo(v1.y);
    a3 += ee0 * bfhi(v0.y) + ee1 * bfhi(v1.y);
    a4 += ee0 * bflo(v0.z) + ee1 * bflo(v1.z);
    a5 += ee0 * bfhi(v0.z) + ee1 * bfhi(v1.z);
    a6 += ee0 * bflo(v0.w) + ee1 * bflo(v1.w);
    a7 += ee0 * bfhi(v0.w) + ee1 * bfhi(v1.w);
    den += ee0 + ee1;
  }
  if (p < p1) {
    int s0 = col[p];
    float e0 = asn[s0 * 8 + head] + aD;
    uint4 v0 = h1v[(size_t)s0 * 16 + lane];
    e0 = e0 > 0.f ? e0 : NEG * e0;
    float ee0 = __expf(e0);
    a0 += ee0 * bflo(v0.x); a1 += ee0 * bfhi(v0.x);
    a2 += ee0 * bflo(v0.y); a3 += ee0 * bfhi(v0.y);
    a4 += ee0 * bflo(v0.z); a5 += ee0 * bfhi(v0.z);
    a6 += ee0 * bflo(v0.w); a7 += ee0 * bfhi(v0.w);
    den += ee0;
  }
  float inv = 1.f / den;
  const float4* b4 = (const float4*)b1;
  float4 ba = b4[lane * 2 + 0], bb = b4[lane * 2 + 1];
  float o0 = fmaf(a0, inv, ba.x), o1 = fmaf(a1, inv, ba.y);
  float o2 = fmaf(a2, inv, ba.z), o3 = fmaf(a3, inv, ba.w);
  float o4 = fmaf(a4, inv, bb.x), o5 = fmaf(a5, inv, bb.y);
  float o6 = fmaf(a6, inv, bb.z), o7 = fmaf(a7, inv, bb.w);
  o0 = o0 > 0.f ? o0 : __expf(o0) - 1.f;
  o1 = o1 > 0.f ? o1 : __expf(o1) - 1.f;
  o2 = o2 > 0.f ? o2 : __expf(o2) - 1.f;
  o3 = o3 > 0.f ? o3 : __expf(o3) - 1.f;
  o4 = o4 > 0.f ? o4 : __expf(o4) - 1.f;
  o5 = o5 > 0.f ? o5 : __expf(o5) - 1.f;
  o6 = o6 > 0.f ? o6 : __expf(o6) - 1.f;
  o7 = o7 > 0.f ? o7 : __expf(o7) - 1.f;
  U8 t;
  t.u[0] = f2bf(o0); t.u[1] = f2bf(o1); t.u[2] = f2bf(o2); t.u[3] = f2bf(o3);
  t.u[4] = f2bf(o4); t.u[5] = f2bf(o5); t.u[6] = f2bf(o6); t.u[7] = f2bf(o7);
  ((uint4*)(x2 + (size_t)node * F1))[lane] = t.q;
}

// ------ layer-2 gather: 16 lanes/node, 4 ch/lane (uint2) + log_softmax ------
__global__ __launch_bounds__(256) void gather2_kernel(
    const int* __restrict__ rp, const int* __restrict__ col,
    const float* __restrict__ asn, const float* __restrict__ adn,
    const ushort_t* __restrict__ h2, const float* __restrict__ b2,
    float* __restrict__ out) {
  int node = (blockIdx.x << 4) + (threadIdx.x >> 4);
  if (node >= NN) return;
  int lane = threadIdx.x & 15;
  float aD = adn[node];
  int p = rp[node], p1 = rp[node + 1];
  float a0 = 0, a1 = 0, a2 = 0, a3 = 0, den = 0.f;
  const uint2* h2v = (const uint2*)h2;

  for (; p + 1 < p1; p += 2) {
    int s0 = col[p], s1 = col[p + 1];
    float e0 = asn[s0] + aD;
    float e1 = asn[s1] + aD;
    uint2 v0 = h2v[(size_t)s0 * 16 + lane];
    uint2 v1 = h2v[(size_t)s1 * 16 + lane];
    e0 = e0 > 0.f ? e0 : NEG * e0;
    e1 = e1 > 0.f ? e1 : NEG * e1;
    float ee0 = __expf(e0), ee1 = __expf(e1);
    a0 += ee0 * bflo(v0.x) + ee1 * bflo(v1.x);
    a1 += ee0 * bfhi(v0.x) + ee1 * bfhi(v1.x);
    a2 += ee0 * bflo(v0.y) + ee1 * bflo(v1.y);
    a3 += ee0 * bfhi(v0.y) + ee1 * bfhi(v1.y);
    den += ee0 + ee1;
  }
  if (p < p1) {
    int s0 = col[p];
    float e0 = asn[s0] + aD;
    uint2 v0 = h2v[(size_t)s0 * 16 + lane];
    e0 = e0 > 0.f ? e0 : NEG * e0;
    float ee0 = __expf(e0);
    a0 += ee0 * bflo(v0.x); a1 += ee0 * bfhi(v0.x);
    a2 += ee0 * bflo(v0.y); a3 += ee0 * bfhi(v0.y);
    den += ee0;
  }
  float inv = 1.f / den;
  float4 bv = ((const float4*)b2)[lane];
  float v0 = fmaf(a0, inv, bv.x), v1 = fmaf(a1, inv, bv.y);
  float v2 = fmaf(a2, inv, bv.z), v3 = fmaf(a3, inv, bv.w);
  float m = fmaxf(fmaxf(v0, v1), fmaxf(v2, v3));
#pragma unroll
  for (int k = 1; k < 16; k <<= 1) m = fmaxf(m, __shfl_xor(m, k));
  float ex = __expf(v0 - m) + __expf(v1 - m) + __expf(v2 - m) + __expf(v3 - m);
#pragma unroll
  for (int k = 1; k < 16; k <<= 1) ex += __shfl_xor(ex, k);
  float lse = m + __logf(ex);
  float4 r = {v0 - lse, v1 - lse, v2 - lse, v3 - lse};
  ((float4*)(out + (size_t)node * NC))[lane] = r;
}

extern "C" void kernel_launch(void* const* d_in, const int* in_sizes, int n_in,
                              void* d_out, int out_size, void* d_ws,
                              size_t ws_size, hipStream_t stream) {
  const float* x = (const float*)d_in[0];
  const int* edge_index = (const int*)d_in[1];
  const float* W1 = (const float*)d_in[2];
  const float* a_src1 = (const float*)d_in[3];
  const float* a_dst1 = (const float*)d_in[4];
  const float* b1 = (const float*)d_in[5];
  const float* W2 = (const float*)d_in[6];
  const float* a_src2 = (const float*)d_in[7];
  const float* a_dst2 = (const float*)d_in[8];
  const float* b2 = (const float*)d_in[9];
  float* out = (float*)d_out;
  float* ws = (float*)d_ws;

  // workspace layout (float offsets) — NON-overlapping (round-7 crash was an
  // overlap of x2b [6.4M,12.8M) with asn/rp/col):
  ushort_t* h1b = (ushort_t*)ws;               // [0, 6.4M)  12.8M bf16
  ushort_t* x2b = (ushort_t*)(ws + 6400000);   // [6.4M, 12.8M) 12.8M bf16
  float* asn1 = ws + 12800000;                 // [12.8M, 13.6M)
  float* adn1 = ws + 13600000;                 // [13.6M, 14.4M)
  float* asn2 = ws + 14400000;                 // [14.4M, 14.5M)
  float* adn2 = ws + 14500000;                 // [14.5M, 14.6M)
  int* rp = (int*)(ws + 14600000);             // NN+1
  int* col = rp + NN + 1;                      // EN
  int* staging = col + EN;                     // EN
  int* cnt = staging + EN;                     // NBUK*NBLK
  int* bucket_base = cnt + NBUK * NBLK;        // NBUK+1  (~18.2M floats total)

  const int* srcA = edge_index;
  const int* dstA = edge_index + NE;

  // ---- CSR build (multisplit, per-node src-sorted) ----
  bucket_count_kernel<<<NBLK, 512, 0, stream>>>(dstA, cnt);
  bucket_scan_kernel<<<1, 256, 0, stream>>>(cnt, bucket_base);
  bucket_scatter_kernel<<<NBLK, 512, 0, stream>>>(srcA, dstA, cnt, staging);
  bucket_csr_kernel<<<NBUK, 512, 0, stream>>>(staging, bucket_base, rp, col);

  // ---- layer 1 ----
  mfma_gemm1_kernel<<<(NN + 127) / 128, 256, 0, stream>>>(x, W1, h1b, NN);
  attn1_kernel<<<(NN * 64 + 255) / 256, 256, 0, stream>>>(h1b, a_src1, a_dst1,
                                                          asn1, adn1);
  gather1_kernel<<<(NN + 15) / 16, 256, 0, stream>>>(rp, col, asn1, adn1, h1b,
                                                     b1, x2b);
  // ---- layer 2 ----
  ushort_t* h2b = h1b;  // h1 dead after gather1
  mfma_gemm2_kernel<<<(NN + 127) / 128, 256, 0, stream>>>(x2b, W2, h2b, NN);
  attn2_kernel<<<(NN * 64 + 255) / 256, 256, 0, stream>>>(h2b, a_src2, a_dst2,
                                                          asn2, adn2);
  gather2_kernel<<<(NN + 15) / 16, 256, 0, stream>>>(rp, col, asn2, adn2, h2b,
                                                     b2, out);
}

// Round 9
// 286.282 us; speedup vs baseline: 1.2541x; 1.0645x over previous
//
#include <hip/hip_runtime.h>

#define NN 100000
#define NE 1600000
#define EN (NE + NN)          // edges incl. self-loops
#define FIN 128
#define H1 8
#define C1 16
#define F1 128                // H1*C1
#define NC 64
#define NEG 0.2f

// ---- CSR-build multisplit parameters ----
#define BSH 9                 // bucket = dst >> BSH
#define BKN 512               // nodes per bucket
#define NBUK ((NN + BKN - 1) / BKN)   // 196
#define NBLK 256              // edge-chunk blocks for P1/P2
#define CHUNK ((EN + NBLK - 1) / NBLK) // 6641
#define CAPB 12288            // LDS col capacity per bucket

typedef unsigned short ushort_t;
typedef unsigned int uint_t;
typedef __attribute__((ext_vector_type(8))) short short8v;
typedef __attribute__((ext_vector_type(4))) float f32x4;
typedef __attribute__((ext_vector_type(2))) float f32x2;

union U8 { ushort_t u[8]; short8v v; uint4 q; };

__device__ __forceinline__ ushort_t f2bf(float f) {
  uint_t u = __builtin_bit_cast(uint_t, f);
  u += 0x7FFF + ((u >> 16) & 1);  // RNE
  return (ushort_t)(u >> 16);
}
__device__ __forceinline__ float bflo(uint_t u) {
  return __builtin_bit_cast(float, u << 16);
}
__device__ __forceinline__ float bfhi(uint_t u) {
  return __builtin_bit_cast(float, u & 0xFFFF0000u);
}
__device__ __forceinline__ float bf2f(ushort_t s) {
  return __builtin_bit_cast(float, (uint_t)s << 16);
}

// ---------------- fp8 encode/decode (HW cvt preferred) -----------------------
#if __has_builtin(__builtin_amdgcn_cvt_pk_fp8_f32) && \
    __has_builtin(__builtin_amdgcn_cvt_pk_f32_fp8)
#define FP8_HW 1
__device__ __forceinline__ uint_t fp8_pack4(float f0, float f1, float f2,
                                            float f3) {
  int p = 0;
  p = __builtin_amdgcn_cvt_pk_fp8_f32(f0, f1, p, false);
  p = __builtin_amdgcn_cvt_pk_fp8_f32(f2, f3, p, true);
  return (uint_t)p;
}
__device__ __forceinline__ void fp8_unpack4(uint_t w, float* o) {
  f32x2 d0 = __builtin_amdgcn_cvt_pk_f32_fp8((int)w, false);
  f32x2 d1 = __builtin_amdgcn_cvt_pk_f32_fp8((int)w, true);
  o[0] = d0.x; o[1] = d0.y; o[2] = d1.x; o[3] = d1.y;
}
#else
// fallback: manual e4m3fn (RNE); slower but correct
__device__ __forceinline__ uint_t fp8_enc1(float f) {
  uint_t u = __builtin_bit_cast(uint_t, f);
  uint_t s = (u >> 24) & 0x80u;
  int e = (int)((u >> 23) & 0xFF) - 127;
  if (e < -9) return s;
  if (e < -6) {
    float af = __builtin_bit_cast(float, u & 0x7FFFFFFFu);
    uint_t m = (uint_t)(af * 512.f + 0.5f);
    return s | m;
  }
  uint_t mant = u & 0x7FFFFF;
  uint_t keep = mant >> 20;
  uint_t rest = mant & 0xFFFFF;
  keep += (rest > 0x80000u) || (rest == 0x80000u && (keep & 1));
  uint_t ee = (uint_t)(e + 7);
  if (keep == 8) { keep = 0; ee += 1; }
  if (ee > 15 || (ee == 15 && keep > 6)) return s | 0x7E;
  return s | (ee << 3) | keep;
}
__device__ __forceinline__ float fp8_dec1(uint_t b) {
  uint_t s = (b & 0x80u) << 24;
  uint_t e = (b >> 3) & 15u, m = b & 7u;
  if (e == 0) {
    float v = (float)m * (1.0f / 512.0f);
    return __builtin_bit_cast(float, s | __builtin_bit_cast(uint_t, v));
  }
  return __builtin_bit_cast(float, s | ((e + 120u) << 23) | (m << 20));
}
__device__ __forceinline__ uint_t fp8_pack4(float f0, float f1, float f2,
                                            float f3) {
  return fp8_enc1(f0) | (fp8_enc1(f1) << 8) | (fp8_enc1(f2) << 16) |
         (fp8_enc1(f3) << 24);
}
__device__ __forceinline__ void fp8_unpack4(uint_t w, float* o) {
  o[0] = fp8_dec1(w & 0xFF); o[1] = fp8_dec1((w >> 8) & 0xFF);
  o[2] = fp8_dec1((w >> 16) & 0xFF); o[3] = fp8_dec1(w >> 24);
}
#endif

// ---------- MFMA GEMM1: H[n,128] = bf16(X[n,128]) @ bf16(W1[128,128]) --------
__global__ __launch_bounds__(256) void mfma_gemm1_kernel(
    const float* __restrict__ X, const float* __restrict__ W,
    ushort_t* __restrict__ H, int nrows) {
  __shared__ ushort_t Wt[128][136];  // [col][k], +8 pad
  const int tid = threadIdx.x;
  for (int i = tid; i < 128 * 128; i += 256) {
    int k = i >> 7, n = i & 127;
    Wt[n][k] = f2bf(W[i]);
  }
  __syncthreads();
  const int wave = tid >> 6, lane = tid & 63;
  const int row0 = blockIdx.x * 128 + wave * 32;
  const int rlo = lane & 15, khi = lane >> 4;  // khi in 0..3

  f32x4 acc[2][8];
#pragma unroll
  for (int m = 0; m < 2; ++m)
#pragma unroll
    for (int n = 0; n < 8; ++n) acc[m][n] = (f32x4){0.f, 0.f, 0.f, 0.f};

#pragma unroll
  for (int ks = 0; ks < 4; ++ks) {
    const int kk = ks * 32 + khi * 8;
    short8v a[2];
#pragma unroll
    for (int m = 0; m < 2; ++m) {
      int row = row0 + m * 16 + rlo;
      if (row >= nrows) row = nrows - 1;
      const float4* xp = (const float4*)(X + (size_t)row * 128 + kk);
      float4 u = xp[0], v = xp[1];
      U8 t;
      t.u[0] = f2bf(u.x); t.u[1] = f2bf(u.y); t.u[2] = f2bf(u.z); t.u[3] = f2bf(u.w);
      t.u[4] = f2bf(v.x); t.u[5] = f2bf(v.y); t.u[6] = f2bf(v.z); t.u[7] = f2bf(v.w);
      a[m] = t.v;
    }
#pragma unroll
    for (int nf = 0; nf < 8; ++nf) {
      short8v b = *(const short8v*)&Wt[nf * 16 + rlo][kk];
#pragma unroll
      for (int m = 0; m < 2; ++m)
        acc[m][nf] = __builtin_amdgcn_mfma_f32_16x16x32_bf16(a[m], b,
                                                             acc[m][nf], 0, 0, 0);
    }
  }
  // C/D layout: col = lane&15, row = (lane>>4)*4 + reg  [m89-verified]
#pragma unroll
  for (int m = 0; m < 2; ++m) {
    int rbase = row0 + m * 16 + khi * 4;
#pragma unroll
    for (int r = 0; r < 4; ++r) {
      int row = rbase + r;
      if (row >= nrows) continue;
      ushort_t* hp = H + (size_t)row * 128 + rlo;
#pragma unroll
      for (int nf = 0; nf < 8; ++nf) hp[nf * 16] = f2bf(acc[m][nf][r]);
    }
  }
}

// ---------- MFMA GEMM2: H[n,64] = X2bf16[n,128] @ bf16(W2[128,64]) -----------
__global__ __launch_bounds__(256) void mfma_gemm2_kernel(
    const ushort_t* __restrict__ X2, const float* __restrict__ W,
    ushort_t* __restrict__ H, int nrows) {
  __shared__ ushort_t Wt[64][136];
  const int tid = threadIdx.x;
  for (int i = tid; i < 128 * 64; i += 256) {
    int k = i >> 6, n = i & 63;
    Wt[n][k] = f2bf(W[i]);
  }
  __syncthreads();
  const int wave = tid >> 6, lane = tid & 63;
  const int row0 = blockIdx.x * 128 + wave * 32;
  const int rlo = lane & 15, khi = lane >> 4;

  f32x4 acc[2][4];
#pragma unroll
  for (int m = 0; m < 2; ++m)
#pragma unroll
    for (int n = 0; n < 4; ++n) acc[m][n] = (f32x4){0.f, 0.f, 0.f, 0.f};

#pragma unroll
  for (int ks = 0; ks < 4; ++ks) {
    const int kk = ks * 32 + khi * 8;
    short8v a[2];
#pragma unroll
    for (int m = 0; m < 2; ++m) {
      int row = row0 + m * 16 + rlo;
      if (row >= nrows) row = nrows - 1;
      U8 t;
      t.q = *(const uint4*)(X2 + (size_t)row * 128 + kk);
      a[m] = t.v;
    }
#pragma unroll
    for (int nf = 0; nf < 4; ++nf) {
      short8v b = *(const short8v*)&Wt[nf * 16 + rlo][kk];
#pragma unroll
      for (int m = 0; m < 2; ++m)
        acc[m][nf] = __builtin_amdgcn_mfma_f32_16x16x32_bf16(a[m], b,
                                                             acc[m][nf], 0, 0, 0);
    }
  }
#pragma unroll
  for (int m = 0; m < 2; ++m) {
    int rbase = row0 + m * 16 + khi * 4;
#pragma unroll
    for (int r = 0; r < 4; ++r) {
      int row = rbase + r;
      if (row >= nrows) continue;
      ushort_t* hp = H + (size_t)row * 64 + rlo;
#pragma unroll
      for (int nf = 0; nf < 4; ++nf) hp[nf * 16] = f2bf(acc[m][nf][r]);
    }
  }
}

// ------------- h1 bf16 -> fp8 copy (gather payload) --------------------------
__global__ __launch_bounds__(256) void h1_fp8_kernel(
    const ushort_t* __restrict__ h1, uint2* __restrict__ h8) {
  int i = blockIdx.x * 256 + threadIdx.x;  // one uint2 (8 ch) per thread
  if (i >= NN * F1 / 8) return;
  uint4 v = ((const uint4*)h1)[i];
  uint2 r;
  r.x = fp8_pack4(bflo(v.x), bfhi(v.x), bflo(v.y), bfhi(v.y));
  r.y = fp8_pack4(bflo(v.z), bfhi(v.z), bflo(v.w), bfhi(v.w));
  h8[i] = r;
}

// ------------- layer-1 per-node attention terms: asn/adn [N,8] ---------------
__global__ void attn1_kernel(const ushort_t* __restrict__ h1,
                             const float* __restrict__ a_src,
                             const float* __restrict__ a_dst,
                             float* __restrict__ asn, float* __restrict__ adn) {
  int wid = (blockIdx.x * blockDim.x + threadIdx.x) >> 6;
  int lane = threadIdx.x & 63;
  if (wid >= NN) return;
  uint_t hv = ((const uint_t*)(h1 + (size_t)wid * F1))[lane];
  float hx = bflo(hv);
  float hy = bfhi(hv);
  float2 as = ((const float2*)a_src)[lane];
  float2 ad = ((const float2*)a_dst)[lane];
  float s = hx * as.x + hy * as.y;
  float d = hx * ad.x + hy * ad.y;
  s += __shfl_xor(s, 1); s += __shfl_xor(s, 2); s += __shfl_xor(s, 4);
  d += __shfl_xor(d, 1); d += __shfl_xor(d, 2); d += __shfl_xor(d, 4);
  if ((lane & 7) == 0) {
    asn[wid * 8 + (lane >> 3)] = s;
    adn[wid * 8 + (lane >> 3)] = d;
  }
}

// ------------- layer-2 per-node attention terms: asn/adn [N] -----------------
__global__ void attn2_kernel(const ushort_t* __restrict__ h2,
                             const float* __restrict__ a_src,
                             const float* __restrict__ a_dst,
                             float* __restrict__ asn, float* __restrict__ adn) {
  int wid = (blockIdx.x * blockDim.x + threadIdx.x) >> 6;
  int lane = threadIdx.x & 63;
  if (wid >= NN) return;
  float h = bf2f(h2[(size_t)wid * NC + lane]);
  float s = h * a_src[lane];
  float d = h * a_dst[lane];
#pragma unroll
  for (int m = 1; m < 64; m <<= 1) { s += __shfl_xor(s, m); d += __shfl_xor(d, m); }
  if (lane == 0) { asn[wid] = s; adn[wid] = d; }
}

// ------------------ CSR build: two-level multisplit by dst -------------------
__global__ __launch_bounds__(512) void bucket_count_kernel(
    const int* __restrict__ dstA, int* __restrict__ cnt) {
  __shared__ int histL[NBUK];
  int b = blockIdx.x, t = threadIdx.x;
  for (int i = t; i < NBUK; i += 512) histL[i] = 0;
  __syncthreads();
  int e0 = b * CHUNK, e1 = min(e0 + CHUNK, EN);
  for (int e = e0 + t; e < e1; e += 512) {
    int d = (e < NE) ? dstA[e] : (e - NE);
    atomicAdd(&histL[d >> BSH], 1);
  }
  __syncthreads();
  for (int i = t; i < NBUK; i += 512) cnt[i * NBLK + b] = histL[i];
}

__global__ __launch_bounds__(256) void bucket_scan_kernel(
    int* __restrict__ cnt, int* __restrict__ bucket_base) {
  __shared__ int colsum[NBUK];
  int t = threadIdx.x;
  if (t < NBUK) {
    int run = 0;
    int* c = cnt + t * NBLK;
    for (int b = 0; b < NBLK; ++b) { int v = c[b]; c[b] = run; run += v; }
    colsum[t] = run;
  }
  __syncthreads();
  if (t == 0) {
    int base = 0;
    for (int j = 0; j < NBUK; ++j) {
      bucket_base[j] = base;
      int v = colsum[j];
      colsum[j] = base;
      base += v;
    }
    bucket_base[NBUK] = base;  // == EN
  }
  __syncthreads();
  if (t < NBUK) {
    int bb = colsum[t];
    int* c = cnt + t * NBLK;
    for (int b = 0; b < NBLK; ++b) c[b] += bb;
  }
}

__global__ __launch_bounds__(512) void bucket_scatter_kernel(
    const int* __restrict__ srcA, const int* __restrict__ dstA,
    const int* __restrict__ cnt, int* __restrict__ staging) {
  __shared__ int cur[NBUK];
  int b = blockIdx.x, t = threadIdx.x;
  for (int i = t; i < NBUK; i += 512) cur[i] = cnt[i * NBLK + b];
  __syncthreads();
  int e0 = b * CHUNK, e1 = min(e0 + CHUNK, EN);
  for (int e = e0 + t; e < e1; e += 512) {
    int s, d;
    if (e < NE) { s = srcA[e]; d = dstA[e]; } else { s = e - NE; d = s; }
    int pos = atomicAdd(&cur[d >> BSH], 1);
    staging[pos] = s | ((d & (BKN - 1)) << 17);
  }
}

// P3: per-bucket fine CSR in LDS; each node's edge list sorted by src.
__global__ __launch_bounds__(512) void bucket_csr_kernel(
    const int* __restrict__ staging, const int* __restrict__ bucket_base,
    int* __restrict__ rp, int* __restrict__ col) {
  __shared__ int degL[BKN];
  __shared__ int exclL[BKN];
  __shared__ int sdata[2][BKN];
  __shared__ int colL[CAPB];
  int bk = blockIdx.x, t = threadIdx.x;
  int ebase = bucket_base[bk], eend = bucket_base[bk + 1];
  int ecnt = eend - ebase;
  bool fits = (ecnt <= CAPB);
  degL[t] = 0;
  __syncthreads();
  for (int e = t; e < ecnt; e += 512)
    atomicAdd(&degL[staging[ebase + e] >> 17], 1);
  __syncthreads();
  int v = degL[t];
  sdata[0][t] = v;
  __syncthreads();
  int sp = 0;
  for (int off = 1; off < BKN; off <<= 1) {
    int val = sdata[sp][t];
    if (t >= off) val += sdata[sp][t - off];
    sdata[sp ^ 1][t] = val;
    __syncthreads();
    sp ^= 1;
  }
  int ex = sdata[sp][t] - v;  // local exclusive offset
  exclL[t] = ex;
  int node = bk * BKN + t;
  if (node < NN) rp[node] = ebase + ex;
  if (bk == 0 && t == 0) rp[NN] = EN;
  __syncthreads();
  if (fits) {
    for (int e = t; e < ecnt; e += 512) {
      int pk = staging[ebase + e];
      int pos = atomicAdd(&exclL[pk >> 17], 1);
      colL[pos] = pk & 0x1FFFF;
    }
    __syncthreads();
    for (int i = ex + 1; i < ex + v; ++i) {
      int key = colL[i];
      int j = i - 1;
      while (j >= ex && colL[j] > key) { colL[j + 1] = colL[j]; --j; }
      colL[j + 1] = key;
    }
    __syncthreads();
    for (int e = t; e < ecnt; e += 512) col[ebase + e] = colL[e];
  } else {
    for (int e = t; e < ecnt; e += 512) {
      int pk = staging[ebase + e];
      int pos = atomicAdd(&exclL[pk >> 17], 1);
      col[ebase + pos] = pk & 0x1FFFF;
    }
  }
}

// ------ layer-1 gather: 16 lanes/node, 8 ch/lane, fp8 h1 payload -------------
__global__ __launch_bounds__(256) void gather1_kernel(
    const int* __restrict__ rp, const int* __restrict__ col,
    const float* __restrict__ asn, const float* __restrict__ adn,
    const uint2* __restrict__ h8, const float* __restrict__ b1,
    ushort_t* __restrict__ x2) {
  int node = (blockIdx.x << 4) + (threadIdx.x >> 4);
  if (node >= NN) return;
  int lane = threadIdx.x & 15;
  int head = lane >> 1;
  float aD = adn[node * 8 + head];
  int p = rp[node], p1 = rp[node + 1];
  float a0 = 0, a1 = 0, a2 = 0, a3 = 0, a4 = 0, a5 = 0, a6 = 0, a7 = 0;
  float den = 0.f;

  for (; p + 1 < p1; p += 2) {
    int s0 = col[p], s1 = col[p + 1];
    float e0 = asn[s0 * 8 + head] + aD;
    float e1 = asn[s1 * 8 + head] + aD;
    uint2 q0 = h8[(size_t)s0 * 16 + lane];
    uint2 q1 = h8[(size_t)s1 * 16 + lane];
    e0 = e0 > 0.f ? e0 : NEG * e0;
    e1 = e1 > 0.f ? e1 : NEG * e1;
    float ee0 = __expf(e0), ee1 = __expf(e1);
    float d0[4], d1[4], d2[4], d3[4];
    fp8_unpack4(q0.x, d0); fp8_unpack4(q0.y, d1);
    fp8_unpack4(q1.x, d2); fp8_unpack4(q1.y, d3);
    a0 += ee0 * d0[0] + ee1 * d2[0];
    a1 += ee0 * d0[1] + ee1 * d2[1];
    a2 += ee0 * d0[2] + ee1 * d2[2];
    a3 += ee0 * d0[3] + ee1 * d2[3];
    a4 += ee0 * d1[0] + ee1 * d3[0];
    a5 += ee0 * d1[1] + ee1 * d3[1];
    a6 += ee0 * d1[2] + ee1 * d3[2];
    a7 += ee0 * d1[3] + ee1 * d3[3];
    den += ee0 + ee1;
  }
  if (p < p1) {
    int s0 = col[p];
    float e0 = asn[s0 * 8 + head] + aD;
    uint2 q0 = h8[(size_t)s0 * 16 + lane];
    e0 = e0 > 0.f ? e0 : NEG * e0;
    float ee0 = __expf(e0);
    float d0[4], d1[4];
    fp8_unpack4(q0.x, d0); fp8_unpack4(q0.y, d1);
    a0 += ee0 * d0[0]; a1 += ee0 * d0[1]; a2 += ee0 * d0[2]; a3 += ee0 * d0[3];
    a4 += ee0 * d1[0]; a5 += ee0 * d1[1]; a6 += ee0 * d1[2]; a7 += ee0 * d1[3];
    den += ee0;
  }
  float inv = 1.f / den;
  const float4* b4 = (const float4*)b1;
  float4 ba = b4[lane * 2 + 0], bb = b4[lane * 2 + 1];
  float o0 = fmaf(a0, inv, ba.x), o1 = fmaf(a1, inv, ba.y);
  float o2 = fmaf(a2, inv, ba.z), o3 = fmaf(a3, inv, ba.w);
  float o4 = fmaf(a4, inv, bb.x), o5 = fmaf(a5, inv, bb.y);
  float o6 = fmaf(a6, inv, bb.z), o7 = fmaf(a7, inv, bb.w);
  o0 = o0 > 0.f ? o0 : __expf(o0) - 1.f;
  o1 = o1 > 0.f ? o1 : __expf(o1) - 1.f;
  o2 = o2 > 0.f ? o2 : __expf(o2) - 1.f;
  o3 = o3 > 0.f ? o3 : __expf(o3) - 1.f;
  o4 = o4 > 0.f ? o4 : __expf(o4) - 1.f;
  o5 = o5 > 0.f ? o5 : __expf(o5) - 1.f;
  o6 = o6 > 0.f ? o6 : __expf(o6) - 1.f;
  o7 = o7 > 0.f ? o7 : __expf(o7) - 1.f;
  U8 t;
  t.u[0] = f2bf(o0); t.u[1] = f2bf(o1); t.u[2] = f2bf(o2); t.u[3] = f2bf(o3);
  t.u[4] = f2bf(o4); t.u[5] = f2bf(o5); t.u[6] = f2bf(o6); t.u[7] = f2bf(o7);
  ((uint4*)(x2 + (size_t)node * F1))[lane] = t.q;
}

// ------ layer-2 gather: 16 lanes/node, 4 ch/lane (uint2) + log_softmax ------
__global__ __launch_bounds__(256) void gather2_kernel(
    const int* __restrict__ rp, const int* __restrict__ col,
    const float* __restrict__ asn, const float* __restrict__ adn,
    const ushort_t* __restrict__ h2, const float* __restrict__ b2,
    float* __restrict__ out) {
  int node = (blockIdx.x << 4) + (threadIdx.x >> 4);
  if (node >= NN) return;
  int lane = threadIdx.x & 15;
  float aD = adn[node];
  int p = rp[node], p1 = rp[node + 1];
  float a0 = 0, a1 = 0, a2 = 0, a3 = 0, den = 0.f;
  const uint2* h2v = (const uint2*)h2;

  for (; p + 1 < p1; p += 2) {
    int s0 = col[p], s1 = col[p + 1];
    float e0 = asn[s0] + aD;
    float e1 = asn[s1] + aD;
    uint2 v0 = h2v[(size_t)s0 * 16 + lane];
    uint2 v1 = h2v[(size_t)s1 * 16 + lane];
    e0 = e0 > 0.f ? e0 : NEG * e0;
    e1 = e1 > 0.f ? e1 : NEG * e1;
    float ee0 = __expf(e0), ee1 = __expf(e1);
    a0 += ee0 * bflo(v0.x) + ee1 * bflo(v1.x);
    a1 += ee0 * bfhi(v0.x) + ee1 * bfhi(v1.x);
    a2 += ee0 * bflo(v0.y) + ee1 * bflo(v1.y);
    a3 += ee0 * bfhi(v0.y) + ee1 * bfhi(v1.y);
    den += ee0 + ee1;
  }
  if (p < p1) {
    int s0 = col[p];
    float e0 = asn[s0] + aD;
    uint2 v0 = h2v[(size_t)s0 * 16 + lane];
    e0 = e0 > 0.f ? e0 : NEG * e0;
    float ee0 = __expf(e0);
    a0 += ee0 * bflo(v0.x); a1 += ee0 * bfhi(v0.x);
    a2 += ee0 * bflo(v0.y); a3 += ee0 * bfhi(v0.y);
    den += ee0;
  }
  float inv = 1.f / den;
  float4 bv = ((const float4*)b2)[lane];
  float v0 = fmaf(a0, inv, bv.x), v1 = fmaf(a1, inv, bv.y);
  float v2 = fmaf(a2, inv, bv.z), v3 = fmaf(a3, inv, bv.w);
  float m = fmaxf(fmaxf(v0, v1), fmaxf(v2, v3));
#pragma unroll
  for (int k = 1; k < 16; k <<= 1) m = fmaxf(m, __shfl_xor(m, k));
  float ex = __expf(v0 - m) + __expf(v1 - m) + __expf(v2 - m) + __expf(v3 - m);
#pragma unroll
  for (int k = 1; k < 16; k <<= 1) ex += __shfl_xor(ex, k);
  float lse = m + __logf(ex);
  float4 r = {v0 - lse, v1 - lse, v2 - lse, v3 - lse};
  ((float4*)(out + (size_t)node * NC))[lane] = r;
}

extern "C" void kernel_launch(void* const* d_in, const int* in_sizes, int n_in,
                              void* d_out, int out_size, void* d_ws,
                              size_t ws_size, hipStream_t stream) {
  const float* x = (const float*)d_in[0];
  const int* edge_index = (const int*)d_in[1];
  const float* W1 = (const float*)d_in[2];
  const float* a_src1 = (const float*)d_in[3];
  const float* a_dst1 = (const float*)d_in[4];
  const float* b1 = (const float*)d_in[5];
  const float* W2 = (const float*)d_in[6];
  const float* a_src2 = (const float*)d_in[7];
  const float* a_dst2 = (const float*)d_in[8];
  const float* b2 = (const float*)d_in[9];
  float* out = (float*)d_out;
  float* ws = (float*)d_ws;

  // workspace layout (float offsets), non-overlapping:
  ushort_t* h1b = (ushort_t*)ws;               // [0, 6.4M)   bf16 h1 / h2
  ushort_t* x2b = (ushort_t*)(ws + 6400000);   // [6.4M, 12.8M) bf16 x2
  uint2* h8 = (uint2*)(ws + 12800000);         // [12.8M, 16.0M) fp8 h1
  float* asn1 = ws + 16000000;                 // [16.0M, 16.8M)
  float* adn1 = ws + 16800000;                 // [16.8M, 17.6M)
  float* asn2 = ws + 17600000;                 // [17.6M, 17.7M)
  float* adn2 = ws + 17700000;                 // [17.7M, 17.8M)
  int* rp = (int*)(ws + 17800000);             // NN+1
  int* col = rp + NN + 1;                      // EN
  int* staging = col + EN;                     // EN
  int* cnt = staging + EN;                     // NBUK*NBLK
  int* bucket_base = cnt + NBUK * NBLK;        // NBUK+1  (~21.4M floats)

  const int* srcA = edge_index;
  const int* dstA = edge_index + NE;

  // ---- CSR build (multisplit, per-node src-sorted) ----
  bucket_count_kernel<<<NBLK, 512, 0, stream>>>(dstA, cnt);
  bucket_scan_kernel<<<1, 256, 0, stream>>>(cnt, bucket_base);
  bucket_scatter_kernel<<<NBLK, 512, 0, stream>>>(srcA, dstA, cnt, staging);
  bucket_csr_kernel<<<NBUK, 512, 0, stream>>>(staging, bucket_base, rp, col);

  // ---- layer 1 ----
  mfma_gemm1_kernel<<<(NN + 127) / 128, 256, 0, stream>>>(x, W1, h1b, NN);
  h1_fp8_kernel<<<(NN * F1 / 8 + 255) / 256, 256, 0, stream>>>(h1b, h8);
  attn1_kernel<<<(NN * 64 + 255) / 256, 256, 0, stream>>>(h1b, a_src1, a_dst1,
                                                          asn1, adn1);
  gather1_kernel<<<(NN + 15) / 16, 256, 0, stream>>>(rp, col, asn1, adn1, h8,
                                                     b1, x2b);
  // ---- layer 2 ----
  ushort_t* h2b = h1b;  // h1 bf16 dead after attn1/h1_fp8
  mfma_gemm2_kernel<<<(NN + 127) / 128, 256, 0, stream>>>(x2b, W2, h2b, NN);
  attn2_kernel<<<(NN * 64 + 255) / 256, 256, 0, stream>>>(h2b, a_src2, a_dst2,
                                                          asn2, adn2);
  gather2_kernel<<<(NN + 15) / 16, 256, 0, stream>>>(rp, col, asn2, adn2, h2b,
                                                     b2, out);
}

// Round 11
// 248.010 us; speedup vs baseline: 1.4476x; 1.1543x over previous
//
#include <hip/hip_runtime.h>

#define NN 100000
#define NE 1600000
#define EN (NE + NN)          // edges incl. self-loops
#define FIN 128
#define H1 8
#define C1 16
#define F1 128                // H1*C1
#define NC 64
#define NEG 0.2f

// ---- CSR-build multisplit parameters ----
#define BSH 9                 // bucket = dst >> BSH
#define BKN 512               // nodes per bucket
#define NBUK ((NN + BKN - 1) / BKN)   // 196
#define NBLK 256              // edge-chunk blocks for P1/P2
#define CHUNK ((EN + NBLK - 1) / NBLK) // 6641

typedef unsigned short ushort_t;
typedef unsigned int uint_t;
typedef __attribute__((ext_vector_type(8))) short short8v;
typedef __attribute__((ext_vector_type(4))) float f32x4;
typedef __attribute__((ext_vector_type(2))) float f32x2;

union U8 { ushort_t u[8]; short8v v; uint4 q; };

__device__ __forceinline__ ushort_t f2bf(float f) {
  uint_t u = __builtin_bit_cast(uint_t, f);
  u += 0x7FFF + ((u >> 16) & 1);  // RNE
  return (ushort_t)(u >> 16);
}
__device__ __forceinline__ float bflo(uint_t u) {
  return __builtin_bit_cast(float, u << 16);
}
__device__ __forceinline__ float bfhi(uint_t u) {
  return __builtin_bit_cast(float, u & 0xFFFF0000u);
}
__device__ __forceinline__ float bf2f(ushort_t s) {
  return __builtin_bit_cast(float, (uint_t)s << 16);
}

// ---------------- fp8 encode/decode (HW cvt preferred) -----------------------
#if __has_builtin(__builtin_amdgcn_cvt_pk_fp8_f32) && \
    __has_builtin(__builtin_amdgcn_cvt_pk_f32_fp8)
__device__ __forceinline__ uint_t fp8_pack4(float f0, float f1, float f2,
                                            float f3) {
  int p = 0;
  p = __builtin_amdgcn_cvt_pk_fp8_f32(f0, f1, p, false);
  p = __builtin_amdgcn_cvt_pk_fp8_f32(f2, f3, p, true);
  return (uint_t)p;
}
__device__ __forceinline__ void fp8_unpack4(uint_t w, float* o) {
  f32x2 d0 = __builtin_amdgcn_cvt_pk_f32_fp8((int)w, false);
  f32x2 d1 = __builtin_amdgcn_cvt_pk_f32_fp8((int)w, true);
  o[0] = d0.x; o[1] = d0.y; o[2] = d1.x; o[3] = d1.y;
}
#else
__device__ __forceinline__ uint_t fp8_enc1(float f) {
  uint_t u = __builtin_bit_cast(uint_t, f);
  uint_t s = (u >> 24) & 0x80u;
  int e = (int)((u >> 23) & 0xFF) - 127;
  if (e < -9) return s;
  if (e < -6) {
    float af = __builtin_bit_cast(float, u & 0x7FFFFFFFu);
    uint_t m = (uint_t)(af * 512.f + 0.5f);
    return s | m;
  }
  uint_t mant = u & 0x7FFFFF;
  uint_t keep = mant >> 20;
  uint_t rest = mant & 0xFFFFF;
  keep += (rest > 0x80000u) || (rest == 0x80000u && (keep & 1));
  uint_t ee = (uint_t)(e + 7);
  if (keep == 8) { keep = 0; ee += 1; }
  if (ee > 15 || (ee == 15 && keep > 6)) return s | 0x7E;
  return s | (ee << 3) | keep;
}
__device__ __forceinline__ float fp8_dec1(uint_t b) {
  uint_t s = (b & 0x80u) << 24;
  uint_t e = (b >> 3) & 15u, m = b & 7u;
  if (e == 0) {
    float v = (float)m * (1.0f / 512.0f);
    return __builtin_bit_cast(float, s | __builtin_bit_cast(uint_t, v));
  }
  return __builtin_bit_cast(float, s | ((e + 120u) << 23) | (m << 20));
}
__device__ __forceinline__ uint_t fp8_pack4(float f0, float f1, float f2,
                                            float f3) {
  return fp8_enc1(f0) | (fp8_enc1(f1) << 8) | (fp8_enc1(f2) << 16) |
         (fp8_enc1(f3) << 24);
}
__device__ __forceinline__ void fp8_unpack4(uint_t w, float* o) {
  o[0] = fp8_dec1(w & 0xFF); o[1] = fp8_dec1((w >> 8) & 0xFF);
  o[2] = fp8_dec1((w >> 16) & 0xFF); o[3] = fp8_dec1(w >> 24);
}
#endif

// ---------- MFMA GEMM1: H[n,128] = bf16(X[n,128]) @ bf16(W1[128,128]) --------
__global__ __launch_bounds__(256) void mfma_gemm1_kernel(
    const float* __restrict__ X, const float* __restrict__ W,
    ushort_t* __restrict__ H, int nrows) {
  __shared__ ushort_t Wt[128][136];  // [col][k], +8 pad
  const int tid = threadIdx.x;
  for (int i = tid; i < 128 * 128; i += 256) {
    int k = i >> 7, n = i & 127;
    Wt[n][k] = f2bf(W[i]);
  }
  __syncthreads();
  const int wave = tid >> 6, lane = tid & 63;
  const int row0 = blockIdx.x * 128 + wave * 32;
  const int rlo = lane & 15, khi = lane >> 4;  // khi in 0..3

  f32x4 acc[2][8];
#pragma unroll
  for (int m = 0; m < 2; ++m)
#pragma unroll
    for (int n = 0; n < 8; ++n) acc[m][n] = (f32x4){0.f, 0.f, 0.f, 0.f};

#pragma unroll
  for (int ks = 0; ks < 4; ++ks) {
    const int kk = ks * 32 + khi * 8;
    short8v a[2];
#pragma unroll
    for (int m = 0; m < 2; ++m) {
      int row = row0 + m * 16 + rlo;
      if (row >= nrows) row = nrows - 1;
      const float4* xp = (const float4*)(X + (size_t)row * 128 + kk);
      float4 u = xp[0], v = xp[1];
      U8 t;
      t.u[0] = f2bf(u.x); t.u[1] = f2bf(u.y); t.u[2] = f2bf(u.z); t.u[3] = f2bf(u.w);
      t.u[4] = f2bf(v.x); t.u[5] = f2bf(v.y); t.u[6] = f2bf(v.z); t.u[7] = f2bf(v.w);
      a[m] = t.v;
    }
#pragma unroll
    for (int nf = 0; nf < 8; ++nf) {
      short8v b = *(const short8v*)&Wt[nf * 16 + rlo][kk];
#pragma unroll
      for (int m = 0; m < 2; ++m)
        acc[m][nf] = __builtin_amdgcn_mfma_f32_16x16x32_bf16(a[m], b,
                                                             acc[m][nf], 0, 0, 0);
    }
  }
  // C/D layout: col = lane&15, row = (lane>>4)*4 + reg  [m89-verified]
#pragma unroll
  for (int m = 0; m < 2; ++m) {
    int rbase = row0 + m * 16 + khi * 4;
#pragma unroll
    for (int r = 0; r < 4; ++r) {
      int row = rbase + r;
      if (row >= nrows) continue;
      ushort_t* hp = H + (size_t)row * 128 + rlo;
#pragma unroll
      for (int nf = 0; nf < 8; ++nf) hp[nf * 16] = f2bf(acc[m][nf][r]);
    }
  }
}

// ---------- MFMA GEMM2: H[n,64] = X2bf16[n,128] @ bf16(W2[128,64]) -----------
__global__ __launch_bounds__(256) void mfma_gemm2_kernel(
    const ushort_t* __restrict__ X2, const float* __restrict__ W,
    ushort_t* __restrict__ H, int nrows) {
  __shared__ ushort_t Wt[64][136];
  const int tid = threadIdx.x;
  for (int i = tid; i < 128 * 64; i += 256) {
    int k = i >> 6, n = i & 63;
    Wt[n][k] = f2bf(W[i]);
  }
  __syncthreads();
  const int wave = tid >> 6, lane = tid & 63;
  const int row0 = blockIdx.x * 128 + wave * 32;
  const int rlo = lane & 15, khi = lane >> 4;

  f32x4 acc[2][4];
#pragma unroll
  for (int m = 0; m < 2; ++m)
#pragma unroll
    for (int n = 0; n < 4; ++n) acc[m][n] = (f32x4){0.f, 0.f, 0.f, 0.f};

#pragma unroll
  for (int ks = 0; ks < 4; ++ks) {
    const int kk = ks * 32 + khi * 8;
    short8v a[2];
#pragma unroll
    for (int m = 0; m < 2; ++m) {
      int row = row0 + m * 16 + rlo;
      if (row >= nrows) row = nrows - 1;
      U8 t;
      t.q = *(const uint4*)(X2 + (size_t)row * 128 + kk);
      a[m] = t.v;
    }
#pragma unroll
    for (int nf = 0; nf < 4; ++nf) {
      short8v b = *(const short8v*)&Wt[nf * 16 + rlo][kk];
#pragma unroll
      for (int m = 0; m < 2; ++m)
        acc[m][nf] = __builtin_amdgcn_mfma_f32_16x16x32_bf16(a[m], b,
                                                             acc[m][nf], 0, 0, 0);
    }
  }
#pragma unroll
  for (int m = 0; m < 2; ++m) {
    int rbase = row0 + m * 16 + khi * 4;
#pragma unroll
    for (int r = 0; r < 4; ++r) {
      int row = rbase + r;
      if (row >= nrows) continue;
      ushort_t* hp = H + (size_t)row * 64 + rlo;
#pragma unroll
      for (int nf = 0; nf < 4; ++nf) hp[nf * 16] = f2bf(acc[m][nf][r]);
    }
  }
}

// ------------- h1 bf16 -> fp8 copy (gather payload, linear layout) -----------
__global__ __launch_bounds__(256) void h1_fp8_kernel(
    const ushort_t* __restrict__ h1, uint2* __restrict__ h8) {
  int i = blockIdx.x * 256 + threadIdx.x;  // one uint2 (8 ch) per thread
  if (i >= NN * F1 / 8) return;
  uint4 v = ((const uint4*)h1)[i];
  uint2 r;
  r.x = fp8_pack4(bflo(v.x), bfhi(v.x), bflo(v.y), bfhi(v.y));
  r.y = fp8_pack4(bflo(v.z), bfhi(v.z), bflo(v.w), bfhi(v.w));
  h8[i] = r;
}

// ------------- layer-1 per-node attention terms: asn/adn [N,8] ---------------
__global__ void attn1_kernel(const ushort_t* __restrict__ h1,
                             const float* __restrict__ a_src,
                             const float* __restrict__ a_dst,
                             float* __restrict__ asn, float* __restrict__ adn) {
  int wid = (blockIdx.x * blockDim.x + threadIdx.x) >> 6;
  int lane = threadIdx.x & 63;
  if (wid >= NN) return;
  uint_t hv = ((const uint_t*)(h1 + (size_t)wid * F1))[lane];
  float hx = bflo(hv);
  float hy = bfhi(hv);
  float2 as = ((const float2*)a_src)[lane];
  float2 ad = ((const float2*)a_dst)[lane];
  float s = hx * as.x + hy * as.y;
  float d = hx * ad.x + hy * ad.y;
  s += __shfl_xor(s, 1); s += __shfl_xor(s, 2); s += __shfl_xor(s, 4);
  d += __shfl_xor(d, 1); d += __shfl_xor(d, 2); d += __shfl_xor(d, 4);
  if ((lane & 7) == 0) {
    asn[wid * 8 + (lane >> 3)] = s;
    adn[wid * 8 + (lane >> 3)] = d;
  }
}

// ------------- layer-2 per-node attention terms: asn/adn [N] -----------------
__global__ void attn2_kernel(const ushort_t* __restrict__ h2,
                             const float* __restrict__ a_src,
                             const float* __restrict__ a_dst,
                             float* __restrict__ asn, float* __restrict__ adn) {
  int wid = (blockIdx.x * blockDim.x + threadIdx.x) >> 6;
  int lane = threadIdx.x & 63;
  if (wid >= NN) return;
  float h = bf2f(h2[(size_t)wid * NC + lane]);
  float s = h * a_src[lane];
  float d = h * a_dst[lane];
#pragma unroll
  for (int m = 1; m < 64; m <<= 1) { s += __shfl_xor(s, m); d += __shfl_xor(d, m); }
  if (lane == 0) { asn[wid] = s; adn[wid] = d; }
}

// ------------------ CSR build: two-level multisplit by dst -------------------
__global__ __launch_bounds__(512) void bucket_count_kernel(
    const int* __restrict__ dstA, int* __restrict__ cnt) {
  __shared__ int histL[NBUK];
  int b = blockIdx.x, t = threadIdx.x;
  for (int i = t; i < NBUK; i += 512) histL[i] = 0;
  __syncthreads();
  int e0 = b * CHUNK, e1 = min(e0 + CHUNK, EN);
  for (int e = e0 + t; e < e1; e += 512) {
    int d = (e < NE) ? dstA[e] : (e - NE);
    atomicAdd(&histL[d >> BSH], 1);
  }
  __syncthreads();
  for (int i = t; i < NBUK; i += 512) cnt[i * NBLK + b] = histL[i];
}

__global__ __launch_bounds__(256) void bucket_scan_kernel(
    int* __restrict__ cnt, int* __restrict__ bucket_base) {
  __shared__ int colsum[NBUK];
  int t = threadIdx.x;
  if (t < NBUK) {
    int run = 0;
    int* c = cnt + t * NBLK;
    for (int b = 0; b < NBLK; ++b) { int v = c[b]; c[b] = run; run += v; }
    colsum[t] = run;
  }
  __syncthreads();
  if (t == 0) {
    int base = 0;
    for (int j = 0; j < NBUK; ++j) {
      bucket_base[j] = base;
      int v = colsum[j];
      colsum[j] = base;
      base += v;
    }
    bucket_base[NBUK] = base;  // == EN
  }
  __syncthreads();
  if (t < NBUK) {
    int bb = colsum[t];
    int* c = cnt + t * NBLK;
    for (int b = 0; b < NBLK; ++b) c[b] += bb;
  }
}

__global__ __launch_bounds__(512) void bucket_scatter_kernel(
    const int* __restrict__ srcA, const int* __restrict__ dstA,
    const int* __restrict__ cnt, int* __restrict__ staging) {
  __shared__ int cur[NBUK];
  int b = blockIdx.x, t = threadIdx.x;
  for (int i = t; i < NBUK; i += 512) cur[i] = cnt[i * NBLK + b];
  __syncthreads();
  int e0 = b * CHUNK, e1 = min(e0 + CHUNK, EN);
  for (int e = e0 + t; e < e1; e += 512) {
    int s, d;
    if (e < NE) { s = srcA[e]; d = dstA[e]; } else { s = e - NE; d = s; }
    int pos = atomicAdd(&cur[d >> BSH], 1);
    staging[pos] = s | ((d & (BKN - 1)) << 17);
  }
}

// P3: per-bucket fine CSR: LDS histogram -> scan -> rp -> direct scatter.
// (insertion sort removed: cost 61us at 12.5% occupancy vs ~7% gather FETCH win)
__global__ __launch_bounds__(512) void bucket_csr_kernel(
    const int* __restrict__ staging, const int* __restrict__ bucket_base,
    int* __restrict__ rp, int* __restrict__ col) {
  __shared__ int degL[BKN];
  __shared__ int exclL[BKN];
  __shared__ int sdata[2][BKN];
  int bk = blockIdx.x, t = threadIdx.x;
  int ebase = bucket_base[bk], eend = bucket_base[bk + 1];
  int ecnt = eend - ebase;
  degL[t] = 0;
  __syncthreads();
  for (int e = t; e < ecnt; e += 512)
    atomicAdd(&degL[staging[ebase + e] >> 17], 1);
  __syncthreads();
  int v = degL[t];
  sdata[0][t] = v;
  __syncthreads();
  int sp = 0;
  for (int off = 1; off < BKN; off <<= 1) {
    int val = sdata[sp][t];
    if (t >= off) val += sdata[sp][t - off];
    sdata[sp ^ 1][t] = val;
    __syncthreads();
    sp ^= 1;
  }
  int ex = sdata[sp][t] - v;  // local exclusive offset
  exclL[t] = ex;
  int node = bk * BKN + t;
  if (node < NN) rp[node] = ebase + ex;
  if (bk == 0 && t == 0) rp[NN] = EN;
  __syncthreads();
  for (int e = t; e < ecnt; e += 512) {
    int pk = staging[ebase + e];
    int pos = atomicAdd(&exclL[pk >> 17], 1);
    col[ebase + pos] = pk & 0x1FFFF;
  }
}

// ------ layer-1 gather: 16 lanes/node, 8 ch/lane, fp8 h1 payload -------------
// linear layout: lane's uint2 covers channels 8*lane..8*lane+7 (head=lane>>1)
__global__ __launch_bounds__(256) void gather1_kernel(
    const int* __restrict__ rp, const int* __restrict__ col,
    const float* __restrict__ asn, const float* __restrict__ adn,
    const uint2* __restrict__ h8, const float* __restrict__ b1,
    ushort_t* __restrict__ x2) {
  int node = (blockIdx.x << 4) + (threadIdx.x >> 4);
  if (node >= NN) return;
  int lane = threadIdx.x & 15;
  int head = lane >> 1;
  float aD = adn[node * 8 + head];
  int p = rp[node], p1 = rp[node + 1];
  float a0 = 0, a1 = 0, a2 = 0, a3 = 0, a4 = 0, a5 = 0, a6 = 0, a7 = 0;
  float den = 0.f;

  for (; p + 1 < p1; p += 2) {
    int s0 = col[p], s1 = col[p + 1];
    float e0 = asn[s0 * 8 + head] + aD;
    float e1 = asn[s1 * 8 + head] + aD;
    uint2 q0 = h8[(size_t)s0 * 16 + lane];
    uint2 q1 = h8[(size_t)s1 * 16 + lane];
    e0 = e0 > 0.f ? e0 : NEG * e0;
    e1 = e1 > 0.f ? e1 : NEG * e1;
    float ee0 = __expf(e0), ee1 = __expf(e1);
    float d0[4], d1[4], d2[4], d3[4];
    fp8_unpack4(q0.x, d0); fp8_unpack4(q0.y, d1);
    fp8_unpack4(q1.x, d2); fp8_unpack4(q1.y, d3);
    a0 += ee0 * d0[0] + ee1 * d2[0];
    a1 += ee0 * d0[1] + ee1 * d2[1];
    a2 += ee0 * d0[2] + ee1 * d2[2];
    a3 += ee0 * d0[3] + ee1 * d2[3];
    a4 += ee0 * d1[0] + ee1 * d3[0];
    a5 += ee0 * d1[1] + ee1 * d3[1];
    a6 += ee0 * d1[2] + ee1 * d3[2];
    a7 += ee0 * d1[3] + ee1 * d3[3];
    den += ee0 + ee1;
  }
  if (p < p1) {
    int s0 = col[p];
    float e0 = asn[s0 * 8 + head] + aD;
    uint2 q0 = h8[(size_t)s0 * 16 + lane];
    e0 = e0 > 0.f ? e0 : NEG * e0;
    float ee0 = __expf(e0);
    float d0[4], d1[4];
    fp8_unpack4(q0.x, d0); fp8_unpack4(q0.y, d1);
    a0 += ee0 * d0[0]; a1 += ee0 * d0[1]; a2 += ee0 * d0[2]; a3 += ee0 * d0[3];
    a4 += ee0 * d1[0]; a5 += ee0 * d1[1]; a6 += ee0 * d1[2]; a7 += ee0 * d1[3];
    den += ee0;
  }
  float inv = 1.f / den;
  const float4* b4 = (const float4*)b1;
  float4 ba = b4[lane * 2 + 0], bb = b4[lane * 2 + 1];
  float o0 = fmaf(a0, inv, ba.x), o1 = fmaf(a1, inv, ba.y);
  float o2 = fmaf(a2, inv, ba.z), o3 = fmaf(a3, inv, ba.w);
  float o4 = fmaf(a4, inv, bb.x), o5 = fmaf(a5, inv, bb.y);
  float o6 = fmaf(a6, inv, bb.z), o7 = fmaf(a7, inv, bb.w);
  o0 = o0 > 0.f ? o0 : __expf(o0) - 1.f;
  o1 = o1 > 0.f ? o1 : __expf(o1) - 1.f;
  o2 = o2 > 0.f ? o2 : __expf(o2) - 1.f;
  o3 = o3 > 0.f ? o3 : __expf(o3) - 1.f;
  o4 = o4 > 0.f ? o4 : __expf(o4) - 1.f;
  o5 = o5 > 0.f ? o5 : __expf(o5) - 1.f;
  o6 = o6 > 0.f ? o6 : __expf(o6) - 1.f;
  o7 = o7 > 0.f ? o7 : __expf(o7) - 1.f;
  U8 t;
  t.u[0] = f2bf(o0); t.u[1] = f2bf(o1); t.u[2] = f2bf(o2); t.u[3] = f2bf(o3);
  t.u[4] = f2bf(o4); t.u[5] = f2bf(o5); t.u[6] = f2bf(o6); t.u[7] = f2bf(o7);
  ((uint4*)(x2 + (size_t)node * F1))[lane] = t.q;
}

// ------ layer-2 gather: 16 lanes/node, 4 ch/lane (uint2) + log_softmax ------
__global__ __launch_bounds__(256) void gather2_kernel(
    const int* __restrict__ rp, const int* __restrict__ col,
    const float* __restrict__ asn, const float* __restrict__ adn,
    const ushort_t* __restrict__ h2, const float* __restrict__ b2,
    float* __restrict__ out) {
  int node = (blockIdx.x << 4) + (threadIdx.x >> 4);
  if (node >= NN) return;
  int lane = threadIdx.x & 15;
  float aD = adn[node];
  int p = rp[node], p1 = rp[node + 1];
  float a0 = 0, a1 = 0, a2 = 0, a3 = 0, den = 0.f;
  const uint2* h2v = (const uint2*)h2;

  for (; p + 1 < p1; p += 2) {
    int s0 = col[p], s1 = col[p + 1];
    float e0 = asn[s0] + aD;
    float e1 = asn[s1] + aD;
    uint2 v0 = h2v[(size_t)s0 * 16 + lane];
    uint2 v1 = h2v[(size_t)s1 * 16 + lane];
    e0 = e0 > 0.f ? e0 : NEG * e0;
    e1 = e1 > 0.f ? e1 : NEG * e1;
    float ee0 = __expf(e0), ee1 = __expf(e1);
    a0 += ee0 * bflo(v0.x) + ee1 * bflo(v1.x);
    a1 += ee0 * bfhi(v0.x) + ee1 * bfhi(v1.x);
    a2 += ee0 * bflo(v0.y) + ee1 * bflo(v1.y);
    a3 += ee0 * bfhi(v0.y) + ee1 * bfhi(v1.y);
    den += ee0 + ee1;
  }
  if (p < p1) {
    int s0 = col[p];
    float e0 = asn[s0] + aD;
    uint2 v0 = h2v[(size_t)s0 * 16 + lane];
    e0 = e0 > 0.f ? e0 : NEG * e0;
    float ee0 = __expf(e0);
    a0 += ee0 * bflo(v0.x); a1 += ee0 * bfhi(v0.x);
    a2 += ee0 * bflo(v0.y); a3 += ee0 * bfhi(v0.y);
    den += ee0;
  }
  float inv = 1.f / den;
  float4 bv = ((const float4*)b2)[lane];
  float v0 = fmaf(a0, inv, bv.x), v1 = fmaf(a1, inv, bv.y);
  float v2 = fmaf(a2, inv, bv.z), v3 = fmaf(a3, inv, bv.w);
  float m = fmaxf(fmaxf(v0, v1), fmaxf(v2, v3));
#pragma unroll
  for (int k = 1; k < 16; k <<= 1) m = fmaxf(m, __shfl_xor(m, k));
  float ex = __expf(v0 - m) + __expf(v1 - m) + __expf(v2 - m) + __expf(v3 - m);
#pragma unroll
  for (int k = 1; k < 16; k <<= 1) ex += __shfl_xor(ex, k);
  float lse = m + __logf(ex);
  float4 r = {v0 - lse, v1 - lse, v2 - lse, v3 - lse};
  ((float4*)(out + (size_t)node * NC))[lane] = r;
}

extern "C" void kernel_launch(void* const* d_in, const int* in_sizes, int n_in,
                              void* d_out, int out_size, void* d_ws,
                              size_t ws_size, hipStream_t stream) {
  const float* x = (const float*)d_in[0];
  const int* edge_index = (const int*)d_in[1];
  const float* W1 = (const float*)d_in[2];
  const float* a_src1 = (const float*)d_in[3];
  const float* a_dst1 = (const float*)d_in[4];
  const float* b1 = (const float*)d_in[5];
  const float* W2 = (const float*)d_in[6];
  const float* a_src2 = (const float*)d_in[7];
  const float* a_dst2 = (const float*)d_in[8];
  const float* b2 = (const float*)d_in[9];
  float* out = (float*)d_out;
  float* ws = (float*)d_ws;

  // workspace layout (float offsets), non-overlapping:
  ushort_t* h1b = (ushort_t*)ws;               // [0, 6.4M)   bf16 h1 / h2
  ushort_t* x2b = (ushort_t*)(ws + 6400000);   // [6.4M, 12.8M) bf16 x2
  uint2* h8 = (uint2*)(ws + 12800000);         // [12.8M, 16.0M) fp8 h1
  float* asn1 = ws + 16000000;                 // [16.0M, 16.8M)
  float* adn1 = ws + 16800000;                 // [16.8M, 17.6M)
  float* asn2 = ws + 17600000;                 // [17.6M, 17.7M)
  float* adn2 = ws + 17700000;                 // [17.7M, 17.8M)
  int* rp = (int*)(ws + 17800000);             // NN+1
  int* col = rp + NN + 1;                      // EN
  int* staging = col + EN;                     // EN
  int* cnt = staging + EN;                     // NBUK*NBLK
  int* bucket_base = cnt + NBUK * NBLK;        // NBUK+1  (~21.4M floats)

  const int* srcA = edge_index;
  const int* dstA = edge_index + NE;

  // ---- CSR build (multisplit) ----
  bucket_count_kernel<<<NBLK, 512, 0, stream>>>(dstA, cnt);
  bucket_scan_kernel<<<1, 256, 0, stream>>>(cnt, bucket_base);
  bucket_scatter_kernel<<<NBLK, 512, 0, stream>>>(srcA, dstA, cnt, staging);
  bucket_csr_kernel<<<NBUK, 512, 0, stream>>>(staging, bucket_base, rp, col);

  // ---- layer 1 ----
  mfma_gemm1_kernel<<<(NN + 127) / 128, 256, 0, stream>>>(x, W1, h1b, NN);
  h1_fp8_kernel<<<(NN * F1 / 8 + 255) / 256, 256, 0, stream>>>(h1b, h8);
  attn1_kernel<<<(NN * 64 + 255) / 256, 256, 0, stream>>>(h1b, a_src1, a_dst1,
                                                          asn1, adn1);
  gather1_kernel<<<(NN + 15) / 16, 256, 0, stream>>>(rp, col, asn1, adn1, h8,
                                                     b1, x2b);
  // ---- layer 2 ----
  ushort_t* h2b = h1b;  // h1 bf16 dead after attn1/h1_fp8
  mfma_gemm2_kernel<<<(NN + 127) / 128, 256, 0, stream>>>(x2b, W2, h2b, NN);
  attn2_kernel<<<(NN * 64 + 255) / 256, 256, 0, stream>>>(h2b, a_src2, a_dst2,
                                                          asn2, adn2);
  gather2_kernel<<<(NN + 15) / 16, 256, 0, stream>>>(rp, col, asn2, adn2, h2b,
                                                     b2, out);
}

// Round 12
// 241.286 us; speedup vs baseline: 1.4880x; 1.0279x over previous
//
#include <hip/hip_runtime.h>

#define NN 100000
#define NE 1600000
#define EN (NE + NN)          // edges incl. self-loops
#define FIN 128
#define H1 8
#define C1 16
#define F1 128                // H1*C1
#define NC 64
#define NEG 0.2f

// ---- CSR-build multisplit parameters ----
#define BSH 9                 // bucket = dst >> BSH
#define BKN 512               // nodes per bucket
#define NBUK ((NN + BKN - 1) / BKN)   // 196
#define NBLK 256              // edge-chunk blocks for P1/P2
#define CHUNK ((EN + NBLK - 1) / NBLK) // 6641

typedef unsigned short ushort_t;
typedef unsigned int uint_t;
typedef __attribute__((ext_vector_type(8))) short short8v;
typedef __attribute__((ext_vector_type(4))) float f32x4;
typedef __attribute__((ext_vector_type(2))) float f32x2;

union U8 { ushort_t u[8]; short8v v; uint4 q; };

__device__ __forceinline__ ushort_t f2bf(float f) {
  uint_t u = __builtin_bit_cast(uint_t, f);
  u += 0x7FFF + ((u >> 16) & 1);  // RNE
  return (ushort_t)(u >> 16);
}
__device__ __forceinline__ float bflo(uint_t u) {
  return __builtin_bit_cast(float, u << 16);
}
__device__ __forceinline__ float bfhi(uint_t u) {
  return __builtin_bit_cast(float, u & 0xFFFF0000u);
}
__device__ __forceinline__ float bf2f(ushort_t s) {
  return __builtin_bit_cast(float, (uint_t)s << 16);
}

// ---------------- fp8 encode/decode (HW cvt preferred) -----------------------
#if __has_builtin(__builtin_amdgcn_cvt_pk_fp8_f32) && \
    __has_builtin(__builtin_amdgcn_cvt_pk_f32_fp8)
__device__ __forceinline__ uint_t fp8_pack4(float f0, float f1, float f2,
                                            float f3) {
  int p = 0;
  p = __builtin_amdgcn_cvt_pk_fp8_f32(f0, f1, p, false);
  p = __builtin_amdgcn_cvt_pk_fp8_f32(f2, f3, p, true);
  return (uint_t)p;
}
__device__ __forceinline__ void fp8_unpack4(uint_t w, float* o) {
  f32x2 d0 = __builtin_amdgcn_cvt_pk_f32_fp8((int)w, false);
  f32x2 d1 = __builtin_amdgcn_cvt_pk_f32_fp8((int)w, true);
  o[0] = d0.x; o[1] = d0.y; o[2] = d1.x; o[3] = d1.y;
}
#else
__device__ __forceinline__ uint_t fp8_enc1(float f) {
  uint_t u = __builtin_bit_cast(uint_t, f);
  uint_t s = (u >> 24) & 0x80u;
  int e = (int)((u >> 23) & 0xFF) - 127;
  if (e < -9) return s;
  if (e < -6) {
    float af = __builtin_bit_cast(float, u & 0x7FFFFFFFu);
    uint_t m = (uint_t)(af * 512.f + 0.5f);
    return s | m;
  }
  uint_t mant = u & 0x7FFFFF;
  uint_t keep = mant >> 20;
  uint_t rest = mant & 0xFFFFF;
  keep += (rest > 0x80000u) || (rest == 0x80000u && (keep & 1));
  uint_t ee = (uint_t)(e + 7);
  if (keep == 8) { keep = 0; ee += 1; }
  if (ee > 15 || (ee == 15 && keep > 6)) return s | 0x7E;
  return s | (ee << 3) | keep;
}
__device__ __forceinline__ float fp8_dec1(uint_t b) {
  uint_t s = (b & 0x80u) << 24;
  uint_t e = (b >> 3) & 15u, m = b & 7u;
  if (e == 0) {
    float v = (float)m * (1.0f / 512.0f);
    return __builtin_bit_cast(float, s | __builtin_bit_cast(uint_t, v));
  }
  return __builtin_bit_cast(float, s | ((e + 120u) << 23) | (m << 20));
}
__device__ __forceinline__ uint_t fp8_pack4(float f0, float f1, float f2,
                                            float f3) {
  return fp8_enc1(f0) | (fp8_enc1(f1) << 8) | (fp8_enc1(f2) << 16) |
         (fp8_enc1(f3) << 24);
}
__device__ __forceinline__ void fp8_unpack4(uint_t w, float* o) {
  o[0] = fp8_dec1(w & 0xFF); o[1] = fp8_dec1((w >> 8) & 0xFF);
  o[2] = fp8_dec1((w >> 16) & 0xFF); o[3] = fp8_dec1(w >> 24);
}
#endif

// ---------- MFMA GEMM1: H[n,128] = bf16(X[n,128]) @ bf16(W1[128,128]) --------
__global__ __launch_bounds__(256) void mfma_gemm1_kernel(
    const float* __restrict__ X, const float* __restrict__ W,
    ushort_t* __restrict__ H, int nrows) {
  __shared__ ushort_t Wt[128][136];  // [col][k], +8 pad
  const int tid = threadIdx.x;
  for (int i = tid; i < 128 * 128; i += 256) {
    int k = i >> 7, n = i & 127;
    Wt[n][k] = f2bf(W[i]);
  }
  __syncthreads();
  const int wave = tid >> 6, lane = tid & 63;
  const int row0 = blockIdx.x * 128 + wave * 32;
  const int rlo = lane & 15, khi = lane >> 4;  // khi in 0..3

  f32x4 acc[2][8];
#pragma unroll
  for (int m = 0; m < 2; ++m)
#pragma unroll
    for (int n = 0; n < 8; ++n) acc[m][n] = (f32x4){0.f, 0.f, 0.f, 0.f};

#pragma unroll
  for (int ks = 0; ks < 4; ++ks) {
    const int kk = ks * 32 + khi * 8;
    short8v a[2];
#pragma unroll
    for (int m = 0; m < 2; ++m) {
      int row = row0 + m * 16 + rlo;
      if (row >= nrows) row = nrows - 1;
      const float4* xp = (const float4*)(X + (size_t)row * 128 + kk);
      float4 u = xp[0], v = xp[1];
      U8 t;
      t.u[0] = f2bf(u.x); t.u[1] = f2bf(u.y); t.u[2] = f2bf(u.z); t.u[3] = f2bf(u.w);
      t.u[4] = f2bf(v.x); t.u[5] = f2bf(v.y); t.u[6] = f2bf(v.z); t.u[7] = f2bf(v.w);
      a[m] = t.v;
    }
#pragma unroll
    for (int nf = 0; nf < 8; ++nf) {
      short8v b = *(const short8v*)&Wt[nf * 16 + rlo][kk];
#pragma unroll
      for (int m = 0; m < 2; ++m)
        acc[m][nf] = __builtin_amdgcn_mfma_f32_16x16x32_bf16(a[m], b,
                                                             acc[m][nf], 0, 0, 0);
    }
  }
  // C/D layout: col = lane&15, row = (lane>>4)*4 + reg  [m89-verified]
#pragma unroll
  for (int m = 0; m < 2; ++m) {
    int rbase = row0 + m * 16 + khi * 4;
#pragma unroll
    for (int r = 0; r < 4; ++r) {
      int row = rbase + r;
      if (row >= nrows) continue;
      ushort_t* hp = H + (size_t)row * 128 + rlo;
#pragma unroll
      for (int nf = 0; nf < 8; ++nf) hp[nf * 16] = f2bf(acc[m][nf][r]);
    }
  }
}

// ---------- MFMA GEMM2: H[n,64] = X2bf16[n,128] @ bf16(W2[128,64]) -----------
__global__ __launch_bounds__(256) void mfma_gemm2_kernel(
    const ushort_t* __restrict__ X2, const float* __restrict__ W,
    ushort_t* __restrict__ H, int nrows) {
  __shared__ ushort_t Wt[64][136];
  const int tid = threadIdx.x;
  for (int i = tid; i < 128 * 64; i += 256) {
    int k = i >> 6, n = i & 63;
    Wt[n][k] = f2bf(W[i]);
  }
  __syncthreads();
  const int wave = tid >> 6, lane = tid & 63;
  const int row0 = blockIdx.x * 128 + wave * 32;
  const int rlo = lane & 15, khi = lane >> 4;

  f32x4 acc[2][4];
#pragma unroll
  for (int m = 0; m < 2; ++m)
#pragma unroll
    for (int n = 0; n < 4; ++n) acc[m][n] = (f32x4){0.f, 0.f, 0.f, 0.f};

#pragma unroll
  for (int ks = 0; ks < 4; ++ks) {
    const int kk = ks * 32 + khi * 8;
    short8v a[2];
#pragma unroll
    for (int m = 0; m < 2; ++m) {
      int row = row0 + m * 16 + rlo;
      if (row >= nrows) row = nrows - 1;
      U8 t;
      t.q = *(const uint4*)(X2 + (size_t)row * 128 + kk);
      a[m] = t.v;
    }
#pragma unroll
    for (int nf = 0; nf < 4; ++nf) {
      short8v b = *(const short8v*)&Wt[nf * 16 + rlo][kk];
#pragma unroll
      for (int m = 0; m < 2; ++m)
        acc[m][nf] = __builtin_amdgcn_mfma_f32_16x16x32_bf16(a[m], b,
                                                             acc[m][nf], 0, 0, 0);
    }
  }
#pragma unroll
  for (int m = 0; m < 2; ++m) {
    int rbase = row0 + m * 16 + khi * 4;
#pragma unroll
    for (int r = 0; r < 4; ++r) {
      int row = rbase + r;
      if (row >= nrows) continue;
      ushort_t* hp = H + (size_t)row * 64 + rlo;
#pragma unroll
      for (int nf = 0; nf < 4; ++nf) hp[nf * 16] = f2bf(acc[m][nf][r]);
    }
  }
}

// ---- fused h1 prep: one pass over h1b -> fp8 h8 + attn terms asn/adn --------
// 16 lanes/node; lane q covers channels 8q..8q+7 (head = q>>1).
__global__ __launch_bounds__(256) void h1_prep_kernel(
    const ushort_t* __restrict__ h1, const float* __restrict__ a_src,
    const float* __restrict__ a_dst, uint2* __restrict__ h8,
    float* __restrict__ asn, float* __restrict__ adn) {
  int node = (blockIdx.x << 4) + (threadIdx.x >> 4);
  if (node >= NN) return;
  int q = threadIdx.x & 15;
  uint4 v = ((const uint4*)(h1 + (size_t)node * F1))[q];  // 8 bf16
  uint2 r;
  r.x = fp8_pack4(bflo(v.x), bfhi(v.x), bflo(v.y), bfhi(v.y));
  r.y = fp8_pack4(bflo(v.z), bfhi(v.z), bflo(v.w), bfhi(v.w));
  h8[(size_t)node * 16 + q] = r;
  // attention partials over this lane's 8 channels
  float h0 = bflo(v.x), h1f = bfhi(v.x), h2 = bflo(v.y), h3 = bfhi(v.y);
  float h4 = bflo(v.z), h5 = bfhi(v.z), h6 = bflo(v.w), h7 = bfhi(v.w);
  const float4* as4 = (const float4*)a_src;
  const float4* ad4 = (const float4*)a_dst;
  float4 a0 = as4[q * 2], a1 = as4[q * 2 + 1];
  float4 d0 = ad4[q * 2], d1 = ad4[q * 2 + 1];
  float s = h0 * a0.x + h1f * a0.y + h2 * a0.z + h3 * a0.w +
            h4 * a1.x + h5 * a1.y + h6 * a1.z + h7 * a1.w;
  float d = h0 * d0.x + h1f * d0.y + h2 * d0.z + h3 * d0.w +
            h4 * d1.x + h5 * d1.y + h6 * d1.z + h7 * d1.w;
  s += __shfl_xor(s, 1);
  d += __shfl_xor(d, 1);
  if ((q & 1) == 0) {
    asn[node * 8 + (q >> 1)] = s;
    adn[node * 8 + (q >> 1)] = d;
  }
}

// ------------- h2 bf16 -> fp8 copy (gather2 payload, linear layout) ----------
__global__ __launch_bounds__(256) void h2_fp8_kernel(
    const ushort_t* __restrict__ h2, uint_t* __restrict__ h28) {
  int i = blockIdx.x * 256 + threadIdx.x;  // one uint (4 ch) per thread
  if (i >= NN * NC / 4) return;
  uint2 v = ((const uint2*)h2)[i];
  h28[i] = fp8_pack4(bflo(v.x), bfhi(v.x), bflo(v.y), bfhi(v.y));
}

// ------------- layer-2 per-node attention terms: asn/adn [N] -----------------
__global__ void attn2_kernel(const ushort_t* __restrict__ h2,
                             const float* __restrict__ a_src,
                             const float* __restrict__ a_dst,
                             float* __restrict__ asn, float* __restrict__ adn) {
  int wid = (blockIdx.x * blockDim.x + threadIdx.x) >> 6;
  int lane = threadIdx.x & 63;
  if (wid >= NN) return;
  float h = bf2f(h2[(size_t)wid * NC + lane]);
  float s = h * a_src[lane];
  float d = h * a_dst[lane];
#pragma unroll
  for (int m = 1; m < 64; m <<= 1) { s += __shfl_xor(s, m); d += __shfl_xor(d, m); }
  if (lane == 0) { asn[wid] = s; adn[wid] = d; }
}

// ------------------ CSR build: two-level multisplit by dst -------------------
__global__ __launch_bounds__(512) void bucket_count_kernel(
    const int* __restrict__ dstA, int* __restrict__ cnt) {
  __shared__ int histL[NBUK];
  int b = blockIdx.x, t = threadIdx.x;
  for (int i = t; i < NBUK; i += 512) histL[i] = 0;
  __syncthreads();
  int e0 = b * CHUNK, e1 = min(e0 + CHUNK, EN);
  for (int e = e0 + t; e < e1; e += 512) {
    int d = (e < NE) ? dstA[e] : (e - NE);
    atomicAdd(&histL[d >> BSH], 1);
  }
  __syncthreads();
  for (int i = t; i < NBUK; i += 512) cnt[i * NBLK + b] = histL[i];
}

__global__ __launch_bounds__(256) void bucket_scan_kernel(
    int* __restrict__ cnt, int* __restrict__ bucket_base) {
  __shared__ int colsum[NBUK];
  int t = threadIdx.x;
  if (t < NBUK) {
    int run = 0;
    int* c = cnt + t * NBLK;
    for (int b = 0; b < NBLK; ++b) { int v = c[b]; c[b] = run; run += v; }
    colsum[t] = run;
  }
  __syncthreads();
  if (t == 0) {
    int base = 0;
    for (int j = 0; j < NBUK; ++j) {
      bucket_base[j] = base;
      int v = colsum[j];
      colsum[j] = base;
      base += v;
    }
    bucket_base[NBUK] = base;  // == EN
  }
  __syncthreads();
  if (t < NBUK) {
    int bb = colsum[t];
    int* c = cnt + t * NBLK;
    for (int b = 0; b < NBLK; ++b) c[b] += bb;
  }
}

__global__ __launch_bounds__(512) void bucket_scatter_kernel(
    const int* __restrict__ srcA, const int* __restrict__ dstA,
    const int* __restrict__ cnt, int* __restrict__ staging) {
  __shared__ int cur[NBUK];
  int b = blockIdx.x, t = threadIdx.x;
  for (int i = t; i < NBUK; i += 512) cur[i] = cnt[i * NBLK + b];
  __syncthreads();
  int e0 = b * CHUNK, e1 = min(e0 + CHUNK, EN);
  for (int e = e0 + t; e < e1; e += 512) {
    int s, d;
    if (e < NE) { s = srcA[e]; d = dstA[e]; } else { s = e - NE; d = s; }
    int pos = atomicAdd(&cur[d >> BSH], 1);
    staging[pos] = s | ((d & (BKN - 1)) << 17);
  }
}

// P3: per-bucket fine CSR: LDS histogram -> scan -> rp -> direct scatter.
__global__ __launch_bounds__(512) void bucket_csr_kernel(
    const int* __restrict__ staging, const int* __restrict__ bucket_base,
    int* __restrict__ rp, int* __restrict__ col) {
  __shared__ int degL[BKN];
  __shared__ int exclL[BKN];
  __shared__ int sdata[2][BKN];
  int bk = blockIdx.x, t = threadIdx.x;
  int ebase = bucket_base[bk], eend = bucket_base[bk + 1];
  int ecnt = eend - ebase;
  degL[t] = 0;
  __syncthreads();
  for (int e = t; e < ecnt; e += 512)
    atomicAdd(&degL[staging[ebase + e] >> 17], 1);
  __syncthreads();
  int v = degL[t];
  sdata[0][t] = v;
  __syncthreads();
  int sp = 0;
  for (int off = 1; off < BKN; off <<= 1) {
    int val = sdata[sp][t];
    if (t >= off) val += sdata[sp][t - off];
    sdata[sp ^ 1][t] = val;
    __syncthreads();
    sp ^= 1;
  }
  int ex = sdata[sp][t] - v;  // local exclusive offset
  exclL[t] = ex;
  int node = bk * BKN + t;
  if (node < NN) rp[node] = ebase + ex;
  if (bk == 0 && t == 0) rp[NN] = EN;
  __syncthreads();
  for (int e = t; e < ecnt; e += 512) {
    int pk = staging[ebase + e];
    int pos = atomicAdd(&exclL[pk >> 17], 1);
    col[ebase + pos] = pk & 0x1FFFF;
  }
}

// ------ layer-1 gather: 16 lanes/node, 8 ch/lane, fp8 h1 payload -------------
__global__ __launch_bounds__(256) void gather1_kernel(
    const int* __restrict__ rp, const int* __restrict__ col,
    const float* __restrict__ asn, const float* __restrict__ adn,
    const uint2* __restrict__ h8, const float* __restrict__ b1,
    ushort_t* __restrict__ x2) {
  int node = (blockIdx.x << 4) + (threadIdx.x >> 4);
  if (node >= NN) return;
  int lane = threadIdx.x & 15;
  int head = lane >> 1;
  float aD = adn[node * 8 + head];
  int p = rp[node], p1 = rp[node + 1];
  float a0 = 0, a1 = 0, a2 = 0, a3 = 0, a4 = 0, a5 = 0, a6 = 0, a7 = 0;
  float den = 0.f;

  for (; p + 1 < p1; p += 2) {
    int s0 = col[p], s1 = col[p + 1];
    float e0 = asn[s0 * 8 + head] + aD;
    float e1 = asn[s1 * 8 + head] + aD;
    uint2 q0 = h8[(size_t)s0 * 16 + lane];
    uint2 q1 = h8[(size_t)s1 * 16 + lane];
    e0 = e0 > 0.f ? e0 : NEG * e0;
    e1 = e1 > 0.f ? e1 : NEG * e1;
    float ee0 = __expf(e0), ee1 = __expf(e1);
    float d0[4], d1[4], d2[4], d3[4];
    fp8_unpack4(q0.x, d0); fp8_unpack4(q0.y, d1);
    fp8_unpack4(q1.x, d2); fp8_unpack4(q1.y, d3);
    a0 += ee0 * d0[0] + ee1 * d2[0];
    a1 += ee0 * d0[1] + ee1 * d2[1];
    a2 += ee0 * d0[2] + ee1 * d2[2];
    a3 += ee0 * d0[3] + ee1 * d2[3];
    a4 += ee0 * d1[0] + ee1 * d3[0];
    a5 += ee0 * d1[1] + ee1 * d3[1];
    a6 += ee0 * d1[2] + ee1 * d3[2];
    a7 += ee0 * d1[3] + ee1 * d3[3];
    den += ee0 + ee1;
  }
  if (p < p1) {
    int s0 = col[p];
    float e0 = asn[s0 * 8 + head] + aD;
    uint2 q0 = h8[(size_t)s0 * 16 + lane];
    e0 = e0 > 0.f ? e0 : NEG * e0;
    float ee0 = __expf(e0);
    float d0[4], d1[4];
    fp8_unpack4(q0.x, d0); fp8_unpack4(q0.y, d1);
    a0 += ee0 * d0[0]; a1 += ee0 * d0[1]; a2 += ee0 * d0[2]; a3 += ee0 * d0[3];
    a4 += ee0 * d1[0]; a5 += ee0 * d1[1]; a6 += ee0 * d1[2]; a7 += ee0 * d1[3];
    den += ee0;
  }
  float inv = 1.f / den;
  const float4* b4 = (const float4*)b1;
  float4 ba = b4[lane * 2 + 0], bb = b4[lane * 2 + 1];
  float o0 = fmaf(a0, inv, ba.x), o1 = fmaf(a1, inv, ba.y);
  float o2 = fmaf(a2, inv, ba.z), o3 = fmaf(a3, inv, ba.w);
  float o4 = fmaf(a4, inv, bb.x), o5 = fmaf(a5, inv, bb.y);
  float o6 = fmaf(a6, inv, bb.z), o7 = fmaf(a7, inv, bb.w);
  o0 = o0 > 0.f ? o0 : __expf(o0) - 1.f;
  o1 = o1 > 0.f ? o1 : __expf(o1) - 1.f;
  o2 = o2 > 0.f ? o2 : __expf(o2) - 1.f;
  o3 = o3 > 0.f ? o3 : __expf(o3) - 1.f;
  o4 = o4 > 0.f ? o4 : __expf(o4) - 1.f;
  o5 = o5 > 0.f ? o5 : __expf(o5) - 1.f;
  o6 = o6 > 0.f ? o6 : __expf(o6) - 1.f;
  o7 = o7 > 0.f ? o7 : __expf(o7) - 1.f;
  U8 t;
  t.u[0] = f2bf(o0); t.u[1] = f2bf(o1); t.u[2] = f2bf(o2); t.u[3] = f2bf(o3);
  t.u[4] = f2bf(o4); t.u[5] = f2bf(o5); t.u[6] = f2bf(o6); t.u[7] = f2bf(o7);
  ((uint4*)(x2 + (size_t)node * F1))[lane] = t.q;
}

// ------ layer-2 gather: 16 lanes/node, 4 ch/lane, fp8 h2 + log_softmax ------
// h2 row = 64 fp8 bytes = ONE cacheline per edge.
__global__ __launch_bounds__(256) void gather2_kernel(
    const int* __restrict__ rp, const int* __restrict__ col,
    const float* __restrict__ asn, const float* __restrict__ adn,
    const uint_t* __restrict__ h28, const float* __restrict__ b2,
    float* __restrict__ out) {
  int node = (blockIdx.x << 4) + (threadIdx.x >> 4);
  if (node >= NN) return;
  int lane = threadIdx.x & 15;
  float aD = adn[node];
  int p = rp[node], p1 = rp[node + 1];
  float a0 = 0, a1 = 0, a2 = 0, a3 = 0, den = 0.f;

  for (; p + 1 < p1; p += 2) {
    int s0 = col[p], s1 = col[p + 1];
    float e0 = asn[s0] + aD;
    float e1 = asn[s1] + aD;
    uint_t q0 = h28[(size_t)s0 * 16 + lane];
    uint_t q1 = h28[(size_t)s1 * 16 + lane];
    e0 = e0 > 0.f ? e0 : NEG * e0;
    e1 = e1 > 0.f ? e1 : NEG * e1;
    float ee0 = __expf(e0), ee1 = __expf(e1);
    float d0[4], d1[4];
    fp8_unpack4(q0, d0); fp8_unpack4(q1, d1);
    a0 += ee0 * d0[0] + ee1 * d1[0];
    a1 += ee0 * d0[1] + ee1 * d1[1];
    a2 += ee0 * d0[2] + ee1 * d1[2];
    a3 += ee0 * d0[3] + ee1 * d1[3];
    den += ee0 + ee1;
  }
  if (p < p1) {
    int s0 = col[p];
    float e0 = asn[s0] + aD;
    uint_t q0 = h28[(size_t)s0 * 16 + lane];
    e0 = e0 > 0.f ? e0 : NEG * e0;
    float ee0 = __expf(e0);
    float d0[4];
    fp8_unpack4(q0, d0);
    a0 += ee0 * d0[0]; a1 += ee0 * d0[1]; a2 += ee0 * d0[2]; a3 += ee0 * d0[3];
    den += ee0;
  }
  float inv = 1.f / den;
  float4 bv = ((const float4*)b2)[lane];
  float v0 = fmaf(a0, inv, bv.x), v1 = fmaf(a1, inv, bv.y);
  float v2 = fmaf(a2, inv, bv.z), v3 = fmaf(a3, inv, bv.w);
  float m = fmaxf(fmaxf(v0, v1), fmaxf(v2, v3));
#pragma unroll
  for (int k = 1; k < 16; k <<= 1) m = fmaxf(m, __shfl_xor(m, k));
  float ex = __expf(v0 - m) + __expf(v1 - m) + __expf(v2 - m) + __expf(v3 - m);
#pragma unroll
  for (int k = 1; k < 16; k <<= 1) ex += __shfl_xor(ex, k);
  float lse = m + __logf(ex);
  float4 r = {v0 - lse, v1 - lse, v2 - lse, v3 - lse};
  ((float4*)(out + (size_t)node * NC))[lane] = r;
}

extern "C" void kernel_launch(void* const* d_in, const int* in_sizes, int n_in,
                              void* d_out, int out_size, void* d_ws,
                              size_t ws_size, hipStream_t stream) {
  const float* x = (const float*)d_in[0];
  const int* edge_index = (const int*)d_in[1];
  const float* W1 = (const float*)d_in[2];
  const float* a_src1 = (const float*)d_in[3];
  const float* a_dst1 = (const float*)d_in[4];
  const float* b1 = (const float*)d_in[5];
  const float* W2 = (const float*)d_in[6];
  const float* a_src2 = (const float*)d_in[7];
  const float* a_dst2 = (const float*)d_in[8];
  const float* b2 = (const float*)d_in[9];
  float* out = (float*)d_out;
  float* ws = (float*)d_ws;

  // workspace layout (float offsets), non-overlapping:
  ushort_t* h1b = (ushort_t*)ws;               // [0, 6.4M)   bf16 h1 / h2
  ushort_t* x2b = (ushort_t*)(ws + 6400000);   // [6.4M, 12.8M) bf16 x2
  uint2* h8 = (uint2*)(ws + 12800000);         // [12.8M, 16.0M) fp8 h1
  uint_t* h28 = (uint_t*)(ws + 16000000);      // [16.0M, 17.6M) fp8 h2
  float* asn1 = ws + 17600000;                 // [17.6M, 18.4M)
  float* adn1 = ws + 18400000;                 // [18.4M, 19.2M)
  float* asn2 = ws + 19200000;                 // [19.2M, 19.3M)
  float* adn2 = ws + 19300000;                 // [19.3M, 19.4M)
  int* rp = (int*)(ws + 19400000);             // NN+1
  int* col = rp + NN + 1;                      // EN
  int* staging = col + EN;                     // EN
  int* cnt = staging + EN;                     // NBUK*NBLK
  int* bucket_base = cnt + NBUK * NBLK;        // NBUK+1  (~23.1M floats)

  const int* srcA = edge_index;
  const int* dstA = edge_index + NE;

  // ---- CSR build (multisplit) ----
  bucket_count_kernel<<<NBLK, 512, 0, stream>>>(dstA, cnt);
  bucket_scan_kernel<<<1, 256, 0, stream>>>(cnt, bucket_base);
  bucket_scatter_kernel<<<NBLK, 512, 0, stream>>>(srcA, dstA, cnt, staging);
  bucket_csr_kernel<<<NBUK, 512, 0, stream>>>(staging, bucket_base, rp, col);

  // ---- layer 1 ----
  mfma_gemm1_kernel<<<(NN + 127) / 128, 256, 0, stream>>>(x, W1, h1b, NN);
  h1_prep_kernel<<<(NN + 15) / 16, 256, 0, stream>>>(h1b, a_src1, a_dst1, h8,
                                                     asn1, adn1);
  gather1_kernel<<<(NN + 15) / 16, 256, 0, stream>>>(rp, col, asn1, adn1, h8,
                                                     b1, x2b);
  // ---- layer 2 ----
  ushort_t* h2b = h1b;  // h1 bf16 dead after h1_prep
  mfma_gemm2_kernel<<<(NN + 127) / 128, 256, 0, stream>>>(x2b, W2, h2b, NN);
  h2_fp8_kernel<<<(NN * NC / 4 + 255) / 256, 256, 0, stream>>>(h2b, h28);
  attn2_kernel<<<(NN * 64 + 255) / 256, 256, 0, stream>>>(h2b, a_src2, a_dst2,
                                                          asn2, adn2);
  gather2_kernel<<<(NN + 15) / 16, 256, 0, stream>>>(rp, col, asn2, adn2, h28,
                                                     b2, out);
}

// Round 13
// 238.647 us; speedup vs baseline: 1.5044x; 1.0111x over previous
//
#include <hip/hip_runtime.h>

#define NN 100000
#define NE 1600000
#define EN (NE + NN)          // edges incl. self-loops
#define FIN 128
#define H1 8
#define C1 16
#define F1 128                // H1*C1
#define NC 64
#define NEG 0.2f

// ---- CSR-build multisplit parameters ----
#define BSH 9                 // bucket = dst >> BSH
#define BKN 512               // nodes per bucket
#define NBUK ((NN + BKN - 1) / BKN)   // 196
#define NBLK 256              // edge-chunk blocks for P1/P2
#define CHUNK ((EN + NBLK - 1) / NBLK) // 6641

typedef unsigned short ushort_t;
typedef unsigned int uint_t;
typedef __attribute__((ext_vector_type(8))) short short8v;
typedef __attribute__((ext_vector_type(4))) float f32x4;
typedef __attribute__((ext_vector_type(2))) float f32x2;

union U8 { ushort_t u[8]; short8v v; uint4 q; };

__device__ __forceinline__ ushort_t f2bf(float f) {
  uint_t u = __builtin_bit_cast(uint_t, f);
  u += 0x7FFF + ((u >> 16) & 1);  // RNE
  return (ushort_t)(u >> 16);
}
__device__ __forceinline__ float bflo(uint_t u) {
  return __builtin_bit_cast(float, u << 16);
}
__device__ __forceinline__ float bfhi(uint_t u) {
  return __builtin_bit_cast(float, u & 0xFFFF0000u);
}

// ---------------- fp8 encode/decode (HW cvt preferred) -----------------------
#if __has_builtin(__builtin_amdgcn_cvt_pk_fp8_f32) && \
    __has_builtin(__builtin_amdgcn_cvt_pk_f32_fp8)
__device__ __forceinline__ uint_t fp8_pack4(float f0, float f1, float f2,
                                            float f3) {
  int p = 0;
  p = __builtin_amdgcn_cvt_pk_fp8_f32(f0, f1, p, false);
  p = __builtin_amdgcn_cvt_pk_fp8_f32(f2, f3, p, true);
  return (uint_t)p;
}
__device__ __forceinline__ void fp8_unpack4(uint_t w, float* o) {
  f32x2 d0 = __builtin_amdgcn_cvt_pk_f32_fp8((int)w, false);
  f32x2 d1 = __builtin_amdgcn_cvt_pk_f32_fp8((int)w, true);
  o[0] = d0.x; o[1] = d0.y; o[2] = d1.x; o[3] = d1.y;
}
#else
__device__ __forceinline__ uint_t fp8_enc1(float f) {
  uint_t u = __builtin_bit_cast(uint_t, f);
  uint_t s = (u >> 24) & 0x80u;
  int e = (int)((u >> 23) & 0xFF) - 127;
  if (e < -9) return s;
  if (e < -6) {
    float af = __builtin_bit_cast(float, u & 0x7FFFFFFFu);
    uint_t m = (uint_t)(af * 512.f + 0.5f);
    return s | m;
  }
  uint_t mant = u & 0x7FFFFF;
  uint_t keep = mant >> 20;
  uint_t rest = mant & 0xFFFFF;
  keep += (rest > 0x80000u) || (rest == 0x80000u && (keep & 1));
  uint_t ee = (uint_t)(e + 7);
  if (keep == 8) { keep = 0; ee += 1; }
  if (ee > 15 || (ee == 15 && keep > 6)) return s | 0x7E;
  return s | (ee << 3) | keep;
}
__device__ __forceinline__ float fp8_dec1(uint_t b) {
  uint_t s = (b & 0x80u) << 24;
  uint_t e = (b >> 3) & 15u, m = b & 7u;
  if (e == 0) {
    float v = (float)m * (1.0f / 512.0f);
    return __builtin_bit_cast(float, s | __builtin_bit_cast(uint_t, v));
  }
  return __builtin_bit_cast(float, s | ((e + 120u) << 23) | (m << 20));
}
__device__ __forceinline__ uint_t fp8_pack4(float f0, float f1, float f2,
                                            float f3) {
  return fp8_enc1(f0) | (fp8_enc1(f1) << 8) | (fp8_enc1(f2) << 16) |
         (fp8_enc1(f3) << 24);
}
__device__ __forceinline__ void fp8_unpack4(uint_t w, float* o) {
  o[0] = fp8_dec1(w & 0xFF); o[1] = fp8_dec1((w >> 8) & 0xFF);
  o[2] = fp8_dec1((w >> 16) & 0xFF); o[3] = fp8_dec1(w >> 24);
}
#endif

// ---------- MFMA GEMM1 (fully fused layer-1 prep) ----------------------------
// W1 columns are PERMUTED in LDS: MFMA col n -> true channel (n&15)*8 + (n>>4).
// Then lane rlo's accumulators acc[m][nf][r] are channels 8*rlo+nf: contiguous,
// single head (rlo>>1). Epilogue emits LINEAR fp8 h8 (uint2/lane) + asn1/adn1
// (one shfl_xor(1) per pair of lanes). No bf16 h1 is materialized at all.
__global__ __launch_bounds__(256) void mfma_gemm1_kernel(
    const float* __restrict__ X, const float* __restrict__ W,
    const float* __restrict__ a_src, const float* __restrict__ a_dst,
    uint2* __restrict__ h8, float* __restrict__ asn, float* __restrict__ adn,
    int nrows) {
  __shared__ ushort_t Wt[128][136];  // [mfma-col][k], +8 pad
  const int tid = threadIdx.x;
  for (int i = tid; i < 128 * 128; i += 256) {
    int k = i >> 7, n = i & 127;
    int c = (n & 15) * 8 + (n >> 4);   // mfma col -> true channel
    Wt[n][k] = f2bf(W[k * 128 + c]);
  }
  __syncthreads();
  const int wave = tid >> 6, lane = tid & 63;
  const int row0 = blockIdx.x * 128 + wave * 32;
  const int rlo = lane & 15, khi = lane >> 4;  // khi in 0..3

  f32x4 acc[2][8];
#pragma unroll
  for (int m = 0; m < 2; ++m)
#pragma unroll
    for (int n = 0; n < 8; ++n) acc[m][n] = (f32x4){0.f, 0.f, 0.f, 0.f};

#pragma unroll
  for (int ks = 0; ks < 4; ++ks) {
    const int kk = ks * 32 + khi * 8;
    short8v a[2];
#pragma unroll
    for (int m = 0; m < 2; ++m) {
      int row = row0 + m * 16 + rlo;
      if (row >= nrows) row = nrows - 1;
      const float4* xp = (const float4*)(X + (size_t)row * 128 + kk);
      float4 u = xp[0], v = xp[1];
      U8 t;
      t.u[0] = f2bf(u.x); t.u[1] = f2bf(u.y); t.u[2] = f2bf(u.z); t.u[3] = f2bf(u.w);
      t.u[4] = f2bf(v.x); t.u[5] = f2bf(v.y); t.u[6] = f2bf(v.z); t.u[7] = f2bf(v.w);
      a[m] = t.v;
    }
#pragma unroll
    for (int nf = 0; nf < 8; ++nf) {
      short8v b = *(const short8v*)&Wt[nf * 16 + rlo][kk];
#pragma unroll
      for (int m = 0; m < 2; ++m)
        acc[m][nf] = __builtin_amdgcn_mfma_f32_16x16x32_bf16(a[m], b,
                                                             acc[m][nf], 0, 0, 0);
    }
  }
  // a_src/a_dst flat [8][16] = head*16 + ch_in_head; lane's 8 channels map to
  // flat indices rlo*8 .. rlo*8+7.
  const float4* as4 = (const float4*)a_src;
  const float4* ad4 = (const float4*)a_dst;
  float4 as0 = as4[rlo * 2], as1 = as4[rlo * 2 + 1];
  float4 ad0 = ad4[rlo * 2], ad1 = ad4[rlo * 2 + 1];
  // C/D layout: col = lane&15, row = (lane>>4)*4 + reg  [m89-verified]
#pragma unroll
  for (int m = 0; m < 2; ++m) {
    int rbase = row0 + m * 16 + khi * 4;
#pragma unroll
    for (int r = 0; r < 4; ++r) {
      int row = rbase + r;
      bool ok = (row < nrows);   // uniform across each lane-pair (rlo, rlo^1)
      uint2 pk;
      pk.x = fp8_pack4(acc[m][0][r], acc[m][1][r], acc[m][2][r], acc[m][3][r]);
      pk.y = fp8_pack4(acc[m][4][r], acc[m][5][r], acc[m][6][r], acc[m][7][r]);
      if (ok) h8[(size_t)row * 16 + rlo] = pk;
      float s = acc[m][0][r] * as0.x + acc[m][1][r] * as0.y +
                acc[m][2][r] * as0.z + acc[m][3][r] * as0.w +
                acc[m][4][r] * as1.x + acc[m][5][r] * as1.y +
                acc[m][6][r] * as1.z + acc[m][7][r] * as1.w;
      float d = acc[m][0][r] * ad0.x + acc[m][1][r] * ad0.y +
                acc[m][2][r] * ad0.z + acc[m][3][r] * ad0.w +
                acc[m][4][r] * ad1.x + acc[m][5][r] * ad1.y +
                acc[m][6][r] * ad1.z + acc[m][7][r] * ad1.w;
      s += __shfl_xor(s, 1);     // pair (rlo, rlo^1) = full 16-ch head
      d += __shfl_xor(d, 1);
      if (ok && (rlo & 1) == 0) {
        asn[row * 8 + (rlo >> 1)] = s;
        adn[row * 8 + (rlo >> 1)] = d;
      }
    }
  }
}

// ---------- MFMA GEMM2 (fully fused layer-2 prep) ----------------------------
// W2 columns permuted: MFMA col n -> true channel (n&15)*4 + (n>>4). Lane rlo
// holds channels 4*rlo..4*rlo+3 -> linear fp8 h28 (uint/lane) + asn2/adn2
// (single head: reduce over all 16 rlo lanes). No bf16 h2 materialized.
__global__ __launch_bounds__(256) void mfma_gemm2_kernel(
    const ushort_t* __restrict__ X2, const float* __restrict__ W,
    const float* __restrict__ a_src, const float* __restrict__ a_dst,
    uint_t* __restrict__ h28, float* __restrict__ asn, float* __restrict__ adn,
    int nrows) {
  __shared__ ushort_t Wt[64][136];
  const int tid = threadIdx.x;
  for (int i = tid; i < 128 * 64; i += 256) {
    int k = i >> 6, n = i & 63;
    int c = (n & 15) * 4 + (n >> 4);   // mfma col -> true channel
    Wt[n][k] = f2bf(W[k * 64 + c]);
  }
  __syncthreads();
  const int wave = tid >> 6, lane = tid & 63;
  const int row0 = blockIdx.x * 128 + wave * 32;
  const int rlo = lane & 15, khi = lane >> 4;

  f32x4 acc[2][4];
#pragma unroll
  for (int m = 0; m < 2; ++m)
#pragma unroll
    for (int n = 0; n < 4; ++n) acc[m][n] = (f32x4){0.f, 0.f, 0.f, 0.f};

#pragma unroll
  for (int ks = 0; ks < 4; ++ks) {
    const int kk = ks * 32 + khi * 8;
    short8v a[2];
#pragma unroll
    for (int m = 0; m < 2; ++m) {
      int row = row0 + m * 16 + rlo;
      if (row >= nrows) row = nrows - 1;
      U8 t;
      t.q = *(const uint4*)(X2 + (size_t)row * 128 + kk);
      a[m] = t.v;
    }
#pragma unroll
    for (int nf = 0; nf < 4; ++nf) {
      short8v b = *(const short8v*)&Wt[nf * 16 + rlo][kk];
#pragma unroll
      for (int m = 0; m < 2; ++m)
        acc[m][nf] = __builtin_amdgcn_mfma_f32_16x16x32_bf16(a[m], b,
                                                             acc[m][nf], 0, 0, 0);
    }
  }
  float4 as = ((const float4*)a_src)[rlo];  // channels 4*rlo..4*rlo+3
  float4 ad = ((const float4*)a_dst)[rlo];
#pragma unroll
  for (int m = 0; m < 2; ++m) {
    int rbase = row0 + m * 16 + khi * 4;
#pragma unroll
    for (int r = 0; r < 4; ++r) {
      int row = rbase + r;
      bool ok = (row < nrows);   // uniform across the 16-lane rlo group
      uint_t pk = fp8_pack4(acc[m][0][r], acc[m][1][r], acc[m][2][r],
                            acc[m][3][r]);
      if (ok) h28[(size_t)row * 16 + rlo] = pk;
      float s = acc[m][0][r] * as.x + acc[m][1][r] * as.y +
                acc[m][2][r] * as.z + acc[m][3][r] * as.w;
      float d = acc[m][0][r] * ad.x + acc[m][1][r] * ad.y +
                acc[m][2][r] * ad.z + acc[m][3][r] * ad.w;
      s += __shfl_xor(s, 1); s += __shfl_xor(s, 2);
      s += __shfl_xor(s, 4); s += __shfl_xor(s, 8);
      d += __shfl_xor(d, 1); d += __shfl_xor(d, 2);
      d += __shfl_xor(d, 4); d += __shfl_xor(d, 8);
      if (ok && rlo == 0) { asn[row] = s; adn[row] = d; }
    }
  }
}

// ------------------ CSR build: two-level multisplit by dst -------------------
__global__ __launch_bounds__(512) void bucket_count_kernel(
    const int* __restrict__ dstA, int* __restrict__ cnt) {
  __shared__ int histL[NBUK];
  int b = blockIdx.x, t = threadIdx.x;
  for (int i = t; i < NBUK; i += 512) histL[i] = 0;
  __syncthreads();
  int e0 = b * CHUNK, e1 = min(e0 + CHUNK, EN);
  for (int e = e0 + t; e < e1; e += 512) {
    int d = (e < NE) ? dstA[e] : (e - NE);
    atomicAdd(&histL[d >> BSH], 1);
  }
  __syncthreads();
  for (int i = t; i < NBUK; i += 512) cnt[i * NBLK + b] = histL[i];
}

__global__ __launch_bounds__(256) void bucket_scan_kernel(
    int* __restrict__ cnt, int* __restrict__ bucket_base) {
  __shared__ int colsum[NBUK];
  int t = threadIdx.x;
  if (t < NBUK) {
    int run = 0;
    int* c = cnt + t * NBLK;
    for (int b = 0; b < NBLK; ++b) { int v = c[b]; c[b] = run; run += v; }
    colsum[t] = run;
  }
  __syncthreads();
  if (t == 0) {
    int base = 0;
    for (int j = 0; j < NBUK; ++j) {
      bucket_base[j] = base;
      int v = colsum[j];
      colsum[j] = base;
      base += v;
    }
    bucket_base[NBUK] = base;  // == EN
  }
  __syncthreads();
  if (t < NBUK) {
    int bb = colsum[t];
    int* c = cnt + t * NBLK;
    for (int b = 0; b < NBLK; ++b) c[b] += bb;
  }
}

__global__ __launch_bounds__(512) void bucket_scatter_kernel(
    const int* __restrict__ srcA, const int* __restrict__ dstA,
    const int* __restrict__ cnt, int* __restrict__ staging) {
  __shared__ int cur[NBUK];
  int b = blockIdx.x, t = threadIdx.x;
  for (int i = t; i < NBUK; i += 512) cur[i] = cnt[i * NBLK + b];
  __syncthreads();
  int e0 = b * CHUNK, e1 = min(e0 + CHUNK, EN);
  for (int e = e0 + t; e < e1; e += 512) {
    int s, d;
    if (e < NE) { s = srcA[e]; d = dstA[e]; } else { s = e - NE; d = s; }
    int pos = atomicAdd(&cur[d >> BSH], 1);
    staging[pos] = s | ((d & (BKN - 1)) << 17);
  }
}

// P3: per-bucket fine CSR: LDS histogram -> scan -> rp -> direct scatter.
__global__ __launch_bounds__(512) void bucket_csr_kernel(
    const int* __restrict__ staging, const int* __restrict__ bucket_base,
    int* __restrict__ rp, int* __restrict__ col) {
  __shared__ int degL[BKN];
  __shared__ int exclL[BKN];
  __shared__ int sdata[2][BKN];
  int bk = blockIdx.x, t = threadIdx.x;
  int ebase = bucket_base[bk], eend = bucket_base[bk + 1];
  int ecnt = eend - ebase;
  degL[t] = 0;
  __syncthreads();
  for (int e = t; e < ecnt; e += 512)
    atomicAdd(&degL[staging[ebase + e] >> 17], 1);
  __syncthreads();
  int v = degL[t];
  sdata[0][t] = v;
  __syncthreads();
  int sp = 0;
  for (int off = 1; off < BKN; off <<= 1) {
    int val = sdata[sp][t];
    if (t >= off) val += sdata[sp][t - off];
    sdata[sp ^ 1][t] = val;
    __syncthreads();
    sp ^= 1;
  }
  int ex = sdata[sp][t] - v;  // local exclusive offset
  exclL[t] = ex;
  int node = bk * BKN + t;
  if (node < NN) rp[node] = ebase + ex;
  if (bk == 0 && t == 0) rp[NN] = EN;
  __syncthreads();
  for (int e = t; e < ecnt; e += 512) {
    int pk = staging[ebase + e];
    int pos = atomicAdd(&exclL[pk >> 17], 1);
    col[ebase + pos] = pk & 0x1FFFF;
  }
}

// ------ layer-1 gather: 16 lanes/node, 8 ch/lane, fp8 h1 payload -------------
__global__ __launch_bounds__(256) void gather1_kernel(
    const int* __restrict__ rp, const int* __restrict__ col,
    const float* __restrict__ asn, const float* __restrict__ adn,
    const uint2* __restrict__ h8, const float* __restrict__ b1,
    ushort_t* __restrict__ x2) {
  int node = (blockIdx.x << 4) + (threadIdx.x >> 4);
  if (node >= NN) return;
  int lane = threadIdx.x & 15;
  int head = lane >> 1;
  float aD = adn[node * 8 + head];
  int p = rp[node], p1 = rp[node + 1];
  float a0 = 0, a1 = 0, a2 = 0, a3 = 0, a4 = 0, a5 = 0, a6 = 0, a7 = 0;
  float den = 0.f;

  for (; p + 1 < p1; p += 2) {
    int s0 = col[p], s1 = col[p + 1];
    float e0 = asn[s0 * 8 + head] + aD;
    float e1 = asn[s1 * 8 + head] + aD;
    uint2 q0 = h8[(size_t)s0 * 16 + lane];
    uint2 q1 = h8[(size_t)s1 * 16 + lane];
    e0 = e0 > 0.f ? e0 : NEG * e0;
    e1 = e1 > 0.f ? e1 : NEG * e1;
    float ee0 = __expf(e0), ee1 = __expf(e1);
    float d0[4], d1[4], d2[4], d3[4];
    fp8_unpack4(q0.x, d0); fp8_unpack4(q0.y, d1);
    fp8_unpack4(q1.x, d2); fp8_unpack4(q1.y, d3);
    a0 += ee0 * d0[0] + ee1 * d2[0];
    a1 += ee0 * d0[1] + ee1 * d2[1];
    a2 += ee0 * d0[2] + ee1 * d2[2];
    a3 += ee0 * d0[3] + ee1 * d2[3];
    a4 += ee0 * d1[0] + ee1 * d3[0];
    a5 += ee0 * d1[1] + ee1 * d3[1];
    a6 += ee0 * d1[2] + ee1 * d3[2];
    a7 += ee0 * d1[3] + ee1 * d3[3];
    den += ee0 + ee1;
  }
  if (p < p1) {
    int s0 = col[p];
    float e0 = asn[s0 * 8 + head] + aD;
    uint2 q0 = h8[(size_t)s0 * 16 + lane];
    e0 = e0 > 0.f ? e0 : NEG * e0;
    float ee0 = __expf(e0);
    float d0[4], d1[4];
    fp8_unpack4(q0.x, d0); fp8_unpack4(q0.y, d1);
    a0 += ee0 * d0[0]; a1 += ee0 * d0[1]; a2 += ee0 * d0[2]; a3 += ee0 * d0[3];
    a4 += ee0 * d1[0]; a5 += ee0 * d1[1]; a6 += ee0 * d1[2]; a7 += ee0 * d1[3];
    den += ee0;
  }
  float inv = 1.f / den;
  const float4* b4 = (const float4*)b1;
  float4 ba = b4[lane * 2 + 0], bb = b4[lane * 2 + 1];
  float o0 = fmaf(a0, inv, ba.x), o1 = fmaf(a1, inv, ba.y);
  float o2 = fmaf(a2, inv, ba.z), o3 = fmaf(a3, inv, ba.w);
  float o4 = fmaf(a4, inv, bb.x), o5 = fmaf(a5, inv, bb.y);
  float o6 = fmaf(a6, inv, bb.z), o7 = fmaf(a7, inv, bb.w);
  o0 = o0 > 0.f ? o0 : __expf(o0) - 1.f;
  o1 = o1 > 0.f ? o1 : __expf(o1) - 1.f;
  o2 = o2 > 0.f ? o2 : __expf(o2) - 1.f;
  o3 = o3 > 0.f ? o3 : __expf(o3) - 1.f;
  o4 = o4 > 0.f ? o4 : __expf(o4) - 1.f;
  o5 = o5 > 0.f ? o5 : __expf(o5) - 1.f;
  o6 = o6 > 0.f ? o6 : __expf(o6) - 1.f;
  o7 = o7 > 0.f ? o7 : __expf(o7) - 1.f;
  U8 t;
  t.u[0] = f2bf(o0); t.u[1] = f2bf(o1); t.u[2] = f2bf(o2); t.u[3] = f2bf(o3);
  t.u[4] = f2bf(o4); t.u[5] = f2bf(o5); t.u[6] = f2bf(o6); t.u[7] = f2bf(o7);
  ((uint4*)(x2 + (size_t)node * F1))[lane] = t.q;
}

// ------ layer-2 gather: 16 lanes/node, 4 ch/lane, fp8 h2 + log_softmax ------
__global__ __launch_bounds__(256) void gather2_kernel(
    const int* __restrict__ rp, const int* __restrict__ col,
    const float* __restrict__ asn, const float* __restrict__ adn,
    const uint_t* __restrict__ h28, const float* __restrict__ b2,
    float* __restrict__ out) {
  int node = (blockIdx.x << 4) + (threadIdx.x >> 4);
  if (node >= NN) return;
  int lane = threadIdx.x & 15;
  float aD = adn[node];
  int p = rp[node], p1 = rp[node + 1];
  float a0 = 0, a1 = 0, a2 = 0, a3 = 0, den = 0.f;

  for (; p + 1 < p1; p += 2) {
    int s0 = col[p], s1 = col[p + 1];
    float e0 = asn[s0] + aD;
    float e1 = asn[s1] + aD;
    uint_t q0 = h28[(size_t)s0 * 16 + lane];
    uint_t q1 = h28[(size_t)s1 * 16 + lane];
    e0 = e0 > 0.f ? e0 : NEG * e0;
    e1 = e1 > 0.f ? e1 : NEG * e1;
    float ee0 = __expf(e0), ee1 = __expf(e1);
    float d0[4], d1[4];
    fp8_unpack4(q0, d0); fp8_unpack4(q1, d1);
    a0 += ee0 * d0[0] + ee1 * d1[0];
    a1 += ee0 * d0[1] + ee1 * d1[1];
    a2 += ee0 * d0[2] + ee1 * d1[2];
    a3 += ee0 * d0[3] + ee1 * d1[3];
    den += ee0 + ee1;
  }
  if (p < p1) {
    int s0 = col[p];
    float e0 = asn[s0] + aD;
    uint_t q0 = h28[(size_t)s0 * 16 + lane];
    e0 = e0 > 0.f ? e0 : NEG * e0;
    float ee0 = __expf(e0);
    float d0[4];
    fp8_unpack4(q0, d0);
    a0 += ee0 * d0[0]; a1 += ee0 * d0[1]; a2 += ee0 * d0[2]; a3 += ee0 * d0[3];
    den += ee0;
  }
  float inv = 1.f / den;
  float4 bv = ((const float4*)b2)[lane];
  float v0 = fmaf(a0, inv, bv.x), v1 = fmaf(a1, inv, bv.y);
  float v2 = fmaf(a2, inv, bv.z), v3 = fmaf(a3, inv, bv.w);
  float m = fmaxf(fmaxf(v0, v1), fmaxf(v2, v3));
#pragma unroll
  for (int k = 1; k < 16; k <<= 1) m = fmaxf(m, __shfl_xor(m, k));
  float ex = __expf(v0 - m) + __expf(v1 - m) + __expf(v2 - m) + __expf(v3 - m);
#pragma unroll
  for (int k = 1; k < 16; k <<= 1) ex += __shfl_xor(ex, k);
  float lse = m + __logf(ex);
  float4 r = {v0 - lse, v1 - lse, v2 - lse, v3 - lse};
  ((float4*)(out + (size_t)node * NC))[lane] = r;
}

extern "C" void kernel_launch(void* const* d_in, const int* in_sizes, int n_in,
                              void* d_out, int out_size, void* d_ws,
                              size_t ws_size, hipStream_t stream) {
  const float* x = (const float*)d_in[0];
  const int* edge_index = (const int*)d_in[1];
  const float* W1 = (const float*)d_in[2];
  const float* a_src1 = (const float*)d_in[3];
  const float* a_dst1 = (const float*)d_in[4];
  const float* b1 = (const float*)d_in[5];
  const float* W2 = (const float*)d_in[6];
  const float* a_src2 = (const float*)d_in[7];
  const float* a_dst2 = (const float*)d_in[8];
  const float* b2 = (const float*)d_in[9];
  float* out = (float*)d_out;
  float* ws = (float*)d_ws;

  // workspace layout (float offsets), non-overlapping:
  ushort_t* x2b = (ushort_t*)ws;               // [0, 6.4M)   bf16 x2
  uint2* h8 = (uint2*)(ws + 6400000);          // [6.4M, 9.6M)  fp8 h1 (linear)
  uint_t* h28 = (uint_t*)(ws + 9600000);       // [9.6M, 11.2M) fp8 h2 (linear)
  float* asn1 = ws + 11200000;                 // [11.2M, 12.0M)
  float* adn1 = ws + 12000000;                 // [12.0M, 12.8M)
  float* asn2 = ws + 12800000;                 // [12.8M, 12.9M)
  float* adn2 = ws + 12900000;                 // [12.9M, 13.0M)
  int* rp = (int*)(ws + 13000000);             // NN+1
  int* col = rp + NN + 1;                      // EN
  int* staging = col + EN;                     // EN
  int* cnt = staging + EN;                     // NBUK*NBLK
  int* bucket_base = cnt + NBUK * NBLK;        // NBUK+1  (~16.7M floats)

  const int* srcA = edge_index;
  const int* dstA = edge_index + NE;

  // ---- CSR build (multisplit) ----
  bucket_count_kernel<<<NBLK, 512, 0, stream>>>(dstA, cnt);
  bucket_scan_kernel<<<1, 256, 0, stream>>>(cnt, bucket_base);
  bucket_scatter_kernel<<<NBLK, 512, 0, stream>>>(srcA, dstA, cnt, staging);
  bucket_csr_kernel<<<NBUK, 512, 0, stream>>>(staging, bucket_base, rp, col);

  // ---- layer 1 (gemm + fp8 + attn fused) ----
  mfma_gemm1_kernel<<<(NN + 127) / 128, 256, 0, stream>>>(
      x, W1, a_src1, a_dst1, h8, asn1, adn1, NN);
  gather1_kernel<<<(NN + 15) / 16, 256, 0, stream>>>(rp, col, asn1, adn1, h8,
                                                     b1, x2b);
  // ---- layer 2 (gemm + fp8 + attn fused) ----
  mfma_gemm2_kernel<<<(NN + 127) / 128, 256, 0, stream>>>(
      x2b, W2, a_src2, a_dst2, h28, asn2, adn2, NN);
  gather2_kernel<<<(NN + 15) / 16, 256, 0, stream>>>(rp, col, asn2, adn2, h28,
                                                     b2, out);
}

// Round 14
// 238.504 us; speedup vs baseline: 1.5053x; 1.0006x over previous
//
#include <hip/hip_runtime.h>

#define NN 100000
#define NE 1600000
#define EN (NE + NN)          // edges incl. self-loops
#define FIN 128
#define H1 8
#define C1 16
#define F1 128                // H1*C1
#define NC 64
#define NEG 0.2f

// ---- CSR-build multisplit parameters ----
#define BSH 9                 // bucket = dst >> BSH
#define BKN 512               // nodes per bucket
#define NBUK ((NN + BKN - 1) / BKN)   // 196
#define NBLK 256              // edge-chunk blocks for P1/P2
#define CHUNK ((EN + NBLK - 1) / NBLK) // 6641

typedef unsigned short ushort_t;
typedef unsigned int uint_t;
typedef __attribute__((ext_vector_type(8))) short short8v;
typedef __attribute__((ext_vector_type(4))) float f32x4;
typedef __attribute__((ext_vector_type(2))) float f32x2;

union U8 { ushort_t u[8]; short8v v; uint4 q; };

__device__ __forceinline__ ushort_t f2bf(float f) {
  uint_t u = __builtin_bit_cast(uint_t, f);
  u += 0x7FFF + ((u >> 16) & 1);  // RNE
  return (ushort_t)(u >> 16);
}
__device__ __forceinline__ float bflo(uint_t u) {
  return __builtin_bit_cast(float, u << 16);
}
__device__ __forceinline__ float bfhi(uint_t u) {
  return __builtin_bit_cast(float, u & 0xFFFF0000u);
}

// ---------------- fp8 encode/decode (HW cvt preferred) -----------------------
#if __has_builtin(__builtin_amdgcn_cvt_pk_fp8_f32) && \
    __has_builtin(__builtin_amdgcn_cvt_pk_f32_fp8)
__device__ __forceinline__ uint_t fp8_pack4(float f0, float f1, float f2,
                                            float f3) {
  int p = 0;
  p = __builtin_amdgcn_cvt_pk_fp8_f32(f0, f1, p, false);
  p = __builtin_amdgcn_cvt_pk_fp8_f32(f2, f3, p, true);
  return (uint_t)p;
}
__device__ __forceinline__ void fp8_unpack4(uint_t w, float* o) {
  f32x2 d0 = __builtin_amdgcn_cvt_pk_f32_fp8((int)w, false);
  f32x2 d1 = __builtin_amdgcn_cvt_pk_f32_fp8((int)w, true);
  o[0] = d0.x; o[1] = d0.y; o[2] = d1.x; o[3] = d1.y;
}
#else
__device__ __forceinline__ uint_t fp8_enc1(float f) {
  uint_t u = __builtin_bit_cast(uint_t, f);
  uint_t s = (u >> 24) & 0x80u;
  int e = (int)((u >> 23) & 0xFF) - 127;
  if (e < -9) return s;
  if (e < -6) {
    float af = __builtin_bit_cast(float, u & 0x7FFFFFFFu);
    uint_t m = (uint_t)(af * 512.f + 0.5f);
    return s | m;
  }
  uint_t mant = u & 0x7FFFFF;
  uint_t keep = mant >> 20;
  uint_t rest = mant & 0xFFFFF;
  keep += (rest > 0x80000u) || (rest == 0x80000u && (keep & 1));
  uint_t ee = (uint_t)(e + 7);
  if (keep == 8) { keep = 0; ee += 1; }
  if (ee > 15 || (ee == 15 && keep > 6)) return s | 0x7E;
  return s | (ee << 3) | keep;
}
__device__ __forceinline__ float fp8_dec1(uint_t b) {
  uint_t s = (b & 0x80u) << 24;
  uint_t e = (b >> 3) & 15u, m = b & 7u;
  if (e == 0) {
    float v = (float)m * (1.0f / 512.0f);
    return __builtin_bit_cast(float, s | __builtin_bit_cast(uint_t, v));
  }
  return __builtin_bit_cast(float, s | ((e + 120u) << 23) | (m << 20));
}
__device__ __forceinline__ uint_t fp8_pack4(float f0, float f1, float f2,
                                            float f3) {
  return fp8_enc1(f0) | (fp8_enc1(f1) << 8) | (fp8_enc1(f2) << 16) |
         (fp8_enc1(f3) << 24);
}
__device__ __forceinline__ void fp8_unpack4(uint_t w, float* o) {
  o[0] = fp8_dec1(w & 0xFF); o[1] = fp8_dec1((w >> 8) & 0xFF);
  o[2] = fp8_dec1((w >> 16) & 0xFF); o[3] = fp8_dec1(w >> 24);
}
#endif

// ---- weight prep: bf16, transposed + column-permuted for the fused gemms ----
// WT1[n][k] = bf16(W1[k][ (n&15)*8 + (n>>4) ]),  n,k in [0,128)
// WT2[n][k] = bf16(W2[k][ (n&15)*4 + (n>>4) ]),  n in [0,64), k in [0,128)
__global__ __launch_bounds__(256) void wt_prep_kernel(
    const float* __restrict__ W1, const float* __restrict__ W2,
    ushort_t* __restrict__ WT1, ushort_t* __restrict__ WT2) {
  int i = blockIdx.x * 256 + threadIdx.x;
  if (i < 128 * 128) {
    int n = i >> 7, k = i & 127;
    int c = (n & 15) * 8 + (n >> 4);
    WT1[i] = f2bf(W1[k * 128 + c]);
  } else {
    int j = i - 128 * 128;
    if (j < 64 * 128) {
      int n = j >> 7, k = j & 127;
      int c = (n & 15) * 4 + (n >> 4);
      WT2[j] = f2bf(W2[k * 64 + c]);
    }
  }
}

// ---------- MFMA GEMM1 (fused layer-1 prep; no LDS, B from L1-resident WT1) --
// 64 rows/block, wave = 16 rows. Lane rlo's accumulators = channels 8*rlo+nf
// (contiguous, single head rlo>>1) -> linear fp8 h8 + asn1/adn1 via 1 shfl.
__global__ __launch_bounds__(256) void mfma_gemm1_kernel(
    const float* __restrict__ X, const ushort_t* __restrict__ WT1,
    const float* __restrict__ a_src, const float* __restrict__ a_dst,
    uint2* __restrict__ h8, float* __restrict__ asn, float* __restrict__ adn,
    int nrows) {
  const int tid = threadIdx.x;
  const int wave = tid >> 6, lane = tid & 63;
  const int row0 = blockIdx.x * 64 + wave * 16;
  const int rlo = lane & 15, khi = lane >> 4;  // khi in 0..3

  f32x4 acc[8];
#pragma unroll
  for (int n = 0; n < 8; ++n) acc[n] = (f32x4){0.f, 0.f, 0.f, 0.f};

#pragma unroll
  for (int ks = 0; ks < 4; ++ks) {
    const int kk = ks * 32 + khi * 8;
    int row = row0 + rlo;
    if (row >= nrows) row = nrows - 1;
    const float4* xp = (const float4*)(X + (size_t)row * 128 + kk);
    float4 u = xp[0], v = xp[1];
    U8 t;
    t.u[0] = f2bf(u.x); t.u[1] = f2bf(u.y); t.u[2] = f2bf(u.z); t.u[3] = f2bf(u.w);
    t.u[4] = f2bf(v.x); t.u[5] = f2bf(v.y); t.u[6] = f2bf(v.z); t.u[7] = f2bf(v.w);
    short8v a = t.v;
#pragma unroll
    for (int nf = 0; nf < 8; ++nf) {
      short8v b = *(const short8v*)(WT1 + (nf * 16 + rlo) * 128 + kk);
      acc[nf] = __builtin_amdgcn_mfma_f32_16x16x32_bf16(a, b, acc[nf], 0, 0, 0);
    }
  }
  // a_src/a_dst flat [8][16]; lane's 8 channels = flat rlo*8 .. rlo*8+7.
  const float4* as4 = (const float4*)a_src;
  const float4* ad4 = (const float4*)a_dst;
  float4 as0 = as4[rlo * 2], as1 = as4[rlo * 2 + 1];
  float4 ad0 = ad4[rlo * 2], ad1 = ad4[rlo * 2 + 1];
  // C/D layout: col = lane&15, row = (lane>>4)*4 + reg  [m89-verified]
  int rbase = row0 + khi * 4;
#pragma unroll
  for (int r = 0; r < 4; ++r) {
    int row = rbase + r;
    bool ok = (row < nrows);   // uniform across each lane-pair (rlo, rlo^1)
    uint2 pk;
    pk.x = fp8_pack4(acc[0][r], acc[1][r], acc[2][r], acc[3][r]);
    pk.y = fp8_pack4(acc[4][r], acc[5][r], acc[6][r], acc[7][r]);
    if (ok) h8[(size_t)row * 16 + rlo] = pk;
    float s = acc[0][r] * as0.x + acc[1][r] * as0.y +
              acc[2][r] * as0.z + acc[3][r] * as0.w +
              acc[4][r] * as1.x + acc[5][r] * as1.y +
              acc[6][r] * as1.z + acc[7][r] * as1.w;
    float d = acc[0][r] * ad0.x + acc[1][r] * ad0.y +
              acc[2][r] * ad0.z + acc[3][r] * ad0.w +
              acc[4][r] * ad1.x + acc[5][r] * ad1.y +
              acc[6][r] * ad1.z + acc[7][r] * ad1.w;
    s += __shfl_xor(s, 1);     // pair (rlo, rlo^1) = full 16-ch head
    d += __shfl_xor(d, 1);
    if (ok && (rlo & 1) == 0) {
      asn[row * 8 + (rlo >> 1)] = s;
      adn[row * 8 + (rlo >> 1)] = d;
    }
  }
}

// ---------- MFMA GEMM2 (fused layer-2 prep; no LDS, B from WT2) --------------
__global__ __launch_bounds__(256) void mfma_gemm2_kernel(
    const ushort_t* __restrict__ X2, const ushort_t* __restrict__ WT2,
    const float* __restrict__ a_src, const float* __restrict__ a_dst,
    uint_t* __restrict__ h28, float* __restrict__ asn, float* __restrict__ adn,
    int nrows) {
  const int tid = threadIdx.x;
  const int wave = tid >> 6, lane = tid & 63;
  const int row0 = blockIdx.x * 64 + wave * 16;
  const int rlo = lane & 15, khi = lane >> 4;

  f32x4 acc[4];
#pragma unroll
  for (int n = 0; n < 4; ++n) acc[n] = (f32x4){0.f, 0.f, 0.f, 0.f};

#pragma unroll
  for (int ks = 0; ks < 4; ++ks) {
    const int kk = ks * 32 + khi * 8;
    int row = row0 + rlo;
    if (row >= nrows) row = nrows - 1;
    U8 t;
    t.q = *(const uint4*)(X2 + (size_t)row * 128 + kk);
    short8v a = t.v;
#pragma unroll
    for (int nf = 0; nf < 4; ++nf) {
      short8v b = *(const short8v*)(WT2 + (nf * 16 + rlo) * 128 + kk);
      acc[nf] = __builtin_amdgcn_mfma_f32_16x16x32_bf16(a, b, acc[nf], 0, 0, 0);
    }
  }
  float4 as = ((const float4*)a_src)[rlo];  // channels 4*rlo..4*rlo+3
  float4 ad = ((const float4*)a_dst)[rlo];
  int rbase = row0 + khi * 4;
#pragma unroll
  for (int r = 0; r < 4; ++r) {
    int row = rbase + r;
    bool ok = (row < nrows);   // uniform across the 16-lane rlo group
    uint_t pk = fp8_pack4(acc[0][r], acc[1][r], acc[2][r], acc[3][r]);
    if (ok) h28[(size_t)row * 16 + rlo] = pk;
    float s = acc[0][r] * as.x + acc[1][r] * as.y +
              acc[2][r] * as.z + acc[3][r] * as.w;
    float d = acc[0][r] * ad.x + acc[1][r] * ad.y +
              acc[2][r] * ad.z + acc[3][r] * ad.w;
    s += __shfl_xor(s, 1); s += __shfl_xor(s, 2);
    s += __shfl_xor(s, 4); s += __shfl_xor(s, 8);
    d += __shfl_xor(d, 1); d += __shfl_xor(d, 2);
    d += __shfl_xor(d, 4); d += __shfl_xor(d, 8);
    if (ok && rlo == 0) { asn[row] = s; adn[row] = d; }
  }
}

// ------------------ CSR build: two-level multisplit by dst -------------------
__global__ __launch_bounds__(512) void bucket_count_kernel(
    const int* __restrict__ dstA, int* __restrict__ cnt) {
  __shared__ int histL[NBUK];
  int b = blockIdx.x, t = threadIdx.x;
  for (int i = t; i < NBUK; i += 512) histL[i] = 0;
  __syncthreads();
  int e0 = b * CHUNK, e1 = min(e0 + CHUNK, EN);
  for (int e = e0 + t; e < e1; e += 512) {
    int d = (e < NE) ? dstA[e] : (e - NE);
    atomicAdd(&histL[d >> BSH], 1);
  }
  __syncthreads();
  for (int i = t; i < NBUK; i += 512) cnt[i * NBLK + b] = histL[i];
}

__global__ __launch_bounds__(256) void bucket_scan_kernel(
    int* __restrict__ cnt, int* __restrict__ bucket_base) {
  __shared__ int colsum[NBUK];
  int t = threadIdx.x;
  if (t < NBUK) {
    int run = 0;
    int* c = cnt + t * NBLK;
    for (int b = 0; b < NBLK; ++b) { int v = c[b]; c[b] = run; run += v; }
    colsum[t] = run;
  }
  __syncthreads();
  if (t == 0) {
    int base = 0;
    for (int j = 0; j < NBUK; ++j) {
      bucket_base[j] = base;
      int v = colsum[j];
      colsum[j] = base;
      base += v;
    }
    bucket_base[NBUK] = base;  // == EN
  }
  __syncthreads();
  if (t < NBUK) {
    int bb = colsum[t];
    int* c = cnt + t * NBLK;
    for (int b = 0; b < NBLK; ++b) c[b] += bb;
  }
}

__global__ __launch_bounds__(512) void bucket_scatter_kernel(
    const int* __restrict__ srcA, const int* __restrict__ dstA,
    const int* __restrict__ cnt, int* __restrict__ staging) {
  __shared__ int cur[NBUK];
  int b = blockIdx.x, t = threadIdx.x;
  for (int i = t; i < NBUK; i += 512) cur[i] = cnt[i * NBLK + b];
  __syncthreads();
  int e0 = b * CHUNK, e1 = min(e0 + CHUNK, EN);
  for (int e = e0 + t; e < e1; e += 512) {
    int s, d;
    if (e < NE) { s = srcA[e]; d = dstA[e]; } else { s = e - NE; d = s; }
    int pos = atomicAdd(&cur[d >> BSH], 1);
    staging[pos] = s | ((d & (BKN - 1)) << 17);
  }
}

// P3: per-bucket fine CSR: LDS histogram -> scan -> rp -> direct scatter.
__global__ __launch_bounds__(512) void bucket_csr_kernel(
    const int* __restrict__ staging, const int* __restrict__ bucket_base,
    int* __restrict__ rp, int* __restrict__ col) {
  __shared__ int degL[BKN];
  __shared__ int exclL[BKN];
  __shared__ int sdata[2][BKN];
  int bk = blockIdx.x, t = threadIdx.x;
  int ebase = bucket_base[bk], eend = bucket_base[bk + 1];
  int ecnt = eend - ebase;
  degL[t] = 0;
  __syncthreads();
  for (int e = t; e < ecnt; e += 512)
    atomicAdd(&degL[staging[ebase + e] >> 17], 1);
  __syncthreads();
  int v = degL[t];
  sdata[0][t] = v;
  __syncthreads();
  int sp = 0;
  for (int off = 1; off < BKN; off <<= 1) {
    int val = sdata[sp][t];
    if (t >= off) val += sdata[sp][t - off];
    sdata[sp ^ 1][t] = val;
    __syncthreads();
    sp ^= 1;
  }
  int ex = sdata[sp][t] - v;  // local exclusive offset
  exclL[t] = ex;
  int node = bk * BKN + t;
  if (node < NN) rp[node] = ebase + ex;
  if (bk == 0 && t == 0) rp[NN] = EN;
  __syncthreads();
  for (int e = t; e < ecnt; e += 512) {
    int pk = staging[ebase + e];
    int pos = atomicAdd(&exclL[pk >> 17], 1);
    col[ebase + pos] = pk & 0x1FFFF;
  }
}

// ------ layer-1 gather: 16 lanes/node, 8 ch/lane, fp8 h1 payload -------------
__global__ __launch_bounds__(256) void gather1_kernel(
    const int* __restrict__ rp, const int* __restrict__ col,
    const float* __restrict__ asn, const float* __restrict__ adn,
    const uint2* __restrict__ h8, const float* __restrict__ b1,
    ushort_t* __restrict__ x2) {
  int node = (blockIdx.x << 4) + (threadIdx.x >> 4);
  if (node >= NN) return;
  int lane = threadIdx.x & 15;
  int head = lane >> 1;
  float aD = adn[node * 8 + head];
  int p = rp[node], p1 = rp[node + 1];
  float a0 = 0, a1 = 0, a2 = 0, a3 = 0, a4 = 0, a5 = 0, a6 = 0, a7 = 0;
  float den = 0.f;

  for (; p + 1 < p1; p += 2) {
    int s0 = col[p], s1 = col[p + 1];
    float e0 = asn[s0 * 8 + head] + aD;
    float e1 = asn[s1 * 8 + head] + aD;
    uint2 q0 = h8[(size_t)s0 * 16 + lane];
    uint2 q1 = h8[(size_t)s1 * 16 + lane];
    e0 = e0 > 0.f ? e0 : NEG * e0;
    e1 = e1 > 0.f ? e1 : NEG * e1;
    float ee0 = __expf(e0), ee1 = __expf(e1);
    float d0[4], d1[4], d2[4], d3[4];
    fp8_unpack4(q0.x, d0); fp8_unpack4(q0.y, d1);
    fp8_unpack4(q1.x, d2); fp8_unpack4(q1.y, d3);
    a0 += ee0 * d0[0] + ee1 * d2[0];
    a1 += ee0 * d0[1] + ee1 * d2[1];
    a2 += ee0 * d0[2] + ee1 * d2[2];
    a3 += ee0 * d0[3] + ee1 * d2[3];
    a4 += ee0 * d1[0] + ee1 * d3[0];
    a5 += ee0 * d1[1] + ee1 * d3[1];
    a6 += ee0 * d1[2] + ee1 * d3[2];
    a7 += ee0 * d1[3] + ee1 * d3[3];
    den += ee0 + ee1;
  }
  if (p < p1) {
    int s0 = col[p];
    float e0 = asn[s0 * 8 + head] + aD;
    uint2 q0 = h8[(size_t)s0 * 16 + lane];
    e0 = e0 > 0.f ? e0 : NEG * e0;
    float ee0 = __expf(e0);
    float d0[4], d1[4];
    fp8_unpack4(q0.x, d0); fp8_unpack4(q0.y, d1);
    a0 += ee0 * d0[0]; a1 += ee0 * d0[1]; a2 += ee0 * d0[2]; a3 += ee0 * d0[3];
    a4 += ee0 * d1[0]; a5 += ee0 * d1[1]; a6 += ee0 * d1[2]; a7 += ee0 * d1[3];
    den += ee0;
  }
  float inv = 1.f / den;
  const float4* b4 = (const float4*)b1;
  float4 ba = b4[lane * 2 + 0], bb = b4[lane * 2 + 1];
  float o0 = fmaf(a0, inv, ba.x), o1 = fmaf(a1, inv, ba.y);
  float o2 = fmaf(a2, inv, ba.z), o3 = fmaf(a3, inv, ba.w);
  float o4 = fmaf(a4, inv, bb.x), o5 = fmaf(a5, inv, bb.y);
  float o6 = fmaf(a6, inv, bb.z), o7 = fmaf(a7, inv, bb.w);
  o0 = o0 > 0.f ? o0 : __expf(o0) - 1.f;
  o1 = o1 > 0.f ? o1 : __expf(o1) - 1.f;
  o2 = o2 > 0.f ? o2 : __expf(o2) - 1.f;
  o3 = o3 > 0.f ? o3 : __expf(o3) - 1.f;
  o4 = o4 > 0.f ? o4 : __expf(o4) - 1.f;
  o5 = o5 > 0.f ? o5 : __expf(o5) - 1.f;
  o6 = o6 > 0.f ? o6 : __expf(o6) - 1.f;
  o7 = o7 > 0.f ? o7 : __expf(o7) - 1.f;
  U8 t;
  t.u[0] = f2bf(o0); t.u[1] = f2bf(o1); t.u[2] = f2bf(o2); t.u[3] = f2bf(o3);
  t.u[4] = f2bf(o4); t.u[5] = f2bf(o5); t.u[6] = f2bf(o6); t.u[7] = f2bf(o7);
  ((uint4*)(x2 + (size_t)node * F1))[lane] = t.q;
}

// ------ layer-2 gather: 16 lanes/node, 4 ch/lane, fp8 h2 + log_softmax ------
__global__ __launch_bounds__(256) void gather2_kernel(
    const int* __restrict__ rp, const int* __restrict__ col,
    const float* __restrict__ asn, const float* __restrict__ adn,
    const uint_t* __restrict__ h28, const float* __restrict__ b2,
    float* __restrict__ out) {
  int node = (blockIdx.x << 4) + (threadIdx.x >> 4);
  if (node >= NN) return;
  int lane = threadIdx.x & 15;
  float aD = adn[node];
  int p = rp[node], p1 = rp[node + 1];
  float a0 = 0, a1 = 0, a2 = 0, a3 = 0, den = 0.f;

  for (; p + 1 < p1; p += 2) {
    int s0 = col[p], s1 = col[p + 1];
    float e0 = asn[s0] + aD;
    float e1 = asn[s1] + aD;
    uint_t q0 = h28[(size_t)s0 * 16 + lane];
    uint_t q1 = h28[(size_t)s1 * 16 + lane];
    e0 = e0 > 0.f ? e0 : NEG * e0;
    e1 = e1 > 0.f ? e1 : NEG * e1;
    float ee0 = __expf(e0), ee1 = __expf(e1);
    float d0[4], d1[4];
    fp8_unpack4(q0, d0); fp8_unpack4(q1, d1);
    a0 += ee0 * d0[0] + ee1 * d1[0];
    a1 += ee0 * d0[1] + ee1 * d1[1];
    a2 += ee0 * d0[2] + ee1 * d1[2];
    a3 += ee0 * d0[3] + ee1 * d1[3];
    den += ee0 + ee1;
  }
  if (p < p1) {
    int s0 = col[p];
    float e0 = asn[s0] + aD;
    uint_t q0 = h28[(size_t)s0 * 16 + lane];
    e0 = e0 > 0.f ? e0 : NEG * e0;
    float ee0 = __expf(e0);
    float d0[4];
    fp8_unpack4(q0, d0);
    a0 += ee0 * d0[0]; a1 += ee0 * d0[1]; a2 += ee0 * d0[2]; a3 += ee0 * d0[3];
    den += ee0;
  }
  float inv = 1.f / den;
  float4 bv = ((const float4*)b2)[lane];
  float v0 = fmaf(a0, inv, bv.x), v1 = fmaf(a1, inv, bv.y);
  float v2 = fmaf(a2, inv, bv.z), v3 = fmaf(a3, inv, bv.w);
  float m = fmaxf(fmaxf(v0, v1), fmaxf(v2, v3));
#pragma unroll
  for (int k = 1; k < 16; k <<= 1) m = fmaxf(m, __shfl_xor(m, k));
  float ex = __expf(v0 - m) + __expf(v1 - m) + __expf(v2 - m) + __expf(v3 - m);
#pragma unroll
  for (int k = 1; k < 16; k <<= 1) ex += __shfl_xor(ex, k);
  float lse = m + __logf(ex);
  float4 r = {v0 - lse, v1 - lse, v2 - lse, v3 - lse};
  ((float4*)(out + (size_t)node * NC))[lane] = r;
}

extern "C" void kernel_launch(void* const* d_in, const int* in_sizes, int n_in,
                              void* d_out, int out_size, void* d_ws,
                              size_t ws_size, hipStream_t stream) {
  const float* x = (const float*)d_in[0];
  const int* edge_index = (const int*)d_in[1];
  const float* W1 = (const float*)d_in[2];
  const float* a_src1 = (const float*)d_in[3];
  const float* a_dst1 = (const float*)d_in[4];
  const float* b1 = (const float*)d_in[5];
  const float* W2 = (const float*)d_in[6];
  const float* a_src2 = (const float*)d_in[7];
  const float* a_dst2 = (const float*)d_in[8];
  const float* b2 = (const float*)d_in[9];
  float* out = (float*)d_out;
  float* ws = (float*)d_ws;

  // workspace layout (float offsets), non-overlapping:
  ushort_t* x2b = (ushort_t*)ws;               // [0, 6.4M)   bf16 x2
  uint2* h8 = (uint2*)(ws + 6400000);          // [6.4M, 9.6M)  fp8 h1 (linear)
  uint_t* h28 = (uint_t*)(ws + 9600000);       // [9.6M, 11.2M) fp8 h2 (linear)
  float* asn1 = ws + 11200000;                 // [11.2M, 12.0M)
  float* adn1 = ws + 12000000;                 // [12.0M, 12.8M)
  float* asn2 = ws + 12800000;                 // [12.8M, 12.9M)
  float* adn2 = ws + 12900000;                 // [12.9M, 13.0M)
  ushort_t* WT1 = (ushort_t*)(ws + 13000000);  // 16384 bf16 (8192 floats)
  ushort_t* WT2 = (ushort_t*)(ws + 13010000);  // 8192 bf16  (4096 floats)
  int* rp = (int*)(ws + 13020000);             // NN+1
  int* col = rp + NN + 1;                      // EN
  int* staging = col + EN;                     // EN
  int* cnt = staging + EN;                     // NBUK*NBLK
  int* bucket_base = cnt + NBUK * NBLK;        // NBUK+1  (~16.7M floats)

  const int* srcA = edge_index;
  const int* dstA = edge_index + NE;

  // ---- CSR build (multisplit) + weight prep ----
  wt_prep_kernel<<<(128 * 128 + 64 * 128 + 255) / 256, 256, 0, stream>>>(
      W1, W2, WT1, WT2);
  bucket_count_kernel<<<NBLK, 512, 0, stream>>>(dstA, cnt);
  bucket_scan_kernel<<<1, 256, 0, stream>>>(cnt, bucket_base);
  bucket_scatter_kernel<<<NBLK, 512, 0, stream>>>(srcA, dstA, cnt, staging);
  bucket_csr_kernel<<<NBUK, 512, 0, stream>>>(staging, bucket_base, rp, col);

  // ---- layer 1 (gemm + fp8 + attn fused; LDS-free) ----
  mfma_gemm1_kernel<<<(NN + 63) / 64, 256, 0, stream>>>(
      x, WT1, a_src1, a_dst1, h8, asn1, adn1, NN);
  gather1_kernel<<<(NN + 15) / 16, 256, 0, stream>>>(rp, col, asn1, adn1, h8,
                                                     b1, x2b);
  // ---- layer 2 (gemm + fp8 + attn fused; LDS-free) ----
  mfma_gemm2_kernel<<<(NN + 63) / 64, 256, 0, stream>>>(
      x2b, WT2, a_src2, a_dst2, h28, asn2, adn2, NN);
  gather2_kernel<<<(NN + 15) / 16, 256, 0, stream>>>(rp, col, asn2, adn2, h28,
                                                     b2, out);
}

// Round 15
// 217.923 us; speedup vs baseline: 1.6475x; 1.0944x over previous
//
#include <hip/hip_runtime.h>

#define NN 100000
#define NE 1600000
#define EN (NE + NN)          // edges incl. self-loops
#define FIN 128
#define H1 8
#define C1 16
#define F1 128                // H1*C1
#define NC 64
#define NEG 0.2f

// ---- CSR-build multisplit parameters ----
#define BSH 9                 // bucket = dst >> BSH
#define BKN 512               // nodes per bucket
#define NBUK ((NN + BKN - 1) / BKN)   // 196
#define NBLK 256              // edge-chunk blocks for P1/P2
#define CHUNK ((EN + NBLK - 1) / NBLK) // 6641

typedef unsigned short ushort_t;
typedef unsigned int uint_t;
typedef __attribute__((ext_vector_type(8))) short short8v;
typedef __attribute__((ext_vector_type(4))) float f32x4;
typedef __attribute__((ext_vector_type(2))) float f32x2;

union U8 { ushort_t u[8]; short8v v; uint4 q; };

__device__ __forceinline__ ushort_t f2bf(float f) {
  uint_t u = __builtin_bit_cast(uint_t, f);
  u += 0x7FFF + ((u >> 16) & 1);  // RNE
  return (ushort_t)(u >> 16);
}
__device__ __forceinline__ float bflo(uint_t u) {
  return __builtin_bit_cast(float, u << 16);
}
__device__ __forceinline__ float bfhi(uint_t u) {
  return __builtin_bit_cast(float, u & 0xFFFF0000u);
}

// ---------------- fp8 encode/decode (HW cvt preferred) -----------------------
#if __has_builtin(__builtin_amdgcn_cvt_pk_fp8_f32) && \
    __has_builtin(__builtin_amdgcn_cvt_pk_f32_fp8)
__device__ __forceinline__ uint_t fp8_pack4(float f0, float f1, float f2,
                                            float f3) {
  int p = 0;
  p = __builtin_amdgcn_cvt_pk_fp8_f32(f0, f1, p, false);
  p = __builtin_amdgcn_cvt_pk_fp8_f32(f2, f3, p, true);
  return (uint_t)p;
}
__device__ __forceinline__ void fp8_unpack4(uint_t w, float* o) {
  f32x2 d0 = __builtin_amdgcn_cvt_pk_f32_fp8((int)w, false);
  f32x2 d1 = __builtin_amdgcn_cvt_pk_f32_fp8((int)w, true);
  o[0] = d0.x; o[1] = d0.y; o[2] = d1.x; o[3] = d1.y;
}
#else
__device__ __forceinline__ uint_t fp8_enc1(float f) {
  uint_t u = __builtin_bit_cast(uint_t, f);
  uint_t s = (u >> 24) & 0x80u;
  int e = (int)((u >> 23) & 0xFF) - 127;
  if (e < -9) return s;
  if (e < -6) {
    float af = __builtin_bit_cast(float, u & 0x7FFFFFFFu);
    uint_t m = (uint_t)(af * 512.f + 0.5f);
    return s | m;
  }
  uint_t mant = u & 0x7FFFFF;
  uint_t keep = mant >> 20;
  uint_t rest = mant & 0xFFFFF;
  keep += (rest > 0x80000u) || (rest == 0x80000u && (keep & 1));
  uint_t ee = (uint_t)(e + 7);
  if (keep == 8) { keep = 0; ee += 1; }
  if (ee > 15 || (ee == 15 && keep > 6)) return s | 0x7E;
  return s | (ee << 3) | keep;
}
__device__ __forceinline__ float fp8_dec1(uint_t b) {
  uint_t s = (b & 0x80u) << 24;
  uint_t e = (b >> 3) & 15u, m = b & 7u;
  if (e == 0) {
    float v = (float)m * (1.0f / 512.0f);
    return __builtin_bit_cast(float, s | __builtin_bit_cast(uint_t, v));
  }
  return __builtin_bit_cast(float, s | ((e + 120u) << 23) | (m << 20));
}
__device__ __forceinline__ uint_t fp8_pack4(float f0, float f1, float f2,
                                            float f3) {
  return fp8_enc1(f0) | (fp8_enc1(f1) << 8) | (fp8_enc1(f2) << 16) |
         (fp8_enc1(f3) << 24);
}
__device__ __forceinline__ void fp8_unpack4(uint_t w, float* o) {
  o[0] = fp8_dec1(w & 0xFF); o[1] = fp8_dec1((w >> 8) & 0xFF);
  o[2] = fp8_dec1((w >> 16) & 0xFF); o[3] = fp8_dec1(w >> 24);
}
#endif

// ---------- MFMA GEMM1 (fused layer-1 prep; no LDS, B from L1-resident WT1) --
__global__ __launch_bounds__(256) void mfma_gemm1_kernel(
    const float* __restrict__ X, const ushort_t* __restrict__ WT1,
    const float* __restrict__ a_src, const float* __restrict__ a_dst,
    uint2* __restrict__ h8, float* __restrict__ asn, float* __restrict__ adn,
    int nrows) {
  const int tid = threadIdx.x;
  const int wave = tid >> 6, lane = tid & 63;
  const int row0 = blockIdx.x * 64 + wave * 16;
  const int rlo = lane & 15, khi = lane >> 4;  // khi in 0..3

  f32x4 acc[8];
#pragma unroll
  for (int n = 0; n < 8; ++n) acc[n] = (f32x4){0.f, 0.f, 0.f, 0.f};

#pragma unroll
  for (int ks = 0; ks < 4; ++ks) {
    const int kk = ks * 32 + khi * 8;
    int row = row0 + rlo;
    if (row >= nrows) row = nrows - 1;
    const float4* xp = (const float4*)(X + (size_t)row * 128 + kk);
    float4 u = xp[0], v = xp[1];
    U8 t;
    t.u[0] = f2bf(u.x); t.u[1] = f2bf(u.y); t.u[2] = f2bf(u.z); t.u[3] = f2bf(u.w);
    t.u[4] = f2bf(v.x); t.u[5] = f2bf(v.y); t.u[6] = f2bf(v.z); t.u[7] = f2bf(v.w);
    short8v a = t.v;
#pragma unroll
    for (int nf = 0; nf < 8; ++nf) {
      short8v b = *(const short8v*)(WT1 + (nf * 16 + rlo) * 128 + kk);
      acc[nf] = __builtin_amdgcn_mfma_f32_16x16x32_bf16(a, b, acc[nf], 0, 0, 0);
    }
  }
  const float4* as4 = (const float4*)a_src;
  const float4* ad4 = (const float4*)a_dst;
  float4 as0 = as4[rlo * 2], as1 = as4[rlo * 2 + 1];
  float4 ad0 = ad4[rlo * 2], ad1 = ad4[rlo * 2 + 1];
  int rbase = row0 + khi * 4;
#pragma unroll
  for (int r = 0; r < 4; ++r) {
    int row = rbase + r;
    bool ok = (row < nrows);
    uint2 pk;
    pk.x = fp8_pack4(acc[0][r], acc[1][r], acc[2][r], acc[3][r]);
    pk.y = fp8_pack4(acc[4][r], acc[5][r], acc[6][r], acc[7][r]);
    if (ok) h8[(size_t)row * 16 + rlo] = pk;
    float s = acc[0][r] * as0.x + acc[1][r] * as0.y +
              acc[2][r] * as0.z + acc[3][r] * as0.w +
              acc[4][r] * as1.x + acc[5][r] * as1.y +
              acc[6][r] * as1.z + acc[7][r] * as1.w;
    float d = acc[0][r] * ad0.x + acc[1][r] * ad0.y +
              acc[2][r] * ad0.z + acc[3][r] * ad0.w +
              acc[4][r] * ad1.x + acc[5][r] * ad1.y +
              acc[6][r] * ad1.z + acc[7][r] * ad1.w;
    s += __shfl_xor(s, 1);
    d += __shfl_xor(d, 1);
    if (ok && (rlo & 1) == 0) {
      asn[row * 8 + (rlo >> 1)] = s;
      adn[row * 8 + (rlo >> 1)] = d;
    }
  }
}

// ---------- MFMA GEMM2 (fused layer-2 prep; no LDS, B from WT2) --------------
__global__ __launch_bounds__(256) void mfma_gemm2_kernel(
    const ushort_t* __restrict__ X2, const ushort_t* __restrict__ WT2,
    const float* __restrict__ a_src, const float* __restrict__ a_dst,
    uint_t* __restrict__ h28, float* __restrict__ asn, float* __restrict__ adn,
    int nrows) {
  const int tid = threadIdx.x;
  const int wave = tid >> 6, lane = tid & 63;
  const int row0 = blockIdx.x * 64 + wave * 16;
  const int rlo = lane & 15, khi = lane >> 4;

  f32x4 acc[4];
#pragma unroll
  for (int n = 0; n < 4; ++n) acc[n] = (f32x4){0.f, 0.f, 0.f, 0.f};

#pragma unroll
  for (int ks = 0; ks < 4; ++ks) {
    const int kk = ks * 32 + khi * 8;
    int row = row0 + rlo;
    if (row >= nrows) row = nrows - 1;
    U8 t;
    t.q = *(const uint4*)(X2 + (size_t)row * 128 + kk);
    short8v a = t.v;
#pragma unroll
    for (int nf = 0; nf < 4; ++nf) {
      short8v b = *(const short8v*)(WT2 + (nf * 16 + rlo) * 128 + kk);
      acc[nf] = __builtin_amdgcn_mfma_f32_16x16x32_bf16(a, b, acc[nf], 0, 0, 0);
    }
  }
  float4 as = ((const float4*)a_src)[rlo];
  float4 ad = ((const float4*)a_dst)[rlo];
  int rbase = row0 + khi * 4;
#pragma unroll
  for (int r = 0; r < 4; ++r) {
    int row = rbase + r;
    bool ok = (row < nrows);
    uint_t pk = fp8_pack4(acc[0][r], acc[1][r], acc[2][r], acc[3][r]);
    if (ok) h28[(size_t)row * 16 + rlo] = pk;
    float s = acc[0][r] * as.x + acc[1][r] * as.y +
              acc[2][r] * as.z + acc[3][r] * as.w;
    float d = acc[0][r] * ad.x + acc[1][r] * ad.y +
              acc[2][r] * ad.z + acc[3][r] * ad.w;
    s += __shfl_xor(s, 1); s += __shfl_xor(s, 2);
    s += __shfl_xor(s, 4); s += __shfl_xor(s, 8);
    d += __shfl_xor(d, 1); d += __shfl_xor(d, 2);
    d += __shfl_xor(d, 4); d += __shfl_xor(d, 8);
    if (ok && rlo == 0) { asn[row] = s; adn[row] = d; }
  }
}

// ------------------ CSR build: two-level multisplit by dst -------------------
// (wt_prep fused into bucket_count: blocks cover 24576 weight elements too)
__global__ __launch_bounds__(512) void bucket_count_kernel(
    const int* __restrict__ dstA, int* __restrict__ cnt,
    const float* __restrict__ W1, const float* __restrict__ W2,
    ushort_t* __restrict__ WT1, ushort_t* __restrict__ WT2) {
  __shared__ int histL[NBUK];
  int b = blockIdx.x, t = threadIdx.x;
  // fused weight prep: first 48 blocks handle 128*128 + 64*128 elements
  int gid = b * 512 + t;
  if (gid < 128 * 128) {
    int n = gid >> 7, k = gid & 127;
    int c = (n & 15) * 8 + (n >> 4);
    WT1[gid] = f2bf(W1[k * 128 + c]);
  } else if (gid < 128 * 128 + 64 * 128) {
    int j = gid - 128 * 128;
    int n = j >> 7, k = j & 127;
    int c = (n & 15) * 4 + (n >> 4);
    WT2[j] = f2bf(W2[k * 64 + c]);
  }
  for (int i = t; i < NBUK; i += 512) histL[i] = 0;
  __syncthreads();
  int e0 = b * CHUNK, e1 = min(e0 + CHUNK, EN);
  for (int e = e0 + t; e < e1; e += 512) {
    int d = (e < NE) ? dstA[e] : (e - NE);
    atomicAdd(&histL[d >> BSH], 1);
  }
  __syncthreads();
  for (int i = t; i < NBUK; i += 512) cnt[i * NBLK + b] = histL[i];
}

__global__ __launch_bounds__(256) void bucket_scan_kernel(
    int* __restrict__ cnt, int* __restrict__ bucket_base) {
  __shared__ int colsum[NBUK];
  int t = threadIdx.x;
  if (t < NBUK) {
    int run = 0;
    int* c = cnt + t * NBLK;
    for (int b = 0; b < NBLK; ++b) { int v = c[b]; c[b] = run; run += v; }
    colsum[t] = run;
  }
  __syncthreads();
  if (t == 0) {
    int base = 0;
    for (int j = 0; j < NBUK; ++j) {
      bucket_base[j] = base;
      int v = colsum[j];
      colsum[j] = base;
      base += v;
    }
    bucket_base[NBUK] = base;  // == EN
  }
  __syncthreads();
  if (t < NBUK) {
    int bb = colsum[t];
    int* c = cnt + t * NBLK;
    for (int b = 0; b < NBLK; ++b) c[b] += bb;
  }
}

__global__ __launch_bounds__(512) void bucket_scatter_kernel(
    const int* __restrict__ srcA, const int* __restrict__ dstA,
    const int* __restrict__ cnt, int* __restrict__ staging) {
  __shared__ int cur[NBUK];
  int b = blockIdx.x, t = threadIdx.x;
  for (int i = t; i < NBUK; i += 512) cur[i] = cnt[i * NBLK + b];
  __syncthreads();
  int e0 = b * CHUNK, e1 = min(e0 + CHUNK, EN);
  for (int e = e0 + t; e < e1; e += 512) {
    int s, d;
    if (e < NE) { s = srcA[e]; d = dstA[e]; } else { s = e - NE; d = s; }
    int pos = atomicAdd(&cur[d >> BSH], 1);
    staging[pos] = s | ((d & (BKN - 1)) << 17);
  }
}

// P3: per-bucket fine CSR: LDS histogram -> scan -> rp -> direct scatter.
__global__ __launch_bounds__(512) void bucket_csr_kernel(
    const int* __restrict__ staging, const int* __restrict__ bucket_base,
    int* __restrict__ rp, int* __restrict__ col) {
  __shared__ int degL[BKN];
  __shared__ int exclL[BKN];
  __shared__ int sdata[2][BKN];
  int bk = blockIdx.x, t = threadIdx.x;
  int ebase = bucket_base[bk], eend = bucket_base[bk + 1];
  int ecnt = eend - ebase;
  degL[t] = 0;
  __syncthreads();
  for (int e = t; e < ecnt; e += 512)
    atomicAdd(&degL[staging[ebase + e] >> 17], 1);
  __syncthreads();
  int v = degL[t];
  sdata[0][t] = v;
  __syncthreads();
  int sp = 0;
  for (int off = 1; off < BKN; off <<= 1) {
    int val = sdata[sp][t];
    if (t >= off) val += sdata[sp][t - off];
    sdata[sp ^ 1][t] = val;
    __syncthreads();
    sp ^= 1;
  }
  int ex = sdata[sp][t] - v;  // local exclusive offset
  exclL[t] = ex;
  int node = bk * BKN + t;
  if (node < NN) rp[node] = ebase + ex;
  if (bk == 0 && t == 0) rp[NN] = EN;
  __syncthreads();
  for (int e = t; e < ecnt; e += 512) {
    int pk = staging[ebase + e];
    int pos = atomicAdd(&exclL[pk >> 17], 1);
    col[ebase + pos] = pk & 0x1FFFF;
  }
}

// ------ layer-1 gather: 8 lanes/node (lane = head), uint4 fp8 payload --------
// lane q holds channels 16q..16q+15 (= head q); 8 nodes per wave.
__global__ __launch_bounds__(256) void gather1_kernel(
    const int* __restrict__ rp, const int* __restrict__ col,
    const float* __restrict__ asn, const float* __restrict__ adn,
    const uint4* __restrict__ h8, const float* __restrict__ b1,
    ushort_t* __restrict__ x2) {
  int node = (blockIdx.x << 5) + (threadIdx.x >> 3);
  if (node >= NN) return;
  int lane = threadIdx.x & 7;  // == head
  float aD = adn[node * 8 + lane];
  int p = rp[node], p1 = rp[node + 1];
  float a[16];
#pragma unroll
  for (int j = 0; j < 16; ++j) a[j] = 0.f;
  float den = 0.f;

  for (; p + 1 < p1; p += 2) {
    int s0 = col[p], s1 = col[p + 1];
    float e0 = asn[s0 * 8 + lane] + aD;
    float e1 = asn[s1 * 8 + lane] + aD;
    uint4 q0 = h8[(size_t)s0 * 8 + lane];
    uint4 q1 = h8[(size_t)s1 * 8 + lane];
    e0 = e0 > 0.f ? e0 : NEG * e0;
    e1 = e1 > 0.f ? e1 : NEG * e1;
    float ee0 = __expf(e0), ee1 = __expf(e1);
    float d0[4], d1[4], d2[4], d3[4];
    fp8_unpack4(q0.x, d0); fp8_unpack4(q0.y, d1);
    fp8_unpack4(q0.z, d2); fp8_unpack4(q0.w, d3);
    float g0[4], g1[4], g2[4], g3[4];
    fp8_unpack4(q1.x, g0); fp8_unpack4(q1.y, g1);
    fp8_unpack4(q1.z, g2); fp8_unpack4(q1.w, g3);
#pragma unroll
    for (int j = 0; j < 4; ++j) {
      a[j]      += ee0 * d0[j] + ee1 * g0[j];
      a[4 + j]  += ee0 * d1[j] + ee1 * g1[j];
      a[8 + j]  += ee0 * d2[j] + ee1 * g2[j];
      a[12 + j] += ee0 * d3[j] + ee1 * g3[j];
    }
    den += ee0 + ee1;
  }
  if (p < p1) {
    int s0 = col[p];
    float e0 = asn[s0 * 8 + lane] + aD;
    uint4 q0 = h8[(size_t)s0 * 8 + lane];
    e0 = e0 > 0.f ? e0 : NEG * e0;
    float ee0 = __expf(e0);
    float d0[4], d1[4], d2[4], d3[4];
    fp8_unpack4(q0.x, d0); fp8_unpack4(q0.y, d1);
    fp8_unpack4(q0.z, d2); fp8_unpack4(q0.w, d3);
#pragma unroll
    for (int j = 0; j < 4; ++j) {
      a[j] += ee0 * d0[j];
      a[4 + j] += ee0 * d1[j];
      a[8 + j] += ee0 * d2[j];
      a[12 + j] += ee0 * d3[j];
    }
    den += ee0;
  }
  float inv = 1.f / den;
  const float4* b4 = (const float4*)b1;  // channels 16*lane + 0..15
  U8 t0, t1;
#pragma unroll
  for (int h = 0; h < 4; ++h) {
    float4 bv = b4[lane * 4 + h];
    float o0 = fmaf(a[h * 4 + 0], inv, bv.x);
    float o1 = fmaf(a[h * 4 + 1], inv, bv.y);
    float o2 = fmaf(a[h * 4 + 2], inv, bv.z);
    float o3 = fmaf(a[h * 4 + 3], inv, bv.w);
    o0 = o0 > 0.f ? o0 : __expf(o0) - 1.f;
    o1 = o1 > 0.f ? o1 : __expf(o1) - 1.f;
    o2 = o2 > 0.f ? o2 : __expf(o2) - 1.f;
    o3 = o3 > 0.f ? o3 : __expf(o3) - 1.f;
    U8& t = (h < 2) ? t0 : t1;
    int base = (h & 1) * 4;
    t.u[base + 0] = f2bf(o0); t.u[base + 1] = f2bf(o1);
    t.u[base + 2] = f2bf(o2); t.u[base + 3] = f2bf(o3);
  }
  uint4* xr = (uint4*)(x2 + (size_t)node * F1);  // row = 8 uint4
  xr[lane * 2 + 0] = t0.q;
  xr[lane * 2 + 1] = t1.q;
}

// ------ layer-2 gather: 8 lanes/node, uint2 fp8 payload + log_softmax --------
// lane q holds channels 8q..8q+7; 8 nodes per wave.
__global__ __launch_bounds__(256) void gather2_kernel(
    const int* __restrict__ rp, const int* __restrict__ col,
    const float* __restrict__ asn, const float* __restrict__ adn,
    const uint2* __restrict__ h28, const float* __restrict__ b2,
    float* __restrict__ out) {
  int node = (blockIdx.x << 5) + (threadIdx.x >> 3);
  if (node >= NN) return;
  int lane = threadIdx.x & 7;
  float aD = adn[node];
  int p = rp[node], p1 = rp[node + 1];
  float a[8];
#pragma unroll
  for (int j = 0; j < 8; ++j) a[j] = 0.f;
  float den = 0.f;

  for (; p + 1 < p1; p += 2) {
    int s0 = col[p], s1 = col[p + 1];
    float e0 = asn[s0] + aD;
    float e1 = asn[s1] + aD;
    uint2 q0 = h28[(size_t)s0 * 8 + lane];
    uint2 q1 = h28[(size_t)s1 * 8 + lane];
    e0 = e0 > 0.f ? e0 : NEG * e0;
    e1 = e1 > 0.f ? e1 : NEG * e1;
    float ee0 = __expf(e0), ee1 = __expf(e1);
    float d0[4], d1[4], g0[4], g1[4];
    fp8_unpack4(q0.x, d0); fp8_unpack4(q0.y, d1);
    fp8_unpack4(q1.x, g0); fp8_unpack4(q1.y, g1);
#pragma unroll
    for (int j = 0; j < 4; ++j) {
      a[j] += ee0 * d0[j] + ee1 * g0[j];
      a[4 + j] += ee0 * d1[j] + ee1 * g1[j];
    }
    den += ee0 + ee1;
  }
  if (p < p1) {
    int s0 = col[p];
    float e0 = asn[s0] + aD;
    uint2 q0 = h28[(size_t)s0 * 8 + lane];
    e0 = e0 > 0.f ? e0 : NEG * e0;
    float ee0 = __expf(e0);
    float d0[4], d1[4];
    fp8_unpack4(q0.x, d0); fp8_unpack4(q0.y, d1);
#pragma unroll
    for (int j = 0; j < 4; ++j) {
      a[j] += ee0 * d0[j];
      a[4 + j] += ee0 * d1[j];
    }
    den += ee0;
  }
  float inv = 1.f / den;
  float4 bv0 = ((const float4*)b2)[lane * 2 + 0];
  float4 bv1 = ((const float4*)b2)[lane * 2 + 1];
  float v[8];
  v[0] = fmaf(a[0], inv, bv0.x); v[1] = fmaf(a[1], inv, bv0.y);
  v[2] = fmaf(a[2], inv, bv0.z); v[3] = fmaf(a[3], inv, bv0.w);
  v[4] = fmaf(a[4], inv, bv1.x); v[5] = fmaf(a[5], inv, bv1.y);
  v[6] = fmaf(a[6], inv, bv1.z); v[7] = fmaf(a[7], inv, bv1.w);
  float m = v[0];
#pragma unroll
  for (int j = 1; j < 8; ++j) m = fmaxf(m, v[j]);
#pragma unroll
  for (int k = 1; k < 8; k <<= 1) m = fmaxf(m, __shfl_xor(m, k));
  float ex = 0.f;
#pragma unroll
  for (int j = 0; j < 8; ++j) ex += __expf(v[j] - m);
#pragma unroll
  for (int k = 1; k < 8; k <<= 1) ex += __shfl_xor(ex, k);
  float lse = m + __logf(ex);
  float4 r0 = {v[0] - lse, v[1] - lse, v[2] - lse, v[3] - lse};
  float4 r1 = {v[4] - lse, v[5] - lse, v[6] - lse, v[7] - lse};
  float4* orow = (float4*)(out + (size_t)node * NC);
  orow[lane * 2 + 0] = r0;
  orow[lane * 2 + 1] = r1;
}

extern "C" void kernel_launch(void* const* d_in, const int* in_sizes, int n_in,
                              void* d_out, int out_size, void* d_ws,
                              size_t ws_size, hipStream_t stream) {
  const float* x = (const float*)d_in[0];
  const int* edge_index = (const int*)d_in[1];
  const float* W1 = (const float*)d_in[2];
  const float* a_src1 = (const float*)d_in[3];
  const float* a_dst1 = (const float*)d_in[4];
  const float* b1 = (const float*)d_in[5];
  const float* W2 = (const float*)d_in[6];
  const float* a_src2 = (const float*)d_in[7];
  const float* a_dst2 = (const float*)d_in[8];
  const float* b2 = (const float*)d_in[9];
  float* out = (float*)d_out;
  float* ws = (float*)d_ws;

  // workspace layout (float offsets), non-overlapping:
  ushort_t* x2b = (ushort_t*)ws;               // [0, 6.4M)   bf16 x2
  uint4* h8 = (uint4*)(ws + 6400000);          // [6.4M, 9.6M)  fp8 h1 (linear)
  uint2* h28 = (uint2*)(ws + 9600000);         // [9.6M, 11.2M) fp8 h2 (linear)
  float* asn1 = ws + 11200000;                 // [11.2M, 12.0M)
  float* adn1 = ws + 12000000;                 // [12.0M, 12.8M)
  float* asn2 = ws + 12800000;                 // [12.8M, 12.9M)
  float* adn2 = ws + 12900000;                 // [12.9M, 13.0M)
  ushort_t* WT1 = (ushort_t*)(ws + 13000000);  // 16384 bf16
  ushort_t* WT2 = (ushort_t*)(ws + 13010000);  // 8192 bf16
  int* rp = (int*)(ws + 13020000);             // NN+1
  int* col = rp + NN + 1;                      // EN
  int* staging = col + EN;                     // EN
  int* cnt = staging + EN;                     // NBUK*NBLK
  int* bucket_base = cnt + NBUK * NBLK;        // NBUK+1  (~16.7M floats)

  const int* srcA = edge_index;
  const int* dstA = edge_index + NE;

  // ---- CSR build (multisplit) with fused weight prep ----
  bucket_count_kernel<<<NBLK, 512, 0, stream>>>(dstA, cnt, W1, W2, WT1, WT2);
  bucket_scan_kernel<<<1, 256, 0, stream>>>(cnt, bucket_base);
  bucket_scatter_kernel<<<NBLK, 512, 0, stream>>>(srcA, dstA, cnt, staging);
  bucket_csr_kernel<<<NBUK, 512, 0, stream>>>(staging, bucket_base, rp, col);

  // ---- layer 1 (gemm + fp8 + attn fused; LDS-free) ----
  mfma_gemm1_kernel<<<(NN + 63) / 64, 256, 0, stream>>>(
      x, WT1, a_src1, a_dst1, (uint2*)h8, asn1, adn1, NN);
  gather1_kernel<<<(NN + 31) / 32, 256, 0, stream>>>(rp, col, asn1, adn1, h8,
                                                     b1, x2b);
  // ---- layer 2 (gemm + fp8 + attn fused; LDS-free) ----
  mfma_gemm2_kernel<<<(NN + 63) / 64, 256, 0, stream>>>(
      x2b, WT2, a_src2, a_dst2, (uint_t*)h28, asn2, adn2, NN);
  gather2_kernel<<<(NN + 31) / 32, 256, 0, stream>>>(rp, col, asn2, adn2, h28,
                                                     b2, out);
}